// Round 1
// baseline (32976.102 us; speedup 1.0000x reference)
//
#include <hip/hip_runtime.h>
#include <hip/hip_bf16.h>

#define N_NODES 50000
#define N_EDGES 600000
#define D 128
#define D2 256
#define NGRAPH 512
#define NTARGET 10

static constexpr float MSG_EPS_F = 1e-7f;
static constexpr float BN_EPS_F  = 1e-5f;

// ---------------------------------------------------------------- encoders
__global__ __launch_bounds__(256) void k_encode(
    const int* __restrict__ x, const int* __restrict__ aoff,
    const float* __restrict__ atab, float* __restrict__ h) {
  int tid = blockIdx.x * 256 + threadIdx.x;
  int n = tid >> 5, f4 = (tid & 31) << 2;
  if (n >= N_NODES) return;
  float4 acc = make_float4(0.f, 0.f, 0.f, 0.f);
#pragma unroll
  for (int i = 0; i < 9; ++i) {
    int row = x[n * 9 + i] + aoff[i];
    float4 v = *(const float4*)&atab[row * D + f4];
    acc.x += v.x; acc.y += v.y; acc.z += v.z; acc.w += v.w;
  }
  *(float4*)&h[n * D + f4] = acc;
}

// ---------------------------------------------------------------- pre-norm: r = relu(BN(h))
__global__ __launch_bounds__(256) void k_prenorm(
    const float* __restrict__ h, const float* __restrict__ statH,
    const float* __restrict__ gamma, const float* __restrict__ beta,
    float* __restrict__ r) {
  int tid = blockIdx.x * 256 + threadIdx.x;
  int n = tid >> 5, f4 = (tid & 31) << 2;
  if (n >= N_NODES) return;
  const float invN = 1.0f / (float)N_NODES;
  float4 s  = *(const float4*)&statH[f4];
  float4 sq = *(const float4*)&statH[D + f4];
  float4 g  = *(const float4*)&gamma[f4];
  float4 b  = *(const float4*)&beta[f4];
  float4 hv = *(const float4*)&h[n * D + f4];
  float4 o;
  {
    float mu = s.x * invN, var = sq.x * invN - mu * mu;
    o.x = fmaxf((hv.x - mu) * rsqrtf(var + BN_EPS_F) * g.x + b.x, 0.f);
    mu = s.y * invN; var = sq.y * invN - mu * mu;
    o.y = fmaxf((hv.y - mu) * rsqrtf(var + BN_EPS_F) * g.y + b.y, 0.f);
    mu = s.z * invN; var = sq.z * invN - mu * mu;
    o.z = fmaxf((hv.z - mu) * rsqrtf(var + BN_EPS_F) * g.z + b.z, 0.f);
    mu = s.w * invN; var = sq.w * invN - mu * mu;
    o.w = fmaxf((hv.w - mu) * rsqrtf(var + BN_EPS_F) * g.w + b.w, 0.f);
  }
  *(float4*)&r[n * D + f4] = o;
}

// ---------------------------------------------------------------- edge message helper
__device__ __forceinline__ float4 edge_msg(
    const float* __restrict__ r, const int* __restrict__ eattr,
    const int* __restrict__ boff, const float* __restrict__ btab,
    int e, int src, int f4) {
  float4 ea = make_float4(0.f, 0.f, 0.f, 0.f);
#pragma unroll
  for (int i = 0; i < 3; ++i) {
    int row = eattr[e * 3 + i] + boff[i];
    float4 v = *(const float4*)&btab[row * D + f4];
    ea.x += v.x; ea.y += v.y; ea.z += v.z; ea.w += v.w;
  }
  float4 hv = *(const float4*)&r[src * D + f4];
  float4 msg;
  msg.x = fmaxf(hv.x + ea.x, 0.f) + MSG_EPS_F;
  msg.y = fmaxf(hv.y + ea.y, 0.f) + MSG_EPS_F;
  msg.z = fmaxf(hv.z + ea.z, 0.f) + MSG_EPS_F;
  msg.w = fmaxf(hv.w + ea.w, 0.f) + MSG_EPS_F;
  return msg;
}

// ---------------------------------------------------------------- edge pass 1: segment max (logits > 0, uint-punned atomicMax, 0-init == isfinite fixup)
__global__ __launch_bounds__(256) void k_edge_max(
    const float* __restrict__ r, const int* __restrict__ ei,
    const int* __restrict__ eattr, const int* __restrict__ boff,
    const float* __restrict__ btab, const float* __restrict__ tptr, int l,
    unsigned int* __restrict__ m) {
  int tid = blockIdx.x * 256 + threadIdx.x;
  int e = tid >> 5, f4 = (tid & 31) << 2;
  if (e >= N_EDGES) return;
  float tv = tptr[l];
  int src = ei[e], dst = ei[N_EDGES + e];
  float4 msg = edge_msg(r, eattr, boff, btab, e, src, f4);
  unsigned int* mp = m + (size_t)dst * D + f4;
  atomicMax(mp + 0, __float_as_uint(msg.x * tv));
  atomicMax(mp + 1, __float_as_uint(msg.y * tv));
  atomicMax(mp + 2, __float_as_uint(msg.z * tv));
  atomicMax(mp + 3, __float_as_uint(msg.w * tv));
}

// ---------------------------------------------------------------- edge pass 2: denom += e, S += msg*e
__global__ __launch_bounds__(256) void k_edge_sum(
    const float* __restrict__ r, const int* __restrict__ ei,
    const int* __restrict__ eattr, const int* __restrict__ boff,
    const float* __restrict__ btab, const float* __restrict__ tptr, int l,
    const float* __restrict__ m, float* __restrict__ den, float* __restrict__ S) {
  int tid = blockIdx.x * 256 + threadIdx.x;
  int e = tid >> 5, f4 = (tid & 31) << 2;
  if (e >= N_EDGES) return;
  float tv = tptr[l];
  int src = ei[e], dst = ei[N_EDGES + e];
  float4 msg = edge_msg(r, eattr, boff, btab, e, src, f4);
  const float4 mv = *(const float4*)&m[(size_t)dst * D + f4];
  float ex = __expf(msg.x * tv - mv.x);
  float ey = __expf(msg.y * tv - mv.y);
  float ez = __expf(msg.z * tv - mv.z);
  float ew = __expf(msg.w * tv - mv.w);
  float* dp = den + (size_t)dst * D + f4;
  float* sp = S + (size_t)dst * D + f4;
  atomicAdd(dp + 0, ex); atomicAdd(sp + 0, msg.x * ex);
  atomicAdd(dp + 1, ey); atomicAdd(sp + 1, msg.y * ey);
  atomicAdd(dp + 2, ez); atomicAdd(sp + 2, msg.z * ez);
  atomicAdd(dp + 3, ew); atomicAdd(sp + 3, msg.w * ew);
}

// ---------------------------------------------------------------- GEMM1: z1 = (r + S/(den+1e-16)) @ W1 + b1 ; accumulate BN stats of z1
__global__ __launch_bounds__(256) void k_gemm1(
    const float* __restrict__ r, const float* __restrict__ S,
    const float* __restrict__ den, const float* __restrict__ W1,
    const float* __restrict__ b1, float* __restrict__ z1,
    float* __restrict__ stat1) {
  __shared__ float A[32 * D];
  int tid = threadIdx.x;
  int row0 = blockIdx.x * 32;
#pragma unroll
  for (int j = 0; j < 4; ++j) {
    int li = tid * 16 + j * 4;
    int rr = li >> 7, kk = li & 127;
    int row = row0 + rr;
    float4 o = make_float4(0.f, 0.f, 0.f, 0.f);
    if (row < N_NODES) {
      size_t g = (size_t)row * D + kk;
      float4 rv = *(const float4*)&r[g];
      float4 Sv = *(const float4*)&S[g];
      float4 dv = *(const float4*)&den[g];
      o.x = rv.x + Sv.x / (dv.x + 1e-16f);
      o.y = rv.y + Sv.y / (dv.y + 1e-16f);
      o.z = rv.z + Sv.z / (dv.z + 1e-16f);
      o.w = rv.w + Sv.w / (dv.w + 1e-16f);
    }
    *(float4*)&A[li] = o;
  }
  __syncthreads();
  int cg = tid & 63, rg = tid >> 6;
  int c4 = cg << 2;
  float acc[8][4];
#pragma unroll
  for (int i = 0; i < 8; ++i)
#pragma unroll
    for (int j = 0; j < 4; ++j) acc[i][j] = 0.f;
  for (int k0 = 0; k0 < D; k0 += 4) {
    float4 w0 = *(const float4*)&W1[(k0 + 0) * D2 + c4];
    float4 w1v = *(const float4*)&W1[(k0 + 1) * D2 + c4];
    float4 w2v = *(const float4*)&W1[(k0 + 2) * D2 + c4];
    float4 w3v = *(const float4*)&W1[(k0 + 3) * D2 + c4];
#pragma unroll
    for (int i = 0; i < 8; ++i) {
      float4 a = *(const float4*)&A[(rg * 8 + i) * D + k0];
      acc[i][0] += a.x * w0.x + a.y * w1v.x + a.z * w2v.x + a.w * w3v.x;
      acc[i][1] += a.x * w0.y + a.y * w1v.y + a.z * w2v.y + a.w * w3v.y;
      acc[i][2] += a.x * w0.z + a.y * w1v.z + a.z * w2v.z + a.w * w3v.z;
      acc[i][3] += a.x * w0.w + a.y * w1v.w + a.z * w2v.w + a.w * w3v.w;
    }
  }
  float4 bb = *(const float4*)&b1[c4];
  float s[4] = {0.f, 0.f, 0.f, 0.f}, sq[4] = {0.f, 0.f, 0.f, 0.f};
#pragma unroll
  for (int i = 0; i < 8; ++i) {
    int row = row0 + rg * 8 + i;
    if (row < N_NODES) {
      float4 z;
      z.x = acc[i][0] + bb.x; z.y = acc[i][1] + bb.y;
      z.z = acc[i][2] + bb.z; z.w = acc[i][3] + bb.w;
      *(float4*)&z1[(size_t)row * D2 + c4] = z;
      s[0] += z.x; sq[0] += z.x * z.x;
      s[1] += z.y; sq[1] += z.y * z.y;
      s[2] += z.z; sq[2] += z.z * z.z;
      s[3] += z.w; sq[3] += z.w * z.w;
    }
  }
#pragma unroll
  for (int j = 0; j < 4; ++j) {
    atomicAdd(&stat1[c4 + j], s[j]);
    atomicAdd(&stat1[D2 + c4 + j], sq[j]);
  }
}

// ---------------------------------------------------------------- GEMM2: h = relu(BN(z1)) @ W2 + b2 (+h) ; accumulate BN stats of new h
__global__ __launch_bounds__(256) void k_gemm2(
    const float* __restrict__ z1, const float* __restrict__ stat1,
    const float* __restrict__ g1, const float* __restrict__ bt1,
    const float* __restrict__ W2, const float* __restrict__ b2,
    float* __restrict__ h, int residual, float* __restrict__ statH) {
  __shared__ float A[32 * D2];
  int tid = threadIdx.x;
  int row0 = blockIdx.x * 32;
  const float invN = 1.0f / (float)N_NODES;
#pragma unroll
  for (int j = 0; j < 8; ++j) {
    int li = j * 1024 + tid * 4;
    int rr = li >> 8, kk = li & 255;
    int row = row0 + rr;
    float4 a = make_float4(0.f, 0.f, 0.f, 0.f);
    if (row < N_NODES) {
      float4 z  = *(const float4*)&z1[(size_t)row * D2 + kk];
      float4 s  = *(const float4*)&stat1[kk];
      float4 sqv = *(const float4*)&stat1[D2 + kk];
      float4 g  = *(const float4*)&g1[kk];
      float4 b  = *(const float4*)&bt1[kk];
      float mu = s.x * invN, var = sqv.x * invN - mu * mu;
      a.x = fmaxf((z.x - mu) * rsqrtf(var + BN_EPS_F) * g.x + b.x, 0.f);
      mu = s.y * invN; var = sqv.y * invN - mu * mu;
      a.y = fmaxf((z.y - mu) * rsqrtf(var + BN_EPS_F) * g.y + b.y, 0.f);
      mu = s.z * invN; var = sqv.z * invN - mu * mu;
      a.z = fmaxf((z.z - mu) * rsqrtf(var + BN_EPS_F) * g.z + b.z, 0.f);
      mu = s.w * invN; var = sqv.w * invN - mu * mu;
      a.w = fmaxf((z.w - mu) * rsqrtf(var + BN_EPS_F) * g.w + b.w, 0.f);
    }
    *(float4*)&A[li] = a;
  }
  __syncthreads();
  int cg = tid & 31, rg = tid >> 5;
  int c4 = cg << 2;
  float acc[4][4];
#pragma unroll
  for (int i = 0; i < 4; ++i)
#pragma unroll
    for (int j = 0; j < 4; ++j) acc[i][j] = 0.f;
  for (int k0 = 0; k0 < D2; k0 += 4) {
    float4 w0 = *(const float4*)&W2[(k0 + 0) * D + c4];
    float4 w1v = *(const float4*)&W2[(k0 + 1) * D + c4];
    float4 w2v = *(const float4*)&W2[(k0 + 2) * D + c4];
    float4 w3v = *(const float4*)&W2[(k0 + 3) * D + c4];
#pragma unroll
    for (int i = 0; i < 4; ++i) {
      float4 a = *(const float4*)&A[(rg * 4 + i) * D2 + k0];
      acc[i][0] += a.x * w0.x + a.y * w1v.x + a.z * w2v.x + a.w * w3v.x;
      acc[i][1] += a.x * w0.y + a.y * w1v.y + a.z * w2v.y + a.w * w3v.y;
      acc[i][2] += a.x * w0.z + a.y * w1v.z + a.z * w2v.z + a.w * w3v.z;
      acc[i][3] += a.x * w0.w + a.y * w1v.w + a.z * w2v.w + a.w * w3v.w;
    }
  }
  float4 bb = *(const float4*)&b2[c4];
  float s[4] = {0.f, 0.f, 0.f, 0.f}, sq[4] = {0.f, 0.f, 0.f, 0.f};
#pragma unroll
  for (int i = 0; i < 4; ++i) {
    int row = row0 + rg * 4 + i;
    if (row < N_NODES) {
      float4 v;
      v.x = acc[i][0] + bb.x; v.y = acc[i][1] + bb.y;
      v.z = acc[i][2] + bb.z; v.w = acc[i][3] + bb.w;
      if (residual) {
        float4 ho = *(const float4*)&h[(size_t)row * D + c4];
        v.x += ho.x; v.y += ho.y; v.z += ho.z; v.w += ho.w;
      }
      *(float4*)&h[(size_t)row * D + c4] = v;
      s[0] += v.x; sq[0] += v.x * v.x;
      s[1] += v.y; sq[1] += v.y * v.y;
      s[2] += v.z; sq[2] += v.z * v.z;
      s[3] += v.w; sq[3] += v.w * v.w;
    }
  }
#pragma unroll
  for (int j = 0; j < 4; ++j) {
    atomicAdd(&statH[c4 + j], s[j]);
    atomicAdd(&statH[D + c4 + j], sq[j]);
  }
}

// ---------------------------------------------------------------- pool: psum[batch[n]] += BN(h[n]), pcnt[batch[n]] += 1
__global__ __launch_bounds__(256) void k_pool(
    const float* __restrict__ h, const float* __restrict__ statH,
    const float* __restrict__ gamma, const float* __restrict__ beta,
    const int* __restrict__ batch, float* __restrict__ psum,
    float* __restrict__ pcnt) {
  int tid = blockIdx.x * 256 + threadIdx.x;
  int n = tid >> 5, f4 = (tid & 31) << 2;
  if (n >= N_NODES) return;
  const float invN = 1.0f / (float)N_NODES;
  int b = batch[n];
  float4 s  = *(const float4*)&statH[f4];
  float4 sq = *(const float4*)&statH[D + f4];
  float4 g  = *(const float4*)&gamma[f4];
  float4 bt = *(const float4*)&beta[f4];
  float4 hv = *(const float4*)&h[(size_t)n * D + f4];
  float4 o;
  float mu = s.x * invN, var = sq.x * invN - mu * mu;
  o.x = (hv.x - mu) * rsqrtf(var + BN_EPS_F) * g.x + bt.x;
  mu = s.y * invN; var = sq.y * invN - mu * mu;
  o.y = (hv.y - mu) * rsqrtf(var + BN_EPS_F) * g.y + bt.y;
  mu = s.z * invN; var = sq.z * invN - mu * mu;
  o.z = (hv.z - mu) * rsqrtf(var + BN_EPS_F) * g.z + bt.z;
  mu = s.w * invN; var = sq.w * invN - mu * mu;
  o.w = (hv.w - mu) * rsqrtf(var + BN_EPS_F) * g.w + bt.w;
  float* pp = psum + (size_t)b * D + f4;
  atomicAdd(pp + 0, o.x); atomicAdd(pp + 1, o.y);
  atomicAdd(pp + 2, o.z); atomicAdd(pp + 3, o.w);
  if ((tid & 31) == 0) atomicAdd(&pcnt[b], 1.0f);
}

// ---------------------------------------------------------------- predict: out = (psum/cnt) @ pred_w + pred_b
__global__ __launch_bounds__(64) void k_pred(
    const float* __restrict__ psum, const float* __restrict__ pcnt,
    const float* __restrict__ pw, const float* __restrict__ pb,
    float* __restrict__ out) {
  int b = blockIdx.x, t = threadIdx.x;
  if (t >= NTARGET) return;
  float inv = 1.0f / fmaxf(pcnt[b], 1.0f);
  float acc = pb[t];
  for (int k = 0; k < D; ++k)
    acc += psum[(size_t)b * D + k] * inv * pw[k * NTARGET + t];
  out[b * NTARGET + t] = acc;
}

// ---------------------------------------------------------------- launch
extern "C" void kernel_launch(void* const* d_in, const int* in_sizes, int n_in,
                              void* d_out, int out_size, void* d_ws, size_t ws_size,
                              hipStream_t stream) {
  const int* x      = (const int*)d_in[0];
  const int* ei     = (const int*)d_in[1];
  const int* eattr  = (const int*)d_in[2];
  const int* batch  = (const int*)d_in[3];
  const int* aoff   = (const int*)d_in[4];
  const int* boff   = (const int*)d_in[5];
  const float* atab = (const float*)d_in[6];
  const float* btab = (const float*)d_in[7];
  const float* ngam = (const float*)d_in[8];
  const float* nbet = (const float*)d_in[9];
  const float* tptr = (const float*)d_in[10];
  const float* w1   = (const float*)d_in[11];
  const float* b1   = (const float*)d_in[12];
  const float* bng  = (const float*)d_in[13];
  const float* bnb  = (const float*)d_in[14];
  const float* w2   = (const float*)d_in[15];
  const float* b2   = (const float*)d_in[16];
  const float* pw   = (const float*)d_in[17];
  const float* pb   = (const float*)d_in[18];
  float* out = (float*)d_out;

  float* ws = (float*)d_ws;
  const size_t ND = (size_t)N_NODES * D;      // 6,400,000
  float* h   = ws;
  float* r   = ws + 1 * ND;
  float* S   = ws + 2 * ND;
  float* den = ws + 3 * ND;
  float* z1  = ws + 4 * ND;                   // 2*ND floats; m aliases first ND
  float* m   = z1;
  float* stat1 = ws + 6 * ND;                 // 512 (sum[256], sumsq[256])
  float* statH = stat1 + 512;                 // 256 (sum[128], sumsq[128])
  float* psum  = statH + 256;                 // 512*128
  float* pcnt  = psum + (size_t)NGRAPH * D;   // 512

  const int nodeBlocks = (N_NODES * 32 + 255) / 256;  // 6250
  const int edgeBlocks = (N_EDGES * 32 + 255) / 256;  // 75000
  const int gemmBlocks = (N_NODES + 31) / 32;         // 1563

  k_encode<<<nodeBlocks, 256, 0, stream>>>(x, aoff, atab, h);

  for (int l = 0; l < 7; ++l) {
    const float* rin = h;
    if (l > 0) {
      k_prenorm<<<nodeBlocks, 256, 0, stream>>>(h, statH, ngam + l * D, nbet + l * D, r);
      rin = r;
    }
    // zero S, den, m (contiguous: ws[2*ND .. 5*ND)) and the stat buffers
    hipMemsetAsync(S, 0, 3 * ND * sizeof(float), stream);
    hipMemsetAsync(stat1, 0, 768 * sizeof(float), stream);

    k_edge_max<<<edgeBlocks, 256, 0, stream>>>(rin, ei, eattr, boff, btab, tptr, l,
                                               (unsigned int*)m);
    k_edge_sum<<<edgeBlocks, 256, 0, stream>>>(rin, ei, eattr, boff, btab, tptr, l,
                                               m, den, S);
    k_gemm1<<<gemmBlocks, 256, 0, stream>>>(rin, S, den, w1 + (size_t)l * D * D2,
                                            b1 + l * D2, z1, stat1);
    k_gemm2<<<gemmBlocks, 256, 0, stream>>>(z1, stat1, bng + l * D2, bnb + l * D2,
                                            w2 + (size_t)l * D2 * D, b2 + l * D,
                                            h, l > 0 ? 1 : 0, statH);
  }

  hipMemsetAsync(psum, 0, ((size_t)NGRAPH * D + NGRAPH) * sizeof(float), stream);
  k_pool<<<nodeBlocks, 256, 0, stream>>>(h, statH, ngam, nbet, batch, psum, pcnt);
  k_pred<<<NGRAPH, 64, 0, stream>>>(psum, pcnt, pw, pb, out);
}

// Round 2
// 13914.276 us; speedup vs baseline: 2.3699x; 2.3699x over previous
//
#include <hip/hip_runtime.h>
#include <hip/hip_bf16.h>

#define N_NODES 50000
#define N_EDGES 600000
#define D 128
#define D2 256
#define NGRAPH 512
#define NTARGET 10

static constexpr float MSG_EPS_F = 1e-7f;
static constexpr float BN_EPS_F  = 1e-5f;

// ---------------------------------------------------------------- encoders
__global__ __launch_bounds__(256) void k_encode(
    const int* __restrict__ x, const int* __restrict__ aoff,
    const float* __restrict__ atab, float* __restrict__ h) {
  int tid = blockIdx.x * 256 + threadIdx.x;
  int n = tid >> 5, f4 = (tid & 31) << 2;
  if (n >= N_NODES) return;
  float4 acc = make_float4(0.f, 0.f, 0.f, 0.f);
#pragma unroll
  for (int i = 0; i < 9; ++i) {
    int row = x[n * 9 + i] + aoff[i];
    float4 v = *(const float4*)&atab[row * D + f4];
    acc.x += v.x; acc.y += v.y; acc.z += v.z; acc.w += v.w;
  }
  *(float4*)&h[n * D + f4] = acc;
}

// ---------------------------------------------------------------- combo table: 60 bond-attr combinations
__global__ __launch_bounds__(128) void k_combo(
    const int* __restrict__ boff, const float* __restrict__ btab,
    float* __restrict__ combo) {
  int c = blockIdx.x, t = threadIdx.x;
  int a0 = c / 12, a1 = (c % 12) / 2, a2 = c % 2;
  combo[c * D + t] = btab[(boff[0] + a0) * D + t] +
                     btab[(boff[1] + a1) * D + t] +
                     btab[(boff[2] + a2) * D + t];
}

// ---------------------------------------------------------------- CSR build
__global__ __launch_bounds__(256) void k_degree(
    const int* __restrict__ ei, int* __restrict__ deg) {
  int e = blockIdx.x * 256 + threadIdx.x;
  if (e >= N_EDGES) return;
  atomicAdd(&deg[ei[N_EDGES + e]], 1);
}

__global__ __launch_bounds__(1024) void k_scan(
    const int* __restrict__ deg, int* __restrict__ rowptr,
    int* __restrict__ cursor) {
  __shared__ int tmp[1024];
  __shared__ int carryS;
  int t = threadIdx.x;
  if (t == 0) carryS = 0;
  __syncthreads();
  for (int base = 0; base < N_NODES; base += 1024) {
    int i = base + t;
    int v = (i < N_NODES) ? deg[i] : 0;
    tmp[t] = v;
    __syncthreads();
    for (int off = 1; off < 1024; off <<= 1) {
      int add = (t >= off) ? tmp[t - off] : 0;
      __syncthreads();
      tmp[t] += add;
      __syncthreads();
    }
    int carry = carryS;
    if (i < N_NODES) {
      int excl = carry + tmp[t] - v;
      rowptr[i] = excl;
      cursor[i] = excl;
    }
    __syncthreads();
    if (t == 1023) carryS = carry + tmp[1023];
    __syncthreads();
  }
  if (t == 0) rowptr[N_NODES] = carryS;
}

__global__ __launch_bounds__(256) void k_scatter(
    const int* __restrict__ ei, const int* __restrict__ eattr,
    int* __restrict__ cursor, int* __restrict__ payload) {
  int e = blockIdx.x * 256 + threadIdx.x;
  if (e >= N_EDGES) return;
  int src = ei[e], dst = ei[N_EDGES + e];
  int cid = eattr[e * 3 + 0] * 12 + eattr[e * 3 + 1] * 2 + eattr[e * 3 + 2];
  int pos = atomicAdd(&cursor[dst], 1);
  payload[pos] = (src << 6) | cid;
}

// ---------------------------------------------------------------- pre-norm: r = relu(BN(h))
__global__ __launch_bounds__(256) void k_prenorm(
    const float* __restrict__ h, const float* __restrict__ statH,
    const float* __restrict__ gamma, const float* __restrict__ beta,
    float* __restrict__ r) {
  int tid = blockIdx.x * 256 + threadIdx.x;
  int n = tid >> 5, f4 = (tid & 31) << 2;
  if (n >= N_NODES) return;
  const float invN = 1.0f / (float)N_NODES;
  float4 s  = *(const float4*)&statH[f4];
  float4 sq = *(const float4*)&statH[D + f4];
  float4 g  = *(const float4*)&gamma[f4];
  float4 b  = *(const float4*)&beta[f4];
  float4 hv = *(const float4*)&h[(size_t)n * D + f4];
  float4 o;
  float mu = s.x * invN, var = sq.x * invN - mu * mu;
  o.x = fmaxf((hv.x - mu) * rsqrtf(var + BN_EPS_F) * g.x + b.x, 0.f);
  mu = s.y * invN; var = sq.y * invN - mu * mu;
  o.y = fmaxf((hv.y - mu) * rsqrtf(var + BN_EPS_F) * g.y + b.y, 0.f);
  mu = s.z * invN; var = sq.z * invN - mu * mu;
  o.z = fmaxf((hv.z - mu) * rsqrtf(var + BN_EPS_F) * g.z + b.z, 0.f);
  mu = s.w * invN; var = sq.w * invN - mu * mu;
  o.w = fmaxf((hv.w - mu) * rsqrtf(var + BN_EPS_F) * g.w + b.w, 0.f);
  *(float4*)&r[(size_t)n * D + f4] = o;
}

// ---------------------------------------------------------------- CSR softmax aggregation (no atomics, no max pass)
__global__ __launch_bounds__(256) void k_aggr(
    const float* __restrict__ r, const int* __restrict__ rowptr,
    const int* __restrict__ payload, const float* __restrict__ combo,
    const float* __restrict__ tptr, int l, float* __restrict__ aggr) {
  int tid = blockIdx.x * 256 + threadIdx.x;
  int dst = tid >> 5, f4 = (tid & 31) << 2;
  if (dst >= N_NODES) return;
  float tv = tptr[l];
  int s = rowptr[dst], e = rowptr[dst + 1];
  float4 den = make_float4(0.f, 0.f, 0.f, 0.f);
  float4 S = make_float4(0.f, 0.f, 0.f, 0.f);
  for (int i = s; i < e; ++i) {
    int p = payload[i];
    int src = p >> 6, cid = p & 63;
    float4 rv = *(const float4*)&r[(size_t)src * D + f4];
    float4 cv = *(const float4*)&combo[cid * D + f4];
    float mx = fmaxf(rv.x + cv.x, 0.f) + MSG_EPS_F;
    float my = fmaxf(rv.y + cv.y, 0.f) + MSG_EPS_F;
    float mz = fmaxf(rv.z + cv.z, 0.f) + MSG_EPS_F;
    float mw = fmaxf(rv.w + cv.w, 0.f) + MSG_EPS_F;
    float ex = __expf(mx * tv), ey = __expf(my * tv);
    float ez = __expf(mz * tv), ew = __expf(mw * tv);
    den.x += ex; den.y += ey; den.z += ez; den.w += ew;
    S.x += mx * ex; S.y += my * ey; S.z += mz * ez; S.w += mw * ew;
  }
  float4 o;
  o.x = S.x / (den.x + 1e-16f);
  o.y = S.y / (den.y + 1e-16f);
  o.z = S.z / (den.z + 1e-16f);
  o.w = S.w / (den.w + 1e-16f);
  *(float4*)&aggr[(size_t)dst * D + f4] = o;
}

// ---------------------------------------------------------------- GEMM1: z1 = (r + aggr) @ W1 + b1 ; accumulate BN stats of z1
__global__ __launch_bounds__(256) void k_gemm1(
    const float* __restrict__ r, const float* __restrict__ aggr,
    const float* __restrict__ W1, const float* __restrict__ b1,
    float* __restrict__ z1, float* __restrict__ stat1) {
  __shared__ float A[32 * D];
  int tid = threadIdx.x;
  int row0 = blockIdx.x * 32;
#pragma unroll
  for (int j = 0; j < 4; ++j) {
    int li = j * 1024 + tid * 4;   // consecutive float4 per thread: conflict-free
    int rr = li >> 7, kk = li & 127;
    int row = row0 + rr;
    float4 o = make_float4(0.f, 0.f, 0.f, 0.f);
    if (row < N_NODES) {
      size_t g = (size_t)row * D + kk;
      float4 rv = *(const float4*)&r[g];
      float4 av = *(const float4*)&aggr[g];
      o.x = rv.x + av.x; o.y = rv.y + av.y;
      o.z = rv.z + av.z; o.w = rv.w + av.w;
    }
    *(float4*)&A[li] = o;
  }
  __syncthreads();
  int cg = tid & 63, rg = tid >> 6;
  int c4 = cg << 2;
  float acc[8][4];
#pragma unroll
  for (int i = 0; i < 8; ++i)
#pragma unroll
    for (int j = 0; j < 4; ++j) acc[i][j] = 0.f;
  for (int k0 = 0; k0 < D; k0 += 4) {
    float4 w0 = *(const float4*)&W1[(k0 + 0) * D2 + c4];
    float4 w1v = *(const float4*)&W1[(k0 + 1) * D2 + c4];
    float4 w2v = *(const float4*)&W1[(k0 + 2) * D2 + c4];
    float4 w3v = *(const float4*)&W1[(k0 + 3) * D2 + c4];
#pragma unroll
    for (int i = 0; i < 8; ++i) {
      float4 a = *(const float4*)&A[(rg * 8 + i) * D + k0];
      acc[i][0] += a.x * w0.x + a.y * w1v.x + a.z * w2v.x + a.w * w3v.x;
      acc[i][1] += a.x * w0.y + a.y * w1v.y + a.z * w2v.y + a.w * w3v.y;
      acc[i][2] += a.x * w0.z + a.y * w1v.z + a.z * w2v.z + a.w * w3v.z;
      acc[i][3] += a.x * w0.w + a.y * w1v.w + a.z * w2v.w + a.w * w3v.w;
    }
  }
  float4 bb = *(const float4*)&b1[c4];
  float s[4] = {0.f, 0.f, 0.f, 0.f}, sq[4] = {0.f, 0.f, 0.f, 0.f};
#pragma unroll
  for (int i = 0; i < 8; ++i) {
    int row = row0 + rg * 8 + i;
    if (row < N_NODES) {
      float4 z;
      z.x = acc[i][0] + bb.x; z.y = acc[i][1] + bb.y;
      z.z = acc[i][2] + bb.z; z.w = acc[i][3] + bb.w;
      *(float4*)&z1[(size_t)row * D2 + c4] = z;
      s[0] += z.x; sq[0] += z.x * z.x;
      s[1] += z.y; sq[1] += z.y * z.y;
      s[2] += z.z; sq[2] += z.z * z.z;
      s[3] += z.w; sq[3] += z.w * z.w;
    }
  }
#pragma unroll
  for (int j = 0; j < 4; ++j) {
    atomicAdd(&stat1[c4 + j], s[j]);
    atomicAdd(&stat1[D2 + c4 + j], sq[j]);
  }
}

// ---------------------------------------------------------------- GEMM2: h = relu(BN(z1)) @ W2 + b2 (+h) ; accumulate BN stats of new h
__global__ __launch_bounds__(256) void k_gemm2(
    const float* __restrict__ z1, const float* __restrict__ stat1,
    const float* __restrict__ g1, const float* __restrict__ bt1,
    const float* __restrict__ W2, const float* __restrict__ b2,
    float* __restrict__ h, int residual, float* __restrict__ statH) {
  __shared__ float A[32 * D2];
  int tid = threadIdx.x;
  int row0 = blockIdx.x * 32;
  const float invN = 1.0f / (float)N_NODES;
#pragma unroll
  for (int j = 0; j < 8; ++j) {
    int li = j * 1024 + tid * 4;
    int rr = li >> 8, kk = li & 255;
    int row = row0 + rr;
    float4 a = make_float4(0.f, 0.f, 0.f, 0.f);
    if (row < N_NODES) {
      float4 z  = *(const float4*)&z1[(size_t)row * D2 + kk];
      float4 s  = *(const float4*)&stat1[kk];
      float4 sqv = *(const float4*)&stat1[D2 + kk];
      float4 g  = *(const float4*)&g1[kk];
      float4 b  = *(const float4*)&bt1[kk];
      float mu = s.x * invN, var = sqv.x * invN - mu * mu;
      a.x = fmaxf((z.x - mu) * rsqrtf(var + BN_EPS_F) * g.x + b.x, 0.f);
      mu = s.y * invN; var = sqv.y * invN - mu * mu;
      a.y = fmaxf((z.y - mu) * rsqrtf(var + BN_EPS_F) * g.y + b.y, 0.f);
      mu = s.z * invN; var = sqv.z * invN - mu * mu;
      a.z = fmaxf((z.z - mu) * rsqrtf(var + BN_EPS_F) * g.z + b.z, 0.f);
      mu = s.w * invN; var = sqv.w * invN - mu * mu;
      a.w = fmaxf((z.w - mu) * rsqrtf(var + BN_EPS_F) * g.w + b.w, 0.f);
    }
    *(float4*)&A[li] = a;
  }
  __syncthreads();
  int cg = tid & 31, rg = tid >> 5;
  int c4 = cg << 2;
  float acc[4][4];
#pragma unroll
  for (int i = 0; i < 4; ++i)
#pragma unroll
    for (int j = 0; j < 4; ++j) acc[i][j] = 0.f;
  for (int k0 = 0; k0 < D2; k0 += 4) {
    float4 w0 = *(const float4*)&W2[(k0 + 0) * D + c4];
    float4 w1v = *(const float4*)&W2[(k0 + 1) * D + c4];
    float4 w2v = *(const float4*)&W2[(k0 + 2) * D + c4];
    float4 w3v = *(const float4*)&W2[(k0 + 3) * D + c4];
#pragma unroll
    for (int i = 0; i < 4; ++i) {
      float4 a = *(const float4*)&A[(rg * 4 + i) * D2 + k0];
      acc[i][0] += a.x * w0.x + a.y * w1v.x + a.z * w2v.x + a.w * w3v.x;
      acc[i][1] += a.x * w0.y + a.y * w1v.y + a.z * w2v.y + a.w * w3v.y;
      acc[i][2] += a.x * w0.z + a.y * w1v.z + a.z * w2v.z + a.w * w3v.z;
      acc[i][3] += a.x * w0.w + a.y * w1v.w + a.z * w2v.w + a.w * w3v.w;
    }
  }
  float4 bb = *(const float4*)&b2[c4];
  float s[4] = {0.f, 0.f, 0.f, 0.f}, sq[4] = {0.f, 0.f, 0.f, 0.f};
#pragma unroll
  for (int i = 0; i < 4; ++i) {
    int row = row0 + rg * 4 + i;
    if (row < N_NODES) {
      float4 v;
      v.x = acc[i][0] + bb.x; v.y = acc[i][1] + bb.y;
      v.z = acc[i][2] + bb.z; v.w = acc[i][3] + bb.w;
      if (residual) {
        float4 ho = *(const float4*)&h[(size_t)row * D + c4];
        v.x += ho.x; v.y += ho.y; v.z += ho.z; v.w += ho.w;
      }
      *(float4*)&h[(size_t)row * D + c4] = v;
      s[0] += v.x; sq[0] += v.x * v.x;
      s[1] += v.y; sq[1] += v.y * v.y;
      s[2] += v.z; sq[2] += v.z * v.z;
      s[3] += v.w; sq[3] += v.w * v.w;
    }
  }
#pragma unroll
  for (int j = 0; j < 4; ++j) {
    atomicAdd(&statH[c4 + j], s[j]);
    atomicAdd(&statH[D + c4 + j], sq[j]);
  }
}

// ---------------------------------------------------------------- pool
__global__ __launch_bounds__(256) void k_pool(
    const float* __restrict__ h, const float* __restrict__ statH,
    const float* __restrict__ gamma, const float* __restrict__ beta,
    const int* __restrict__ batch, float* __restrict__ psum,
    float* __restrict__ pcnt) {
  int tid = blockIdx.x * 256 + threadIdx.x;
  int n = tid >> 5, f4 = (tid & 31) << 2;
  if (n >= N_NODES) return;
  const float invN = 1.0f / (float)N_NODES;
  int b = batch[n];
  float4 s  = *(const float4*)&statH[f4];
  float4 sq = *(const float4*)&statH[D + f4];
  float4 g  = *(const float4*)&gamma[f4];
  float4 bt = *(const float4*)&beta[f4];
  float4 hv = *(const float4*)&h[(size_t)n * D + f4];
  float4 o;
  float mu = s.x * invN, var = sq.x * invN - mu * mu;
  o.x = (hv.x - mu) * rsqrtf(var + BN_EPS_F) * g.x + bt.x;
  mu = s.y * invN; var = sq.y * invN - mu * mu;
  o.y = (hv.y - mu) * rsqrtf(var + BN_EPS_F) * g.y + bt.y;
  mu = s.z * invN; var = sq.z * invN - mu * mu;
  o.z = (hv.z - mu) * rsqrtf(var + BN_EPS_F) * g.z + bt.z;
  mu = s.w * invN; var = sq.w * invN - mu * mu;
  o.w = (hv.w - mu) * rsqrtf(var + BN_EPS_F) * g.w + bt.w;
  float* pp = psum + (size_t)b * D + f4;
  atomicAdd(pp + 0, o.x); atomicAdd(pp + 1, o.y);
  atomicAdd(pp + 2, o.z); atomicAdd(pp + 3, o.w);
  if ((tid & 31) == 0) atomicAdd(&pcnt[b], 1.0f);
}

// ---------------------------------------------------------------- predict
__global__ __launch_bounds__(64) void k_pred(
    const float* __restrict__ psum, const float* __restrict__ pcnt,
    const float* __restrict__ pw, const float* __restrict__ pb,
    float* __restrict__ out) {
  int b = blockIdx.x, t = threadIdx.x;
  if (t >= NTARGET) return;
  float inv = 1.0f / fmaxf(pcnt[b], 1.0f);
  float acc = pb[t];
  for (int k = 0; k < D; ++k)
    acc += psum[(size_t)b * D + k] * inv * pw[k * NTARGET + t];
  out[b * NTARGET + t] = acc;
}

// ---------------------------------------------------------------- launch
extern "C" void kernel_launch(void* const* d_in, const int* in_sizes, int n_in,
                              void* d_out, int out_size, void* d_ws, size_t ws_size,
                              hipStream_t stream) {
  const int* x      = (const int*)d_in[0];
  const int* ei     = (const int*)d_in[1];
  const int* eattr  = (const int*)d_in[2];
  const int* batch  = (const int*)d_in[3];
  const int* aoff   = (const int*)d_in[4];
  const int* boff   = (const int*)d_in[5];
  const float* atab = (const float*)d_in[6];
  const float* btab = (const float*)d_in[7];
  const float* ngam = (const float*)d_in[8];
  const float* nbet = (const float*)d_in[9];
  const float* tptr = (const float*)d_in[10];
  const float* w1   = (const float*)d_in[11];
  const float* b1   = (const float*)d_in[12];
  const float* bng  = (const float*)d_in[13];
  const float* bnb  = (const float*)d_in[14];
  const float* w2   = (const float*)d_in[15];
  const float* b2   = (const float*)d_in[16];
  const float* pw   = (const float*)d_in[17];
  const float* pb   = (const float*)d_in[18];
  float* out = (float*)d_out;

  float* ws = (float*)d_ws;
  const size_t ND = (size_t)N_NODES * D;      // 6,400,000
  float* h    = ws;
  float* r    = ws + 1 * ND;
  float* aggr = ws + 2 * ND;
  float* z1   = ws + 3 * ND;                  // 2*ND floats
  float* stat1 = ws + 5 * ND;                 // 512
  float* statH = stat1 + 512;                 // 256
  float* psum  = statH + 256;                 // 512*128
  float* pcnt  = psum + (size_t)NGRAPH * D;   // 512
  float* combo = pcnt + NGRAPH;               // 60*128
  int* ibuf    = (int*)(combo + 60 * D);
  int* rowptr  = ibuf;                        // 50001
  int* cursor  = rowptr + N_NODES + 1;        // 50000
  int* deg     = cursor + N_NODES;            // 50000
  int* payload = deg + N_NODES;               // 600000

  const int nodeBlocks = (N_NODES * 32 + 255) / 256;  // 6250
  const int edgeThreadBlocks = (N_EDGES + 255) / 256; // 2344
  const int gemmBlocks = (N_NODES + 31) / 32;         // 1563

  // CSR build (same work every call)
  hipMemsetAsync(deg, 0, N_NODES * sizeof(int), stream);
  k_encode<<<nodeBlocks, 256, 0, stream>>>(x, aoff, atab, h);
  k_combo<<<60, 128, 0, stream>>>(boff, btab, combo);
  k_degree<<<edgeThreadBlocks, 256, 0, stream>>>(ei, deg);
  k_scan<<<1, 1024, 0, stream>>>(deg, rowptr, cursor);
  k_scatter<<<edgeThreadBlocks, 256, 0, stream>>>(ei, eattr, cursor, payload);

  for (int l = 0; l < 7; ++l) {
    const float* rin = h;
    if (l > 0) {
      k_prenorm<<<nodeBlocks, 256, 0, stream>>>(h, statH, ngam + l * D, nbet + l * D, r);
      rin = r;
    }
    hipMemsetAsync(stat1, 0, 768 * sizeof(float), stream);
    k_aggr<<<nodeBlocks, 256, 0, stream>>>(rin, rowptr, payload, combo, tptr, l, aggr);
    k_gemm1<<<gemmBlocks, 256, 0, stream>>>(rin, aggr, w1 + (size_t)l * D * D2,
                                            b1 + l * D2, z1, stat1);
    k_gemm2<<<gemmBlocks, 256, 0, stream>>>(z1, stat1, bng + l * D2, bnb + l * D2,
                                            w2 + (size_t)l * D2 * D, b2 + l * D,
                                            h, l > 0 ? 1 : 0, statH);
  }

  hipMemsetAsync(psum, 0, ((size_t)NGRAPH * D + NGRAPH) * sizeof(float), stream);
  k_pool<<<nodeBlocks, 256, 0, stream>>>(h, statH, ngam, nbet, batch, psum, pcnt);
  k_pred<<<NGRAPH, 64, 0, stream>>>(psum, pcnt, pw, pb, out);
}

// Round 3
// 8317.883 us; speedup vs baseline: 3.9645x; 1.6728x over previous
//
#include <hip/hip_runtime.h>
#include <hip/hip_bf16.h>

#define N_NODES 50000
#define N_EDGES 600000
#define D 128
#define D2 256
#define NGRAPH 512
#define NTARGET 10

static constexpr float MSG_EPS_F = 1e-7f;
static constexpr float BN_EPS_F  = 1e-5f;

// ---------------------------------------------------------------- encoders
__global__ __launch_bounds__(256) void k_encode(
    const int* __restrict__ x, const int* __restrict__ aoff,
    const float* __restrict__ atab, float* __restrict__ h) {
  int tid = blockIdx.x * 256 + threadIdx.x;
  int n = tid >> 5, f4 = (tid & 31) << 2;
  if (n >= N_NODES) return;
  float4 acc = make_float4(0.f, 0.f, 0.f, 0.f);
#pragma unroll
  for (int i = 0; i < 9; ++i) {
    int row = x[n * 9 + i] + aoff[i];
    float4 v = *(const float4*)&atab[row * D + f4];
    acc.x += v.x; acc.y += v.y; acc.z += v.z; acc.w += v.w;
  }
  *(float4*)&h[n * D + f4] = acc;
}

// ---------------------------------------------------------------- combo table
__global__ __launch_bounds__(128) void k_combo(
    const int* __restrict__ boff, const float* __restrict__ btab,
    float* __restrict__ combo) {
  int c = blockIdx.x, t = threadIdx.x;
  int a0 = c / 12, a1 = (c % 12) / 2, a2 = c % 2;
  combo[c * D + t] = btab[(boff[0] + a0) * D + t] +
                     btab[(boff[1] + a1) * D + t] +
                     btab[(boff[2] + a2) * D + t];
}

// ---------------------------------------------------------------- CSR build
__global__ __launch_bounds__(256) void k_degree(
    const int* __restrict__ ei, int* __restrict__ deg) {
  int e = blockIdx.x * 256 + threadIdx.x;
  if (e >= N_EDGES) return;
  atomicAdd(&deg[ei[N_EDGES + e]], 1);
}

__global__ __launch_bounds__(1024) void k_scan(
    const int* __restrict__ deg, int* __restrict__ rowptr,
    int* __restrict__ cursor) {
  __shared__ int tmp[1024];
  __shared__ int carryS;
  int t = threadIdx.x;
  if (t == 0) carryS = 0;
  __syncthreads();
  for (int base = 0; base < N_NODES; base += 1024) {
    int i = base + t;
    int v = (i < N_NODES) ? deg[i] : 0;
    tmp[t] = v;
    __syncthreads();
    for (int off = 1; off < 1024; off <<= 1) {
      int add = (t >= off) ? tmp[t - off] : 0;
      __syncthreads();
      tmp[t] += add;
      __syncthreads();
    }
    int carry = carryS;
    if (i < N_NODES) {
      int excl = carry + tmp[t] - v;
      rowptr[i] = excl;
      cursor[i] = excl;
    }
    __syncthreads();
    if (t == 1023) carryS = carry + tmp[1023];
    __syncthreads();
  }
  if (t == 0) rowptr[N_NODES] = carryS;
}

__global__ __launch_bounds__(256) void k_scatter(
    const int* __restrict__ ei, const int* __restrict__ eattr,
    int* __restrict__ cursor, int* __restrict__ payload) {
  int e = blockIdx.x * 256 + threadIdx.x;
  if (e >= N_EDGES) return;
  int src = ei[e], dst = ei[N_EDGES + e];
  int cid = eattr[e * 3 + 0] * 12 + eattr[e * 3 + 1] * 2 + eattr[e * 3 + 2];
  int pos = atomicAdd(&cursor[dst], 1);
  payload[pos] = (src << 6) | cid;
}

// ---------------------------------------------------------------- pre-norm: r = relu(BN(h))
__global__ __launch_bounds__(256) void k_prenorm(
    const float* __restrict__ h, const float* __restrict__ statH,
    const float* __restrict__ gamma, const float* __restrict__ beta,
    float* __restrict__ r) {
  int tid = blockIdx.x * 256 + threadIdx.x;
  int n = tid >> 5, f4 = (tid & 31) << 2;
  if (n >= N_NODES) return;
  const float invN = 1.0f / (float)N_NODES;
  float4 s  = *(const float4*)&statH[f4];
  float4 sq = *(const float4*)&statH[D + f4];
  float4 g  = *(const float4*)&gamma[f4];
  float4 b  = *(const float4*)&beta[f4];
  float4 hv = *(const float4*)&h[(size_t)n * D + f4];
  float4 o;
  float mu = s.x * invN, var = sq.x * invN - mu * mu;
  o.x = fmaxf((hv.x - mu) * rsqrtf(var + BN_EPS_F) * g.x + b.x, 0.f);
  mu = s.y * invN; var = sq.y * invN - mu * mu;
  o.y = fmaxf((hv.y - mu) * rsqrtf(var + BN_EPS_F) * g.y + b.y, 0.f);
  mu = s.z * invN; var = sq.z * invN - mu * mu;
  o.z = fmaxf((hv.z - mu) * rsqrtf(var + BN_EPS_F) * g.z + b.z, 0.f);
  mu = s.w * invN; var = sq.w * invN - mu * mu;
  o.w = fmaxf((hv.w - mu) * rsqrtf(var + BN_EPS_F) * g.w + b.w, 0.f);
  *(float4*)&r[(size_t)n * D + f4] = o;
}

// ---------------------------------------------------------------- CSR softmax aggregation
__global__ __launch_bounds__(256) void k_aggr(
    const float* __restrict__ r, const int* __restrict__ rowptr,
    const int* __restrict__ payload, const float* __restrict__ combo,
    const float* __restrict__ tptr, int l, float* __restrict__ aggr) {
  int tid = blockIdx.x * 256 + threadIdx.x;
  int dst = tid >> 5, f4 = (tid & 31) << 2;
  if (dst >= N_NODES) return;
  float tv = tptr[l];
  int s = rowptr[dst], e = rowptr[dst + 1];
  float4 den = make_float4(0.f, 0.f, 0.f, 0.f);
  float4 S = make_float4(0.f, 0.f, 0.f, 0.f);
  for (int i = s; i < e; ++i) {
    int p = payload[i];
    int src = p >> 6, cid = p & 63;
    float4 rv = *(const float4*)&r[(size_t)src * D + f4];
    float4 cv = *(const float4*)&combo[cid * D + f4];
    float mx = fmaxf(rv.x + cv.x, 0.f) + MSG_EPS_F;
    float my = fmaxf(rv.y + cv.y, 0.f) + MSG_EPS_F;
    float mz = fmaxf(rv.z + cv.z, 0.f) + MSG_EPS_F;
    float mw = fmaxf(rv.w + cv.w, 0.f) + MSG_EPS_F;
    float ex = __expf(mx * tv), ey = __expf(my * tv);
    float ez = __expf(mz * tv), ew = __expf(mw * tv);
    den.x += ex; den.y += ey; den.z += ez; den.w += ew;
    S.x += mx * ex; S.y += my * ey; S.z += mz * ez; S.w += mw * ew;
  }
  float4 o;
  o.x = S.x / (den.x + 1e-16f);
  o.y = S.y / (den.y + 1e-16f);
  o.z = S.z / (den.z + 1e-16f);
  o.w = S.w / (den.w + 1e-16f);
  *(float4*)&aggr[(size_t)dst * D + f4] = o;
}

// ---------------------------------------------------------------- GEMM1: z1 = (r+aggr) @ W1 + b1 ; BN stats of z1
// BM=128 BN=128 BK=32, 256 thr, 8x8 micro-tile. A in LDS K-major (pad 132).
__global__ __launch_bounds__(256) void k_gemm1(
    const float* __restrict__ r, const float* __restrict__ aggr,
    const float* __restrict__ W1, const float* __restrict__ b1,
    float* __restrict__ z1, float* __restrict__ stat1) {
  __shared__ float As[32 * 132];
  __shared__ float Bs[32 * 128];
  int tid = threadIdx.x;
  int row0 = blockIdx.x * 128;
  int col0 = blockIdx.y * 128;
  int tx = tid & 15, ty = tid >> 4;
  float acc[8][8];
#pragma unroll
  for (int i = 0; i < 8; ++i)
#pragma unroll
    for (int j = 0; j < 8; ++j) acc[i][j] = 0.f;

  int mrow = tid >> 3;            // 0..31
  int mk   = (tid & 7) << 2;      // 0..28

  for (int k0 = 0; k0 < D; k0 += 32) {
    // stage A (transposed, K-major): 128 rows x 32 k
#pragma unroll
    for (int p = 0; p < 4; ++p) {
      int row = row0 + p * 32 + mrow;
      float4 v = make_float4(0.f, 0.f, 0.f, 0.f);
      if (row < N_NODES) {
        size_t g = (size_t)row * D + k0 + mk;
        float4 rv = *(const float4*)&r[g];
        float4 av = *(const float4*)&aggr[g];
        v.x = rv.x + av.x; v.y = rv.y + av.y;
        v.z = rv.z + av.z; v.w = rv.w + av.w;
      }
      int m = p * 32 + mrow;
      As[(mk + 0) * 132 + m] = v.x;
      As[(mk + 1) * 132 + m] = v.y;
      As[(mk + 2) * 132 + m] = v.z;
      As[(mk + 3) * 132 + m] = v.w;
    }
    // stage B: 32 k-rows x 128 cols
#pragma unroll
    for (int p = 0; p < 4; ++p) {
      int li = p * 1024 + tid * 4;
      int kk = li >> 7, cc = li & 127;
      *(float4*)&Bs[kk * 128 + cc] =
          *(const float4*)&W1[(size_t)(k0 + kk) * D2 + col0 + cc];
    }
    __syncthreads();
#pragma unroll 4
    for (int kk = 0; kk < 32; ++kk) {
      float4 a0 = *(const float4*)&As[kk * 132 + ty * 8];
      float4 a1 = *(const float4*)&As[kk * 132 + ty * 8 + 4];
      float4 b0 = *(const float4*)&Bs[kk * 128 + tx * 8];
      float4 b1v = *(const float4*)&Bs[kk * 128 + tx * 8 + 4];
      float a[8] = {a0.x, a0.y, a0.z, a0.w, a1.x, a1.y, a1.z, a1.w};
      float b[8] = {b0.x, b0.y, b0.z, b0.w, b1v.x, b1v.y, b1v.z, b1v.w};
#pragma unroll
      for (int i = 0; i < 8; ++i)
#pragma unroll
        for (int j = 0; j < 8; ++j) acc[i][j] += a[i] * b[j];
    }
    __syncthreads();
  }
  // epilogue: +bias, store, column stats
  float4 bb0 = *(const float4*)&b1[col0 + tx * 8];
  float4 bb1 = *(const float4*)&b1[col0 + tx * 8 + 4];
  float bsc[8] = {bb0.x, bb0.y, bb0.z, bb0.w, bb1.x, bb1.y, bb1.z, bb1.w};
  float cs[8], cq[8];
#pragma unroll
  for (int j = 0; j < 8; ++j) { cs[j] = 0.f; cq[j] = 0.f; }
#pragma unroll
  for (int i = 0; i < 8; ++i) {
    int row = row0 + ty * 8 + i;
    if (row < N_NODES) {
      float z[8];
#pragma unroll
      for (int j = 0; j < 8; ++j) {
        z[j] = acc[i][j] + bsc[j];
        cs[j] += z[j]; cq[j] += z[j] * z[j];
      }
      float4 o0 = make_float4(z[0], z[1], z[2], z[3]);
      float4 o1 = make_float4(z[4], z[5], z[6], z[7]);
      *(float4*)&z1[(size_t)row * D2 + col0 + tx * 8] = o0;
      *(float4*)&z1[(size_t)row * D2 + col0 + tx * 8 + 4] = o1;
    }
  }
  // wave reduce over the 4 ty values in this wave (lanes xor 16, 32)
#pragma unroll
  for (int j = 0; j < 8; ++j) {
    float v = cs[j], w = cq[j];
    v += __shfl_xor(v, 16); v += __shfl_xor(v, 32);
    w += __shfl_xor(w, 16); w += __shfl_xor(w, 32);
    if ((tid & 48) == 0) {
      atomicAdd(&stat1[col0 + tx * 8 + j], v);
      atomicAdd(&stat1[D2 + col0 + tx * 8 + j], w);
    }
  }
}

// ---------------------------------------------------------------- GEMM2: h = relu(BN(z1)) @ W2 + b2 (+h) ; BN stats of h
// BM=64 BN=128 BK=32, 256 thr, 4x8 micro-tile. A in LDS K-major (pad 68).
__global__ __launch_bounds__(256) void k_gemm2(
    const float* __restrict__ z1, const float* __restrict__ stat1,
    const float* __restrict__ g1, const float* __restrict__ bt1,
    const float* __restrict__ W2, const float* __restrict__ b2,
    float* __restrict__ h, int residual, float* __restrict__ statH) {
  __shared__ float As[32 * 68];
  __shared__ float Bs[32 * 128];
  int tid = threadIdx.x;
  int row0 = blockIdx.x * 64;
  int tx = tid & 15, ty = tid >> 4;
  const float invN = 1.0f / (float)N_NODES;
  float acc[4][8];
#pragma unroll
  for (int i = 0; i < 4; ++i)
#pragma unroll
    for (int j = 0; j < 8; ++j) acc[i][j] = 0.f;

  int mrow = tid >> 3;            // 0..31
  int mk   = (tid & 7) << 2;      // 0..28

  for (int k0 = 0; k0 < D2; k0 += 32) {
    // stage A: 64 rows x 32 k of relu(BN(z1))
    float4 sv  = *(const float4*)&stat1[k0 + mk];
    float4 sqv = *(const float4*)&stat1[D2 + k0 + mk];
    float4 gv  = *(const float4*)&g1[k0 + mk];
    float4 bv  = *(const float4*)&bt1[k0 + mk];
    float mu0 = sv.x * invN, isg0 = rsqrtf(sqv.x * invN - mu0 * mu0 + BN_EPS_F) * gv.x;
    float mu1 = sv.y * invN, isg1 = rsqrtf(sqv.y * invN - mu1 * mu1 + BN_EPS_F) * gv.y;
    float mu2 = sv.z * invN, isg2 = rsqrtf(sqv.z * invN - mu2 * mu2 + BN_EPS_F) * gv.z;
    float mu3 = sv.w * invN, isg3 = rsqrtf(sqv.w * invN - mu3 * mu3 + BN_EPS_F) * gv.w;
#pragma unroll
    for (int p = 0; p < 2; ++p) {
      int rr = p * 32 + mrow;
      int row = row0 + rr;
      float4 a = make_float4(0.f, 0.f, 0.f, 0.f);
      if (row < N_NODES) {
        float4 z = *(const float4*)&z1[(size_t)row * D2 + k0 + mk];
        a.x = fmaxf((z.x - mu0) * isg0 + bv.x, 0.f);
        a.y = fmaxf((z.y - mu1) * isg1 + bv.y, 0.f);
        a.z = fmaxf((z.z - mu2) * isg2 + bv.z, 0.f);
        a.w = fmaxf((z.w - mu3) * isg3 + bv.w, 0.f);
      }
      As[(mk + 0) * 68 + rr] = a.x;
      As[(mk + 1) * 68 + rr] = a.y;
      As[(mk + 2) * 68 + rr] = a.z;
      As[(mk + 3) * 68 + rr] = a.w;
    }
    // stage B: 32 k-rows x 128 cols
#pragma unroll
    for (int p = 0; p < 4; ++p) {
      int li = p * 1024 + tid * 4;
      int kk = li >> 7, cc = li & 127;
      *(float4*)&Bs[kk * 128 + cc] =
          *(const float4*)&W2[(size_t)(k0 + kk) * D + cc];
    }
    __syncthreads();
#pragma unroll 4
    for (int kk = 0; kk < 32; ++kk) {
      float4 a0 = *(const float4*)&As[kk * 68 + ty * 4];
      float4 b0 = *(const float4*)&Bs[kk * 128 + tx * 8];
      float4 b1v = *(const float4*)&Bs[kk * 128 + tx * 8 + 4];
      float a[4] = {a0.x, a0.y, a0.z, a0.w};
      float b[8] = {b0.x, b0.y, b0.z, b0.w, b1v.x, b1v.y, b1v.z, b1v.w};
#pragma unroll
      for (int i = 0; i < 4; ++i)
#pragma unroll
        for (int j = 0; j < 8; ++j) acc[i][j] += a[i] * b[j];
    }
    __syncthreads();
  }
  // epilogue
  float4 bb0 = *(const float4*)&b2[tx * 8];
  float4 bb1 = *(const float4*)&b2[tx * 8 + 4];
  float bsc[8] = {bb0.x, bb0.y, bb0.z, bb0.w, bb1.x, bb1.y, bb1.z, bb1.w};
  float cs[8], cq[8];
#pragma unroll
  for (int j = 0; j < 8; ++j) { cs[j] = 0.f; cq[j] = 0.f; }
#pragma unroll
  for (int i = 0; i < 4; ++i) {
    int row = row0 + ty * 4 + i;
    if (row < N_NODES) {
      float v[8];
#pragma unroll
      for (int j = 0; j < 8; ++j) v[j] = acc[i][j] + bsc[j];
      if (residual) {
        float4 h0 = *(const float4*)&h[(size_t)row * D + tx * 8];
        float4 h1 = *(const float4*)&h[(size_t)row * D + tx * 8 + 4];
        v[0] += h0.x; v[1] += h0.y; v[2] += h0.z; v[3] += h0.w;
        v[4] += h1.x; v[5] += h1.y; v[6] += h1.z; v[7] += h1.w;
      }
#pragma unroll
      for (int j = 0; j < 8; ++j) { cs[j] += v[j]; cq[j] += v[j] * v[j]; }
      *(float4*)&h[(size_t)row * D + tx * 8] = make_float4(v[0], v[1], v[2], v[3]);
      *(float4*)&h[(size_t)row * D + tx * 8 + 4] = make_float4(v[4], v[5], v[6], v[7]);
    }
  }
#pragma unroll
  for (int j = 0; j < 8; ++j) {
    float v = cs[j], w = cq[j];
    v += __shfl_xor(v, 16); v += __shfl_xor(v, 32);
    w += __shfl_xor(w, 16); w += __shfl_xor(w, 32);
    if ((tid & 48) == 0) {
      atomicAdd(&statH[tx * 8 + j], v);
      atomicAdd(&statH[D + tx * 8 + j], w);
    }
  }
}

// ---------------------------------------------------------------- pool
__global__ __launch_bounds__(256) void k_pool(
    const float* __restrict__ h, const float* __restrict__ statH,
    const float* __restrict__ gamma, const float* __restrict__ beta,
    const int* __restrict__ batch, float* __restrict__ psum,
    float* __restrict__ pcnt) {
  int tid = blockIdx.x * 256 + threadIdx.x;
  int n = tid >> 5, f4 = (tid & 31) << 2;
  if (n >= N_NODES) return;
  const float invN = 1.0f / (float)N_NODES;
  int b = batch[n];
  float4 s  = *(const float4*)&statH[f4];
  float4 sq = *(const float4*)&statH[D + f4];
  float4 g  = *(const float4*)&gamma[f4];
  float4 bt = *(const float4*)&beta[f4];
  float4 hv = *(const float4*)&h[(size_t)n * D + f4];
  float4 o;
  float mu = s.x * invN, var = sq.x * invN - mu * mu;
  o.x = (hv.x - mu) * rsqrtf(var + BN_EPS_F) * g.x + bt.x;
  mu = s.y * invN; var = sq.y * invN - mu * mu;
  o.y = (hv.y - mu) * rsqrtf(var + BN_EPS_F) * g.y + bt.y;
  mu = s.z * invN; var = sq.z * invN - mu * mu;
  o.z = (hv.z - mu) * rsqrtf(var + BN_EPS_F) * g.z + bt.z;
  mu = s.w * invN; var = sq.w * invN - mu * mu;
  o.w = (hv.w - mu) * rsqrtf(var + BN_EPS_F) * g.w + bt.w;
  float* pp = psum + (size_t)b * D + f4;
  atomicAdd(pp + 0, o.x); atomicAdd(pp + 1, o.y);
  atomicAdd(pp + 2, o.z); atomicAdd(pp + 3, o.w);
  if ((tid & 31) == 0) atomicAdd(&pcnt[b], 1.0f);
}

// ---------------------------------------------------------------- predict
__global__ __launch_bounds__(64) void k_pred(
    const float* __restrict__ psum, const float* __restrict__ pcnt,
    const float* __restrict__ pw, const float* __restrict__ pb,
    float* __restrict__ out) {
  int b = blockIdx.x, t = threadIdx.x;
  if (t >= NTARGET) return;
  float inv = 1.0f / fmaxf(pcnt[b], 1.0f);
  float acc = pb[t];
  for (int k = 0; k < D; ++k)
    acc += psum[(size_t)b * D + k] * inv * pw[k * NTARGET + t];
  out[b * NTARGET + t] = acc;
}

// ---------------------------------------------------------------- launch
extern "C" void kernel_launch(void* const* d_in, const int* in_sizes, int n_in,
                              void* d_out, int out_size, void* d_ws, size_t ws_size,
                              hipStream_t stream) {
  const int* x      = (const int*)d_in[0];
  const int* ei     = (const int*)d_in[1];
  const int* eattr  = (const int*)d_in[2];
  const int* batch  = (const int*)d_in[3];
  const int* aoff   = (const int*)d_in[4];
  const int* boff   = (const int*)d_in[5];
  const float* atab = (const float*)d_in[6];
  const float* btab = (const float*)d_in[7];
  const float* ngam = (const float*)d_in[8];
  const float* nbet = (const float*)d_in[9];
  const float* tptr = (const float*)d_in[10];
  const float* w1   = (const float*)d_in[11];
  const float* b1   = (const float*)d_in[12];
  const float* bng  = (const float*)d_in[13];
  const float* bnb  = (const float*)d_in[14];
  const float* w2   = (const float*)d_in[15];
  const float* b2   = (const float*)d_in[16];
  const float* pw   = (const float*)d_in[17];
  const float* pb   = (const float*)d_in[18];
  float* out = (float*)d_out;

  float* ws = (float*)d_ws;
  const size_t ND = (size_t)N_NODES * D;
  float* h    = ws;
  float* r    = ws + 1 * ND;
  float* aggr = ws + 2 * ND;
  float* z1   = ws + 3 * ND;                  // 2*ND floats
  float* stat1 = ws + 5 * ND;                 // 512
  float* statH = stat1 + 512;                 // 256
  float* psum  = statH + 256;                 // 512*128
  float* pcnt  = psum + (size_t)NGRAPH * D;   // 512
  float* combo = pcnt + NGRAPH;               // 60*128
  int* ibuf    = (int*)(combo + 60 * D);
  int* rowptr  = ibuf;
  int* cursor  = rowptr + N_NODES + 1;
  int* deg     = cursor + N_NODES;
  int* payload = deg + N_NODES;

  const int nodeBlocks = (N_NODES * 32 + 255) / 256;
  const int edgeThreadBlocks = (N_EDGES + 255) / 256;
  const int g1Rows = (N_NODES + 127) / 128;   // 391
  const int g2Rows = (N_NODES + 63) / 64;     // 782

  hipMemsetAsync(deg, 0, N_NODES * sizeof(int), stream);
  k_encode<<<nodeBlocks, 256, 0, stream>>>(x, aoff, atab, h);
  k_combo<<<60, 128, 0, stream>>>(boff, btab, combo);
  k_degree<<<edgeThreadBlocks, 256, 0, stream>>>(ei, deg);
  k_scan<<<1, 1024, 0, stream>>>(deg, rowptr, cursor);
  k_scatter<<<edgeThreadBlocks, 256, 0, stream>>>(ei, eattr, cursor, payload);

  for (int l = 0; l < 7; ++l) {
    const float* rin = h;
    if (l > 0) {
      k_prenorm<<<nodeBlocks, 256, 0, stream>>>(h, statH, ngam + l * D, nbet + l * D, r);
      rin = r;
    }
    hipMemsetAsync(stat1, 0, 768 * sizeof(float), stream);
    k_aggr<<<nodeBlocks, 256, 0, stream>>>(rin, rowptr, payload, combo, tptr, l, aggr);
    k_gemm1<<<dim3(g1Rows, 2), 256, 0, stream>>>(rin, aggr, w1 + (size_t)l * D * D2,
                                                 b1 + l * D2, z1, stat1);
    k_gemm2<<<g2Rows, 256, 0, stream>>>(z1, stat1, bng + l * D2, bnb + l * D2,
                                        w2 + (size_t)l * D2 * D, b2 + l * D,
                                        h, l > 0 ? 1 : 0, statH);
  }

  hipMemsetAsync(psum, 0, ((size_t)NGRAPH * D + NGRAPH) * sizeof(float), stream);
  k_pool<<<nodeBlocks, 256, 0, stream>>>(h, statH, ngam, nbet, batch, psum, pcnt);
  k_pred<<<NGRAPH, 64, 0, stream>>>(psum, pcnt, pw, pb, out);
}

// Round 4
// 2107.366 us; speedup vs baseline: 15.6480x; 3.9471x over previous
//
#include <hip/hip_runtime.h>
#include <hip/hip_bf16.h>

#define N_NODES 50000
#define N_EDGES 600000
#define D 128
#define D2 256
#define NGRAPH 512
#define NTARGET 10

static constexpr float MSG_EPS_F = 1e-7f;
static constexpr float BN_EPS_F  = 1e-5f;

typedef _Float16 half8 __attribute__((ext_vector_type(8)));
typedef float f32x4 __attribute__((ext_vector_type(4)));
#define MFMA16(a, b, c) __builtin_amdgcn_mfma_f32_16x16x32_f16(a, b, c, 0, 0, 0)

// ---------------------------------------------------------------- encoders
__global__ __launch_bounds__(256) void k_encode(
    const int* __restrict__ x, const int* __restrict__ aoff,
    const float* __restrict__ atab, float* __restrict__ h) {
  int tid = blockIdx.x * 256 + threadIdx.x;
  int n = tid >> 5, f4 = (tid & 31) << 2;
  if (n >= N_NODES) return;
  float4 acc = make_float4(0.f, 0.f, 0.f, 0.f);
#pragma unroll
  for (int i = 0; i < 9; ++i) {
    int row = x[n * 9 + i] + aoff[i];
    float4 v = *(const float4*)&atab[row * D + f4];
    acc.x += v.x; acc.y += v.y; acc.z += v.z; acc.w += v.w;
  }
  *(float4*)&h[n * D + f4] = acc;
}

// ---------------------------------------------------------------- combo table
__global__ __launch_bounds__(128) void k_combo(
    const int* __restrict__ boff, const float* __restrict__ btab,
    float* __restrict__ combo) {
  int c = blockIdx.x, t = threadIdx.x;
  int a0 = c / 12, a1 = (c % 12) / 2, a2 = c % 2;
  combo[c * D + t] = btab[(boff[0] + a0) * D + t] +
                     btab[(boff[1] + a1) * D + t] +
                     btab[(boff[2] + a2) * D + t];
}

// ---------------------------------------------------------------- CSR build
__global__ __launch_bounds__(256) void k_degree(
    const int* __restrict__ ei, int* __restrict__ deg) {
  int e = blockIdx.x * 256 + threadIdx.x;
  if (e >= N_EDGES) return;
  atomicAdd(&deg[ei[N_EDGES + e]], 1);
}

__global__ __launch_bounds__(1024) void k_scan(
    const int* __restrict__ deg, int* __restrict__ rowptr,
    int* __restrict__ cursor) {
  __shared__ int tmp[1024];
  __shared__ int carryS;
  int t = threadIdx.x;
  if (t == 0) carryS = 0;
  __syncthreads();
  for (int base = 0; base < N_NODES; base += 1024) {
    int i = base + t;
    int v = (i < N_NODES) ? deg[i] : 0;
    tmp[t] = v;
    __syncthreads();
    for (int off = 1; off < 1024; off <<= 1) {
      int add = (t >= off) ? tmp[t - off] : 0;
      __syncthreads();
      tmp[t] += add;
      __syncthreads();
    }
    int carry = carryS;
    if (i < N_NODES) {
      int excl = carry + tmp[t] - v;
      rowptr[i] = excl;
      cursor[i] = excl;
    }
    __syncthreads();
    if (t == 1023) carryS = carry + tmp[1023];
    __syncthreads();
  }
  if (t == 0) rowptr[N_NODES] = carryS;
}

__global__ __launch_bounds__(256) void k_scatter(
    const int* __restrict__ ei, const int* __restrict__ eattr,
    int* __restrict__ cursor, int* __restrict__ payload) {
  int e = blockIdx.x * 256 + threadIdx.x;
  if (e >= N_EDGES) return;
  int src = ei[e], dst = ei[N_EDGES + e];
  int cid = eattr[e * 3 + 0] * 12 + eattr[e * 3 + 1] * 2 + eattr[e * 3 + 2];
  int pos = atomicAdd(&cursor[dst], 1);
  payload[pos] = (src << 6) | cid;
}

// ---------------------------------------------------------------- pre-norm: r = relu(BN(h))
__global__ __launch_bounds__(256) void k_prenorm(
    const float* __restrict__ h, const float* __restrict__ statH,
    const float* __restrict__ gamma, const float* __restrict__ beta,
    float* __restrict__ r) {
  int tid = blockIdx.x * 256 + threadIdx.x;
  int n = tid >> 5, f4 = (tid & 31) << 2;
  if (n >= N_NODES) return;
  const float invN = 1.0f / (float)N_NODES;
  float4 s  = *(const float4*)&statH[f4];
  float4 sq = *(const float4*)&statH[D + f4];
  float4 g  = *(const float4*)&gamma[f4];
  float4 b  = *(const float4*)&beta[f4];
  float4 hv = *(const float4*)&h[(size_t)n * D + f4];
  float4 o;
  float mu = s.x * invN, var = sq.x * invN - mu * mu;
  o.x = fmaxf((hv.x - mu) * rsqrtf(var + BN_EPS_F) * g.x + b.x, 0.f);
  mu = s.y * invN; var = sq.y * invN - mu * mu;
  o.y = fmaxf((hv.y - mu) * rsqrtf(var + BN_EPS_F) * g.y + b.y, 0.f);
  mu = s.z * invN; var = sq.z * invN - mu * mu;
  o.z = fmaxf((hv.z - mu) * rsqrtf(var + BN_EPS_F) * g.z + b.z, 0.f);
  mu = s.w * invN; var = sq.w * invN - mu * mu;
  o.w = fmaxf((hv.w - mu) * rsqrtf(var + BN_EPS_F) * g.w + b.w, 0.f);
  *(float4*)&r[(size_t)n * D + f4] = o;
}

// ---------------------------------------------------------------- CSR softmax aggregation
__global__ __launch_bounds__(256) void k_aggr(
    const float* __restrict__ r, const int* __restrict__ rowptr,
    const int* __restrict__ payload, const float* __restrict__ combo,
    const float* __restrict__ tptr, int l, float* __restrict__ aggr) {
  int tid = blockIdx.x * 256 + threadIdx.x;
  int dst = tid >> 5, f4 = (tid & 31) << 2;
  if (dst >= N_NODES) return;
  float tv = tptr[l];
  int s = rowptr[dst], e = rowptr[dst + 1];
  float4 den = make_float4(0.f, 0.f, 0.f, 0.f);
  float4 S = make_float4(0.f, 0.f, 0.f, 0.f);
  for (int i = s; i < e; ++i) {
    int p = payload[i];
    int src = p >> 6, cid = p & 63;
    float4 rv = *(const float4*)&r[(size_t)src * D + f4];
    float4 cv = *(const float4*)&combo[cid * D + f4];
    float mx = fmaxf(rv.x + cv.x, 0.f) + MSG_EPS_F;
    float my = fmaxf(rv.y + cv.y, 0.f) + MSG_EPS_F;
    float mz = fmaxf(rv.z + cv.z, 0.f) + MSG_EPS_F;
    float mw = fmaxf(rv.w + cv.w, 0.f) + MSG_EPS_F;
    float ex = __expf(mx * tv), ey = __expf(my * tv);
    float ez = __expf(mz * tv), ew = __expf(mw * tv);
    den.x += ex; den.y += ey; den.z += ez; den.w += ew;
    S.x += mx * ex; S.y += my * ey; S.z += mz * ez; S.w += mw * ew;
  }
  float4 o;
  o.x = S.x / (den.x + 1e-16f);
  o.y = S.y / (den.y + 1e-16f);
  o.z = S.z / (den.z + 1e-16f);
  o.w = S.w / (den.w + 1e-16f);
  *(float4*)&aggr[(size_t)dst * D + f4] = o;
}

// ---------------------------------------------------------------- GEMM1 (MFMA fp16): z1h = fp16((r+aggr) @ W1 + b1); stats of z1
// BM=64, BN=128, K=128 fully staged. 4 waves: 2(M)x2(N); wave tile 32x64.
// Frag-contiguous LDS: Af[kc][mt][lane]*16B, Bf[kc][nt][lane]*16B.
__global__ __launch_bounds__(256) void k_gemm1(
    const float* __restrict__ r, const float* __restrict__ aggr,
    const float* __restrict__ W1, const float* __restrict__ b1,
    _Float16* __restrict__ z1h, float* __restrict__ stat1) {
  __shared__ __align__(16) _Float16 Af[1024 * 8];   // 16 KB
  __shared__ __align__(16) _Float16 Bf[2048 * 8];   // 32 KB
  int tid = threadIdx.x;
  int row0 = blockIdx.x * 64;
  int col0 = blockIdx.y * 128;

  // stage A fragments: slot s = (kc*4+mt)*64+lane
#pragma unroll
  for (int s0 = 0; s0 < 4; ++s0) {
    int s = s0 * 256 + tid;
    int kc = s >> 8, mt = (s >> 6) & 3, l2 = s & 63;
    int row = row0 + mt * 16 + (l2 & 15);
    int kb = kc * 32 + ((l2 >> 4) << 3);
    half8 v;
    if (row < N_NODES) {
      const float* rp = &r[(size_t)row * D + kb];
      const float* ap = &aggr[(size_t)row * D + kb];
      float4 r0 = *(const float4*)rp, r1 = *(const float4*)(rp + 4);
      float4 a0 = *(const float4*)ap, a1 = *(const float4*)(ap + 4);
      v[0] = (_Float16)(r0.x + a0.x); v[1] = (_Float16)(r0.y + a0.y);
      v[2] = (_Float16)(r0.z + a0.z); v[3] = (_Float16)(r0.w + a0.w);
      v[4] = (_Float16)(r1.x + a1.x); v[5] = (_Float16)(r1.y + a1.y);
      v[6] = (_Float16)(r1.z + a1.z); v[7] = (_Float16)(r1.w + a1.w);
    } else {
#pragma unroll
      for (int j = 0; j < 8; ++j) v[j] = (_Float16)0.f;
    }
    *(half8*)&Af[s * 8] = v;
  }
  // stage B fragments: transpose W1[k][col0+c] into Bf[(kc*8+nt)*64 + q*16 + (c&15)][j]
#pragma unroll
  for (int it = 0; it < 16; ++it) {
    int li = it * 256 + tid;        // 4096 float4s
    int k = li >> 5;
    int c = (li & 31) << 2;
    float4 w = *(const float4*)&W1[(size_t)k * D2 + col0 + c];
    int kc = k >> 5, q = (k >> 3) & 3, j = k & 7;
    int nt = c >> 4;
    int base = ((kc * 8 + nt) * 64 + q * 16 + (c & 15)) * 8 + j;
    Bf[base] = (_Float16)w.x;
    Bf[base + 8] = (_Float16)w.y;
    Bf[base + 16] = (_Float16)w.z;
    Bf[base + 24] = (_Float16)w.w;
  }
  __syncthreads();

  int wv = tid >> 6, ln = tid & 63;
  int wm = wv & 1, wn = wv >> 1;
  f32x4 acc[2][4];
#pragma unroll
  for (int i = 0; i < 2; ++i)
#pragma unroll
    for (int j = 0; j < 4; ++j) acc[i][j] = (f32x4){0.f, 0.f, 0.f, 0.f};

#pragma unroll
  for (int kc = 0; kc < 4; ++kc) {
    half8 a0 = *(half8*)&Af[((kc * 4 + wm * 2 + 0) * 64 + ln) * 8];
    half8 a1 = *(half8*)&Af[((kc * 4 + wm * 2 + 1) * 64 + ln) * 8];
#pragma unroll
    for (int nt = 0; nt < 4; ++nt) {
      half8 b = *(half8*)&Bf[((kc * 8 + wn * 4 + nt) * 64 + ln) * 8];
      acc[0][nt] = MFMA16(a0, b, acc[0][nt]);
      acc[1][nt] = MFMA16(a1, b, acc[1][nt]);
    }
  }
  // epilogue: C/D layout col=lane&15, row=(lane>>4)*4+reg
  int lq = ln >> 4, lc = ln & 15;
  float cs[4], cq[4];
#pragma unroll
  for (int nt = 0; nt < 4; ++nt) { cs[nt] = 0.f; cq[nt] = 0.f; }
#pragma unroll
  for (int nt = 0; nt < 4; ++nt) {
    int col = col0 + (wn * 4 + nt) * 16 + lc;
    float bias = b1[col];
#pragma unroll
    for (int mt = 0; mt < 2; ++mt) {
      int rbase = row0 + (wm * 2 + mt) * 16 + lq * 4;
#pragma unroll
      for (int rg = 0; rg < 4; ++rg) {
        int row = rbase + rg;
        if (row < N_NODES) {
          float z = acc[mt][nt][rg] + bias;
          z1h[(size_t)row * D2 + col] = (_Float16)z;
          cs[nt] += z; cq[nt] += z * z;
        }
      }
    }
  }
#pragma unroll
  for (int nt = 0; nt < 4; ++nt) {
    float v = cs[nt], q = cq[nt];
    v += __shfl_xor(v, 16); v += __shfl_xor(v, 32);
    q += __shfl_xor(q, 16); q += __shfl_xor(q, 32);
    if (lq == 0) {
      int col = col0 + (wn * 4 + nt) * 16 + lc;
      atomicAdd(&stat1[col], v);
      atomicAdd(&stat1[D2 + col], q);
    }
  }
}

// ---------------------------------------------------------------- GEMM2 (MFMA fp16): h = relu(BN(z1)) @ W2 + b2 (+h); stats of h
// BM=64, BN=128, BK=64 (4 k-tiles). Same wave layout as gemm1.
__global__ __launch_bounds__(256) void k_gemm2(
    const _Float16* __restrict__ z1h, const float* __restrict__ stat1,
    const float* __restrict__ g1, const float* __restrict__ bt1,
    const float* __restrict__ W2, const float* __restrict__ b2,
    float* __restrict__ h, int residual, float* __restrict__ statH) {
  __shared__ __align__(16) _Float16 Af[512 * 8];    // 8 KB
  __shared__ __align__(16) _Float16 Bf[1024 * 8];   // 16 KB
  const float invN = 1.0f / (float)N_NODES;
  int tid = threadIdx.x;
  int row0 = blockIdx.x * 64;
  int wv = tid >> 6, ln = tid & 63;
  int wm = wv & 1, wn = wv >> 1;
  f32x4 acc[2][4];
#pragma unroll
  for (int i = 0; i < 2; ++i)
#pragma unroll
    for (int j = 0; j < 4; ++j) acc[i][j] = (f32x4){0.f, 0.f, 0.f, 0.f};

  for (int kt = 0; kt < 4; ++kt) {
    // stage A: relu(BN(z1)) fragments, slot s = (kc*4+mt)*64+lane
#pragma unroll
    for (int s0 = 0; s0 < 2; ++s0) {
      int s = s0 * 256 + tid;
      int kc = s >> 8, mt = (s >> 6) & 3, l2 = s & 63;
      int row = row0 + mt * 16 + (l2 & 15);
      int kb = kt * 64 + kc * 32 + ((l2 >> 4) << 3);
      float sm[8], sq[8], gg[8], bb[8];
      *(float4*)&sm[0] = *(const float4*)&stat1[kb];
      *(float4*)&sm[4] = *(const float4*)&stat1[kb + 4];
      *(float4*)&sq[0] = *(const float4*)&stat1[D2 + kb];
      *(float4*)&sq[4] = *(const float4*)&stat1[D2 + kb + 4];
      *(float4*)&gg[0] = *(const float4*)&g1[kb];
      *(float4*)&gg[4] = *(const float4*)&g1[kb + 4];
      *(float4*)&bb[0] = *(const float4*)&bt1[kb];
      *(float4*)&bb[4] = *(const float4*)&bt1[kb + 4];
      half8 v;
      if (row < N_NODES) {
        half8 z = *(const half8*)&z1h[(size_t)row * D2 + kb];
#pragma unroll
        for (int j = 0; j < 8; ++j) {
          float mu = sm[j] * invN;
          float isg = rsqrtf(sq[j] * invN - mu * mu + BN_EPS_F) * gg[j];
          v[j] = (_Float16)fmaxf(((float)z[j] - mu) * isg + bb[j], 0.f);
        }
      } else {
#pragma unroll
        for (int j = 0; j < 8; ++j) v[j] = (_Float16)0.f;
      }
      *(half8*)&Af[s * 8] = v;
    }
    // stage B: W2 rows kt*64..+63 x 128 cols
#pragma unroll
    for (int it = 0; it < 8; ++it) {
      int li = it * 256 + tid;     // 2048 float4s
      int k = li >> 5;             // 0..63
      int c = (li & 31) << 2;
      float4 w = *(const float4*)&W2[(size_t)(kt * 64 + k) * D + c];
      int kc = k >> 5, q = (k >> 3) & 3, j = k & 7;
      int nt = c >> 4;
      int base = ((kc * 8 + nt) * 64 + q * 16 + (c & 15)) * 8 + j;
      Bf[base] = (_Float16)w.x;
      Bf[base + 8] = (_Float16)w.y;
      Bf[base + 16] = (_Float16)w.z;
      Bf[base + 24] = (_Float16)w.w;
    }
    __syncthreads();
#pragma unroll
    for (int kc = 0; kc < 2; ++kc) {
      half8 a0 = *(half8*)&Af[((kc * 4 + wm * 2 + 0) * 64 + ln) * 8];
      half8 a1 = *(half8*)&Af[((kc * 4 + wm * 2 + 1) * 64 + ln) * 8];
#pragma unroll
      for (int nt = 0; nt < 4; ++nt) {
        half8 b = *(half8*)&Bf[((kc * 8 + wn * 4 + nt) * 64 + ln) * 8];
        acc[0][nt] = MFMA16(a0, b, acc[0][nt]);
        acc[1][nt] = MFMA16(a1, b, acc[1][nt]);
      }
    }
    __syncthreads();
  }
  // epilogue
  int lq = ln >> 4, lc = ln & 15;
  float cs[4], cq[4];
#pragma unroll
  for (int nt = 0; nt < 4; ++nt) { cs[nt] = 0.f; cq[nt] = 0.f; }
#pragma unroll
  for (int nt = 0; nt < 4; ++nt) {
    int col = (wn * 4 + nt) * 16 + lc;
    float bias = b2[col];
#pragma unroll
    for (int mt = 0; mt < 2; ++mt) {
      int rbase = row0 + (wm * 2 + mt) * 16 + lq * 4;
#pragma unroll
      for (int rg = 0; rg < 4; ++rg) {
        int row = rbase + rg;
        if (row < N_NODES) {
          float v = acc[mt][nt][rg] + bias;
          if (residual) v += h[(size_t)row * D + col];
          h[(size_t)row * D + col] = v;
          cs[nt] += v; cq[nt] += v * v;
        }
      }
    }
  }
#pragma unroll
  for (int nt = 0; nt < 4; ++nt) {
    float v = cs[nt], q = cq[nt];
    v += __shfl_xor(v, 16); v += __shfl_xor(v, 32);
    q += __shfl_xor(q, 16); q += __shfl_xor(q, 32);
    if (lq == 0) {
      int col = (wn * 4 + nt) * 16 + lc;
      atomicAdd(&statH[col], v);
      atomicAdd(&statH[D + col], q);
    }
  }
}

// ---------------------------------------------------------------- pool
__global__ __launch_bounds__(256) void k_pool(
    const float* __restrict__ h, const float* __restrict__ statH,
    const float* __restrict__ gamma, const float* __restrict__ beta,
    const int* __restrict__ batch, float* __restrict__ psum,
    float* __restrict__ pcnt) {
  int tid = blockIdx.x * 256 + threadIdx.x;
  int n = tid >> 5, f4 = (tid & 31) << 2;
  if (n >= N_NODES) return;
  const float invN = 1.0f / (float)N_NODES;
  int b = batch[n];
  float4 s  = *(const float4*)&statH[f4];
  float4 sq = *(const float4*)&statH[D + f4];
  float4 g  = *(const float4*)&gamma[f4];
  float4 bt = *(const float4*)&beta[f4];
  float4 hv = *(const float4*)&h[(size_t)n * D + f4];
  float4 o;
  float mu = s.x * invN, var = sq.x * invN - mu * mu;
  o.x = (hv.x - mu) * rsqrtf(var + BN_EPS_F) * g.x + bt.x;
  mu = s.y * invN; var = sq.y * invN - mu * mu;
  o.y = (hv.y - mu) * rsqrtf(var + BN_EPS_F) * g.y + bt.y;
  mu = s.z * invN; var = sq.z * invN - mu * mu;
  o.z = (hv.z - mu) * rsqrtf(var + BN_EPS_F) * g.z + bt.z;
  mu = s.w * invN; var = sq.w * invN - mu * mu;
  o.w = (hv.w - mu) * rsqrtf(var + BN_EPS_F) * g.w + bt.w;
  float* pp = psum + (size_t)b * D + f4;
  atomicAdd(pp + 0, o.x); atomicAdd(pp + 1, o.y);
  atomicAdd(pp + 2, o.z); atomicAdd(pp + 3, o.w);
  if ((tid & 31) == 0) atomicAdd(&pcnt[b], 1.0f);
}

// ---------------------------------------------------------------- predict
__global__ __launch_bounds__(64) void k_pred(
    const float* __restrict__ psum, const float* __restrict__ pcnt,
    const float* __restrict__ pw, const float* __restrict__ pb,
    float* __restrict__ out) {
  int b = blockIdx.x, t = threadIdx.x;
  if (t >= NTARGET) return;
  float inv = 1.0f / fmaxf(pcnt[b], 1.0f);
  float acc = pb[t];
  for (int k = 0; k < D; ++k)
    acc += psum[(size_t)b * D + k] * inv * pw[k * NTARGET + t];
  out[b * NTARGET + t] = acc;
}

// ---------------------------------------------------------------- launch
extern "C" void kernel_launch(void* const* d_in, const int* in_sizes, int n_in,
                              void* d_out, int out_size, void* d_ws, size_t ws_size,
                              hipStream_t stream) {
  const int* x      = (const int*)d_in[0];
  const int* ei     = (const int*)d_in[1];
  const int* eattr  = (const int*)d_in[2];
  const int* batch  = (const int*)d_in[3];
  const int* aoff   = (const int*)d_in[4];
  const int* boff   = (const int*)d_in[5];
  const float* atab = (const float*)d_in[6];
  const float* btab = (const float*)d_in[7];
  const float* ngam = (const float*)d_in[8];
  const float* nbet = (const float*)d_in[9];
  const float* tptr = (const float*)d_in[10];
  const float* w1   = (const float*)d_in[11];
  const float* b1   = (const float*)d_in[12];
  const float* bng  = (const float*)d_in[13];
  const float* bnb  = (const float*)d_in[14];
  const float* w2   = (const float*)d_in[15];
  const float* b2   = (const float*)d_in[16];
  const float* pw   = (const float*)d_in[17];
  const float* pb   = (const float*)d_in[18];
  float* out = (float*)d_out;

  float* ws = (float*)d_ws;
  const size_t ND = (size_t)N_NODES * D;
  float* h    = ws;
  float* r    = ws + 1 * ND;
  float* aggr = ws + 2 * ND;
  _Float16* z1h = (_Float16*)(ws + 3 * ND);   // N*256 halfs = ND floats
  float* stat1 = ws + 4 * ND;                 // 512
  float* statH = stat1 + 512;                 // 256
  float* psum  = statH + 256;                 // 512*128
  float* pcnt  = psum + (size_t)NGRAPH * D;   // 512
  float* combo = pcnt + NGRAPH;               // 60*128
  int* ibuf    = (int*)(combo + 60 * D);
  int* rowptr  = ibuf;
  int* cursor  = rowptr + N_NODES + 1;
  int* deg     = cursor + N_NODES;
  int* payload = deg + N_NODES;

  const int nodeBlocks = (N_NODES * 32 + 255) / 256;
  const int edgeThreadBlocks = (N_EDGES + 255) / 256;
  const int gRows = (N_NODES + 63) / 64;      // 782

  hipMemsetAsync(deg, 0, N_NODES * sizeof(int), stream);
  k_encode<<<nodeBlocks, 256, 0, stream>>>(x, aoff, atab, h);
  k_combo<<<60, 128, 0, stream>>>(boff, btab, combo);
  k_degree<<<edgeThreadBlocks, 256, 0, stream>>>(ei, deg);
  k_scan<<<1, 1024, 0, stream>>>(deg, rowptr, cursor);
  k_scatter<<<edgeThreadBlocks, 256, 0, stream>>>(ei, eattr, cursor, payload);

  for (int l = 0; l < 7; ++l) {
    const float* rin = h;
    if (l > 0) {
      k_prenorm<<<nodeBlocks, 256, 0, stream>>>(h, statH, ngam + l * D, nbet + l * D, r);
      rin = r;
    }
    hipMemsetAsync(stat1, 0, 768 * sizeof(float), stream);
    k_aggr<<<nodeBlocks, 256, 0, stream>>>(rin, rowptr, payload, combo, tptr, l, aggr);
    k_gemm1<<<dim3(gRows, 2), 256, 0, stream>>>(rin, aggr, w1 + (size_t)l * D * D2,
                                                b1 + l * D2, z1h, stat1);
    k_gemm2<<<gRows, 256, 0, stream>>>(z1h, stat1, bng + l * D2, bnb + l * D2,
                                       w2 + (size_t)l * D2 * D, b2 + l * D,
                                       h, l > 0 ? 1 : 0, statH);
  }

  hipMemsetAsync(psum, 0, ((size_t)NGRAPH * D + NGRAPH) * sizeof(float), stream);
  k_pool<<<nodeBlocks, 256, 0, stream>>>(h, statH, ngam, nbet, batch, psum, pcnt);
  k_pred<<<NGRAPH, 64, 0, stream>>>(psum, pcnt, pw, pb, out);
}

// Round 5
// 1790.321 us; speedup vs baseline: 18.4191x; 1.1771x over previous
//
#include <hip/hip_runtime.h>
#include <hip/hip_bf16.h>

#define N_NODES 50000
#define N_EDGES 600000
#define D 128
#define D2 256
#define NGRAPH 512
#define NTARGET 10

static constexpr float MSG_EPS_F = 1e-7f;
static constexpr float BN_EPS_F  = 1e-5f;

typedef _Float16 half8 __attribute__((ext_vector_type(8)));
typedef _Float16 half4v __attribute__((ext_vector_type(4)));
typedef float f32x4 __attribute__((ext_vector_type(4)));
#define MFMA16(a, b, c) __builtin_amdgcn_mfma_f32_16x16x32_f16(a, b, c, 0, 0, 0)

// ---------------------------------------------------------------- encoder: h fp32 + rh fp16
__global__ __launch_bounds__(256) void k_encode(
    const int* __restrict__ x, const int* __restrict__ aoff,
    const float* __restrict__ atab, float* __restrict__ h,
    _Float16* __restrict__ rh) {
  int tid = blockIdx.x * 256 + threadIdx.x;
  int n = tid >> 5, f4 = (tid & 31) << 2;
  if (n >= N_NODES) return;
  float4 acc = make_float4(0.f, 0.f, 0.f, 0.f);
#pragma unroll
  for (int i = 0; i < 9; ++i) {
    int row = x[n * 9 + i] + aoff[i];
    float4 v = *(const float4*)&atab[row * D + f4];
    acc.x += v.x; acc.y += v.y; acc.z += v.z; acc.w += v.w;
  }
  *(float4*)&h[(size_t)n * D + f4] = acc;
  half4v o = {(_Float16)acc.x, (_Float16)acc.y, (_Float16)acc.z, (_Float16)acc.w};
  *(half4v*)&rh[(size_t)n * D + f4] = o;
}

// ---------------------------------------------------------------- combo table
__global__ __launch_bounds__(128) void k_combo(
    const int* __restrict__ boff, const float* __restrict__ btab,
    float* __restrict__ combo) {
  int c = blockIdx.x, t = threadIdx.x;
  int a0 = c / 12, a1 = (c % 12) / 2, a2 = c % 2;
  combo[c * D + t] = btab[(boff[0] + a0) * D + t] +
                     btab[(boff[1] + a1) * D + t] +
                     btab[(boff[2] + a2) * D + t];
}

// ---------------------------------------------------------------- CSR build
__global__ __launch_bounds__(256) void k_degree(
    const int* __restrict__ ei, int* __restrict__ deg) {
  int e = blockIdx.x * 256 + threadIdx.x;
  if (e >= N_EDGES) return;
  atomicAdd(&deg[ei[N_EDGES + e]], 1);
}

__global__ __launch_bounds__(1024) void k_scan(
    const int* __restrict__ deg, int* __restrict__ rowptr,
    int* __restrict__ cursor) {
  __shared__ int tmp[1024];
  __shared__ int carryS;
  int t = threadIdx.x;
  if (t == 0) carryS = 0;
  __syncthreads();
  for (int base = 0; base < N_NODES; base += 1024) {
    int i = base + t;
    int v = (i < N_NODES) ? deg[i] : 0;
    tmp[t] = v;
    __syncthreads();
    for (int off = 1; off < 1024; off <<= 1) {
      int add = (t >= off) ? tmp[t - off] : 0;
      __syncthreads();
      tmp[t] += add;
      __syncthreads();
    }
    int carry = carryS;
    if (i < N_NODES) {
      int excl = carry + tmp[t] - v;
      rowptr[i] = excl;
      cursor[i] = excl;
    }
    __syncthreads();
    if (t == 1023) carryS = carry + tmp[1023];
    __syncthreads();
  }
  if (t == 0) rowptr[N_NODES] = carryS;
}

__global__ __launch_bounds__(256) void k_scatter(
    const int* __restrict__ ei, const int* __restrict__ eattr,
    int* __restrict__ cursor, int* __restrict__ payload) {
  int e = blockIdx.x * 256 + threadIdx.x;
  if (e >= N_EDGES) return;
  int src = ei[e], dst = ei[N_EDGES + e];
  int cid = eattr[e * 3 + 0] * 12 + eattr[e * 3 + 1] * 2 + eattr[e * 3 + 2];
  int pos = atomicAdd(&cursor[dst], 1);
  payload[pos] = (src << 6) | cid;
}

// ---------------------------------------------------------------- graph bounds from sorted batch
__global__ __launch_bounds__(256) void k_gbounds(
    const int* __restrict__ batch, int* __restrict__ gstart) {
  int n = blockIdx.x * 256 + threadIdx.x;
  if (n >= N_NODES) return;
  int b0 = batch[n];
  int b1 = (n + 1 < N_NODES) ? batch[n + 1] : NGRAPH;
  for (int bb = b0 + 1; bb <= b1; ++bb) gstart[bb] = n + 1;
  if (n == 0)
    for (int bb = 0; bb <= b0; ++bb) gstart[bb] = 0;
}

// ---------------------------------------------------------------- pre-norm: rh = fp16(relu(BN(h)))
__global__ __launch_bounds__(256) void k_prenorm(
    const float* __restrict__ h, const float* __restrict__ statH,
    const float* __restrict__ gamma, const float* __restrict__ beta,
    _Float16* __restrict__ rh) {
  int tid = blockIdx.x * 256 + threadIdx.x;
  int n = tid >> 5, f4 = (tid & 31) << 2;
  if (n >= N_NODES) return;
  const float invN = 1.0f / (float)N_NODES;
  float4 s  = *(const float4*)&statH[f4];
  float4 sq = *(const float4*)&statH[D + f4];
  float4 g  = *(const float4*)&gamma[f4];
  float4 b  = *(const float4*)&beta[f4];
  float4 hv = *(const float4*)&h[(size_t)n * D + f4];
  float mu = s.x * invN, var = sq.x * invN - mu * mu;
  float ox = fmaxf((hv.x - mu) * rsqrtf(var + BN_EPS_F) * g.x + b.x, 0.f);
  mu = s.y * invN; var = sq.y * invN - mu * mu;
  float oy = fmaxf((hv.y - mu) * rsqrtf(var + BN_EPS_F) * g.y + b.y, 0.f);
  mu = s.z * invN; var = sq.z * invN - mu * mu;
  float oz = fmaxf((hv.z - mu) * rsqrtf(var + BN_EPS_F) * g.z + b.z, 0.f);
  mu = s.w * invN; var = sq.w * invN - mu * mu;
  float ow = fmaxf((hv.w - mu) * rsqrtf(var + BN_EPS_F) * g.w + b.w, 0.f);
  half4v o = {(_Float16)ox, (_Float16)oy, (_Float16)oz, (_Float16)ow};
  *(half4v*)&rh[(size_t)n * D + f4] = o;
}

// ---------------------------------------------------------------- CSR softmax aggregation (fp16 gather)
__global__ __launch_bounds__(256) void k_aggr(
    const _Float16* __restrict__ rh, const int* __restrict__ rowptr,
    const int* __restrict__ payload, const float* __restrict__ combo,
    const float* __restrict__ tptr, int l, _Float16* __restrict__ aggrh) {
  int tid = blockIdx.x * 256 + threadIdx.x;
  int dst = tid >> 5, f4 = (tid & 31) << 2;
  if (dst >= N_NODES) return;
  float tv = tptr[l];
  int s = rowptr[dst], e = rowptr[dst + 1];
  float4 den = make_float4(0.f, 0.f, 0.f, 0.f);
  float4 S = make_float4(0.f, 0.f, 0.f, 0.f);
  int i = s;
  for (; i + 1 < e; i += 2) {
    int p0 = payload[i], p1 = payload[i + 1];
    half4v r0 = *(const half4v*)&rh[(size_t)(p0 >> 6) * D + f4];
    half4v r1 = *(const half4v*)&rh[(size_t)(p1 >> 6) * D + f4];
    const float* c0 = &combo[(p0 & 63) * D + f4];
    const float* c1 = &combo[(p1 & 63) * D + f4];
    float4 cv0 = *(const float4*)c0;
    float4 cv1 = *(const float4*)c1;
    float m0x = fmaxf((float)r0[0] + cv0.x, 0.f) + MSG_EPS_F;
    float m0y = fmaxf((float)r0[1] + cv0.y, 0.f) + MSG_EPS_F;
    float m0z = fmaxf((float)r0[2] + cv0.z, 0.f) + MSG_EPS_F;
    float m0w = fmaxf((float)r0[3] + cv0.w, 0.f) + MSG_EPS_F;
    float m1x = fmaxf((float)r1[0] + cv1.x, 0.f) + MSG_EPS_F;
    float m1y = fmaxf((float)r1[1] + cv1.y, 0.f) + MSG_EPS_F;
    float m1z = fmaxf((float)r1[2] + cv1.z, 0.f) + MSG_EPS_F;
    float m1w = fmaxf((float)r1[3] + cv1.w, 0.f) + MSG_EPS_F;
    float e0x = __expf(m0x * tv), e0y = __expf(m0y * tv);
    float e0z = __expf(m0z * tv), e0w = __expf(m0w * tv);
    float e1x = __expf(m1x * tv), e1y = __expf(m1y * tv);
    float e1z = __expf(m1z * tv), e1w = __expf(m1w * tv);
    den.x += e0x + e1x; den.y += e0y + e1y;
    den.z += e0z + e1z; den.w += e0w + e1w;
    S.x += m0x * e0x + m1x * e1x; S.y += m0y * e0y + m1y * e1y;
    S.z += m0z * e0z + m1z * e1z; S.w += m0w * e0w + m1w * e1w;
  }
  if (i < e) {
    int p0 = payload[i];
    half4v r0 = *(const half4v*)&rh[(size_t)(p0 >> 6) * D + f4];
    float4 cv0 = *(const float4*)&combo[(p0 & 63) * D + f4];
    float m0x = fmaxf((float)r0[0] + cv0.x, 0.f) + MSG_EPS_F;
    float m0y = fmaxf((float)r0[1] + cv0.y, 0.f) + MSG_EPS_F;
    float m0z = fmaxf((float)r0[2] + cv0.z, 0.f) + MSG_EPS_F;
    float m0w = fmaxf((float)r0[3] + cv0.w, 0.f) + MSG_EPS_F;
    float e0x = __expf(m0x * tv), e0y = __expf(m0y * tv);
    float e0z = __expf(m0z * tv), e0w = __expf(m0w * tv);
    den.x += e0x; den.y += e0y; den.z += e0z; den.w += e0w;
    S.x += m0x * e0x; S.y += m0y * e0y; S.z += m0z * e0z; S.w += m0w * e0w;
  }
  half4v o;
  o[0] = (_Float16)(S.x / (den.x + 1e-16f));
  o[1] = (_Float16)(S.y / (den.y + 1e-16f));
  o[2] = (_Float16)(S.z / (den.z + 1e-16f));
  o[3] = (_Float16)(S.w / (den.w + 1e-16f));
  *(half4v*)&aggrh[(size_t)dst * D + f4] = o;
}

// ---------------------------------------------------------------- GEMM1 (MFMA fp16): z1h = fp16((rh+aggrh) @ W1 + b1); stats of z1
// BM=64, BN=128, K=128 fully staged. 4 waves: 2(M)x2(N).
__global__ __launch_bounds__(256) void k_gemm1(
    const _Float16* __restrict__ rh, const _Float16* __restrict__ aggrh,
    const float* __restrict__ W1, const float* __restrict__ b1,
    _Float16* __restrict__ z1h, float* __restrict__ stat1) {
  __shared__ __align__(16) _Float16 Af[1024 * 8];   // 16 KB
  __shared__ __align__(16) _Float16 Bf[2048 * 8];   // 32 KB
  int tid = threadIdx.x;
  int row0 = blockIdx.x * 64;
  int col0 = blockIdx.y * 128;

  // stage A fragments: slot s = (kc*4+mt)*64+lane
#pragma unroll
  for (int s0 = 0; s0 < 4; ++s0) {
    int s = s0 * 256 + tid;
    int kc = s >> 8, mt = (s >> 6) & 3, l2 = s & 63;
    int row = row0 + mt * 16 + (l2 & 15);
    int kb = kc * 32 + ((l2 >> 4) << 3);
    half8 v;
    if (row < N_NODES) {
      half8 rv = *(const half8*)&rh[(size_t)row * D + kb];
      half8 av = *(const half8*)&aggrh[(size_t)row * D + kb];
      v = rv + av;
    } else {
#pragma unroll
      for (int j = 0; j < 8; ++j) v[j] = (_Float16)0.f;
    }
    *(half8*)&Af[s * 8] = v;
  }
  // stage B fragments
#pragma unroll
  for (int it = 0; it < 16; ++it) {
    int li = it * 256 + tid;
    int k = li >> 5;
    int c = (li & 31) << 2;
    float4 w = *(const float4*)&W1[(size_t)k * D2 + col0 + c];
    int kc = k >> 5, q = (k >> 3) & 3, j = k & 7;
    int nt = c >> 4;
    int base = ((kc * 8 + nt) * 64 + q * 16 + (c & 15)) * 8 + j;
    Bf[base] = (_Float16)w.x;
    Bf[base + 8] = (_Float16)w.y;
    Bf[base + 16] = (_Float16)w.z;
    Bf[base + 24] = (_Float16)w.w;
  }
  __syncthreads();

  int wv = tid >> 6, ln = tid & 63;
  int wm = wv & 1, wn = wv >> 1;
  f32x4 acc[2][4];
#pragma unroll
  for (int i = 0; i < 2; ++i)
#pragma unroll
    for (int j = 0; j < 4; ++j) acc[i][j] = (f32x4){0.f, 0.f, 0.f, 0.f};

#pragma unroll
  for (int kc = 0; kc < 4; ++kc) {
    half8 a0 = *(half8*)&Af[((kc * 4 + wm * 2 + 0) * 64 + ln) * 8];
    half8 a1 = *(half8*)&Af[((kc * 4 + wm * 2 + 1) * 64 + ln) * 8];
#pragma unroll
    for (int nt = 0; nt < 4; ++nt) {
      half8 b = *(half8*)&Bf[((kc * 8 + wn * 4 + nt) * 64 + ln) * 8];
      acc[0][nt] = MFMA16(a0, b, acc[0][nt]);
      acc[1][nt] = MFMA16(a1, b, acc[1][nt]);
    }
  }
  int lq = ln >> 4, lc = ln & 15;
  float cs[4], cq[4];
#pragma unroll
  for (int nt = 0; nt < 4; ++nt) { cs[nt] = 0.f; cq[nt] = 0.f; }
#pragma unroll
  for (int nt = 0; nt < 4; ++nt) {
    int col = col0 + (wn * 4 + nt) * 16 + lc;
    float bias = b1[col];
#pragma unroll
    for (int mt = 0; mt < 2; ++mt) {
      int rbase = row0 + (wm * 2 + mt) * 16 + lq * 4;
#pragma unroll
      for (int rg = 0; rg < 4; ++rg) {
        int row = rbase + rg;
        if (row < N_NODES) {
          float z = acc[mt][nt][rg] + bias;
          z1h[(size_t)row * D2 + col] = (_Float16)z;
          cs[nt] += z; cq[nt] += z * z;
        }
      }
    }
  }
#pragma unroll
  for (int nt = 0; nt < 4; ++nt) {
    float v = cs[nt], q = cq[nt];
    v += __shfl_xor(v, 16); v += __shfl_xor(v, 32);
    q += __shfl_xor(q, 16); q += __shfl_xor(q, 32);
    if (lq == 0) {
      int col = col0 + (wn * 4 + nt) * 16 + lc;
      atomicAdd(&stat1[col], v);
      atomicAdd(&stat1[D2 + col], q);
    }
  }
}

// ---------------------------------------------------------------- GEMM2 (MFMA fp16): h = relu(BN(z1)) @ W2 + b2 (+h); stats of h
__global__ __launch_bounds__(256) void k_gemm2(
    const _Float16* __restrict__ z1h, const float* __restrict__ stat1,
    const float* __restrict__ g1, const float* __restrict__ bt1,
    const float* __restrict__ W2, const float* __restrict__ b2,
    float* __restrict__ h, int residual, float* __restrict__ statH) {
  __shared__ __align__(16) _Float16 Af[512 * 8];    // 8 KB
  __shared__ __align__(16) _Float16 Bf[1024 * 8];   // 16 KB
  const float invN = 1.0f / (float)N_NODES;
  int tid = threadIdx.x;
  int row0 = blockIdx.x * 64;
  int wv = tid >> 6, ln = tid & 63;
  int wm = wv & 1, wn = wv >> 1;
  f32x4 acc[2][4];
#pragma unroll
  for (int i = 0; i < 2; ++i)
#pragma unroll
    for (int j = 0; j < 4; ++j) acc[i][j] = (f32x4){0.f, 0.f, 0.f, 0.f};

  for (int kt = 0; kt < 4; ++kt) {
#pragma unroll
    for (int s0 = 0; s0 < 2; ++s0) {
      int s = s0 * 256 + tid;
      int kc = s >> 8, mt = (s >> 6) & 3, l2 = s & 63;
      int row = row0 + mt * 16 + (l2 & 15);
      int kb = kt * 64 + kc * 32 + ((l2 >> 4) << 3);
      float sm[8], sq[8], gg[8], bb[8];
      *(float4*)&sm[0] = *(const float4*)&stat1[kb];
      *(float4*)&sm[4] = *(const float4*)&stat1[kb + 4];
      *(float4*)&sq[0] = *(const float4*)&stat1[D2 + kb];
      *(float4*)&sq[4] = *(const float4*)&stat1[D2 + kb + 4];
      *(float4*)&gg[0] = *(const float4*)&g1[kb];
      *(float4*)&gg[4] = *(const float4*)&g1[kb + 4];
      *(float4*)&bb[0] = *(const float4*)&bt1[kb];
      *(float4*)&bb[4] = *(const float4*)&bt1[kb + 4];
      half8 v;
      if (row < N_NODES) {
        half8 z = *(const half8*)&z1h[(size_t)row * D2 + kb];
#pragma unroll
        for (int j = 0; j < 8; ++j) {
          float mu = sm[j] * invN;
          float isg = rsqrtf(sq[j] * invN - mu * mu + BN_EPS_F) * gg[j];
          v[j] = (_Float16)fmaxf(((float)z[j] - mu) * isg + bb[j], 0.f);
        }
      } else {
#pragma unroll
        for (int j = 0; j < 8; ++j) v[j] = (_Float16)0.f;
      }
      *(half8*)&Af[s * 8] = v;
    }
#pragma unroll
    for (int it = 0; it < 8; ++it) {
      int li = it * 256 + tid;
      int k = li >> 5;
      int c = (li & 31) << 2;
      float4 w = *(const float4*)&W2[(size_t)(kt * 64 + k) * D + c];
      int kc = k >> 5, q = (k >> 3) & 3, j = k & 7;
      int nt = c >> 4;
      int base = ((kc * 8 + nt) * 64 + q * 16 + (c & 15)) * 8 + j;
      Bf[base] = (_Float16)w.x;
      Bf[base + 8] = (_Float16)w.y;
      Bf[base + 16] = (_Float16)w.z;
      Bf[base + 24] = (_Float16)w.w;
    }
    __syncthreads();
#pragma unroll
    for (int kc = 0; kc < 2; ++kc) {
      half8 a0 = *(half8*)&Af[((kc * 4 + wm * 2 + 0) * 64 + ln) * 8];
      half8 a1 = *(half8*)&Af[((kc * 4 + wm * 2 + 1) * 64 + ln) * 8];
#pragma unroll
      for (int nt = 0; nt < 4; ++nt) {
        half8 b = *(half8*)&Bf[((kc * 8 + wn * 4 + nt) * 64 + ln) * 8];
        acc[0][nt] = MFMA16(a0, b, acc[0][nt]);
        acc[1][nt] = MFMA16(a1, b, acc[1][nt]);
      }
    }
    __syncthreads();
  }
  int lq = ln >> 4, lc = ln & 15;
  float cs[4], cq[4];
#pragma unroll
  for (int nt = 0; nt < 4; ++nt) { cs[nt] = 0.f; cq[nt] = 0.f; }
#pragma unroll
  for (int nt = 0; nt < 4; ++nt) {
    int col = (wn * 4 + nt) * 16 + lc;
    float bias = b2[col];
#pragma unroll
    for (int mt = 0; mt < 2; ++mt) {
      int rbase = row0 + (wm * 2 + mt) * 16 + lq * 4;
#pragma unroll
      for (int rg = 0; rg < 4; ++rg) {
        int row = rbase + rg;
        if (row < N_NODES) {
          float v = acc[mt][nt][rg] + bias;
          if (residual) v += h[(size_t)row * D + col];
          h[(size_t)row * D + col] = v;
          cs[nt] += v; cq[nt] += v * v;
        }
      }
    }
  }
#pragma unroll
  for (int nt = 0; nt < 4; ++nt) {
    float v = cs[nt], q = cq[nt];
    v += __shfl_xor(v, 16); v += __shfl_xor(v, 32);
    q += __shfl_xor(q, 16); q += __shfl_xor(q, 32);
    if (lq == 0) {
      int col = (wn * 4 + nt) * 16 + lc;
      atomicAdd(&statH[col], v);
      atomicAdd(&statH[D + col], q);
    }
  }
}

// ---------------------------------------------------------------- pool: segment-sum raw h per graph (no atomics)
__global__ __launch_bounds__(256) void k_pool(
    const float* __restrict__ h, const int* __restrict__ gstart,
    float* __restrict__ psum) {
  __shared__ float4 red[256];
  int b = blockIdx.x, tid = threadIdx.x;
  int fl = (tid & 31) << 2, ns = tid >> 5;
  int gs = gstart[b], ge = gstart[b + 1];
  float4 acc = make_float4(0.f, 0.f, 0.f, 0.f);
  for (int n = gs + ns; n < ge; n += 8) {
    float4 v = *(const float4*)&h[(size_t)n * D + fl];
    acc.x += v.x; acc.y += v.y; acc.z += v.z; acc.w += v.w;
  }
  red[tid] = acc;
  __syncthreads();
  if (ns < 4) {
    float4 o = red[tid + 128];
    acc.x += o.x; acc.y += o.y; acc.z += o.z; acc.w += o.w;
    red[tid] = acc;
  }
  __syncthreads();
  if (ns < 2) {
    float4 o = red[tid + 64];
    acc.x += o.x; acc.y += o.y; acc.z += o.z; acc.w += o.w;
    red[tid] = acc;
  }
  __syncthreads();
  if (ns == 0) {
    float4 o = red[tid + 32];
    acc.x += o.x; acc.y += o.y; acc.z += o.z; acc.w += o.w;
    *(float4*)&psum[(size_t)b * D + fl] = acc;
  }
}

// ---------------------------------------------------------------- predict: affine-BN + linear head
__global__ __launch_bounds__(64) void k_pred(
    const float* __restrict__ psum, const int* __restrict__ gstart,
    const float* __restrict__ statH, const float* __restrict__ gamma,
    const float* __restrict__ beta, const float* __restrict__ pw,
    const float* __restrict__ pb, float* __restrict__ out) {
  int b = blockIdx.x, t = threadIdx.x;
  if (t >= NTARGET) return;
  int gs = gstart[b], ge = gstart[b + 1];
  float acc = pb[t];
  if (ge > gs) {
    const float invN = 1.0f / (float)N_NODES;
    float inv = 1.0f / (float)(ge - gs);
    for (int k = 0; k < D; ++k) {
      float mu = statH[k] * invN;
      float var = statH[D + k] * invN - mu * mu;
      float emb = (psum[(size_t)b * D + k] * inv - mu) * rsqrtf(var + BN_EPS_F) * gamma[k] + beta[k];
      acc += emb * pw[k * NTARGET + t];
    }
  }
  out[b * NTARGET + t] = acc;
}

// ---------------------------------------------------------------- launch
extern "C" void kernel_launch(void* const* d_in, const int* in_sizes, int n_in,
                              void* d_out, int out_size, void* d_ws, size_t ws_size,
                              hipStream_t stream) {
  const int* x      = (const int*)d_in[0];
  const int* ei     = (const int*)d_in[1];
  const int* eattr  = (const int*)d_in[2];
  const int* batch  = (const int*)d_in[3];
  const int* aoff   = (const int*)d_in[4];
  const int* boff   = (const int*)d_in[5];
  const float* atab = (const float*)d_in[6];
  const float* btab = (const float*)d_in[7];
  const float* ngam = (const float*)d_in[8];
  const float* nbet = (const float*)d_in[9];
  const float* tptr = (const float*)d_in[10];
  const float* w1   = (const float*)d_in[11];
  const float* b1   = (const float*)d_in[12];
  const float* bng  = (const float*)d_in[13];
  const float* bnb  = (const float*)d_in[14];
  const float* w2   = (const float*)d_in[15];
  const float* b2   = (const float*)d_in[16];
  const float* pw   = (const float*)d_in[17];
  const float* pb   = (const float*)d_in[18];
  float* out = (float*)d_out;

  float* ws = (float*)d_ws;
  const size_t ND = (size_t)N_NODES * D;
  float* h      = ws;                          // ND fp32
  _Float16* rh  = (_Float16*)(ws + 1 * ND);    // ND halfs = ND/2 floats
  _Float16* aggrh = (_Float16*)(ws + 1 * ND + ND / 2);
  _Float16* z1h = (_Float16*)(ws + 2 * ND);    // N*D2 halfs = ND floats
  float* stat1  = ws + 3 * ND;                 // 512
  float* statH  = stat1 + 512;                 // 256
  float* psum   = statH + 256;                 // 512*128
  float* combo  = psum + (size_t)NGRAPH * D;   // 60*128
  int* ibuf     = (int*)(combo + 60 * D);
  int* rowptr   = ibuf;                        // N+1
  int* cursor   = rowptr + N_NODES + 1;        // N
  int* deg      = cursor + N_NODES;            // N
  int* payload  = deg + N_NODES;               // E
  int* gstart   = payload + N_EDGES;           // NGRAPH+1

  const int nodeBlocks = (N_NODES * 32 + 255) / 256;
  const int edgeThreadBlocks = (N_EDGES + 255) / 256;
  const int nBlocks256 = (N_NODES + 255) / 256;
  const int gRows = (N_NODES + 63) / 64;       // 782

  hipMemsetAsync(deg, 0, N_NODES * sizeof(int), stream);
  k_encode<<<nodeBlocks, 256, 0, stream>>>(x, aoff, atab, h, rh);
  k_combo<<<60, 128, 0, stream>>>(boff, btab, combo);
  k_degree<<<edgeThreadBlocks, 256, 0, stream>>>(ei, deg);
  k_gbounds<<<nBlocks256, 256, 0, stream>>>(batch, gstart);
  k_scan<<<1, 1024, 0, stream>>>(deg, rowptr, cursor);
  k_scatter<<<edgeThreadBlocks, 256, 0, stream>>>(ei, eattr, cursor, payload);

  for (int l = 0; l < 7; ++l) {
    if (l > 0)
      k_prenorm<<<nodeBlocks, 256, 0, stream>>>(h, statH, ngam + l * D, nbet + l * D, rh);
    hipMemsetAsync(stat1, 0, 768 * sizeof(float), stream);
    k_aggr<<<nodeBlocks, 256, 0, stream>>>(rh, rowptr, payload, combo, tptr, l, aggrh);
    k_gemm1<<<dim3(gRows, 2), 256, 0, stream>>>(rh, aggrh, w1 + (size_t)l * D * D2,
                                                b1 + l * D2, z1h, stat1);
    k_gemm2<<<gRows, 256, 0, stream>>>(z1h, stat1, bng + l * D2, bnb + l * D2,
                                       w2 + (size_t)l * D2 * D, b2 + l * D,
                                       h, l > 0 ? 1 : 0, statH);
  }

  k_pool<<<NGRAPH, 256, 0, stream>>>(h, gstart, psum);
  k_pred<<<NGRAPH, 64, 0, stream>>>(psum, gstart, statH, ngam, nbet, pw, pb, out);
}

// Round 6
// 1447.542 us; speedup vs baseline: 22.7808x; 1.2368x over previous
//
#include <hip/hip_runtime.h>
#include <hip/hip_bf16.h>

#define N_NODES 50000
#define N_EDGES 600000
#define D 128
#define D2 256
#define NGRAPH 512
#define NTARGET 10
#define NSB 49  // scan blocks: ceil(50000/1024)

static constexpr float MSG_EPS_F = 1e-7f;
static constexpr float BN_EPS_F  = 1e-5f;

typedef _Float16 half8 __attribute__((ext_vector_type(8)));
typedef _Float16 half4v __attribute__((ext_vector_type(4)));
typedef float f32x4 __attribute__((ext_vector_type(4)));
#define MFMA16(a, b, c) __builtin_amdgcn_mfma_f32_16x16x32_f16(a, b, c, 0, 0, 0)

// ---------------------------------------------------------------- encoder: h fp32 + rh fp16 (+ zero deg)
__global__ __launch_bounds__(256) void k_encode(
    const int* __restrict__ x, const int* __restrict__ aoff,
    const float* __restrict__ atab, float* __restrict__ h,
    _Float16* __restrict__ rh, int* __restrict__ deg) {
  int tid = blockIdx.x * 256 + threadIdx.x;
  if (tid < N_NODES) deg[tid] = 0;
  int n = tid >> 5, f4 = (tid & 31) << 2;
  if (n >= N_NODES) return;
  float4 acc = make_float4(0.f, 0.f, 0.f, 0.f);
#pragma unroll
  for (int i = 0; i < 9; ++i) {
    int row = x[n * 9 + i] + aoff[i];
    float4 v = *(const float4*)&atab[row * D + f4];
    acc.x += v.x; acc.y += v.y; acc.z += v.z; acc.w += v.w;
  }
  *(float4*)&h[(size_t)n * D + f4] = acc;
  half4v o = {(_Float16)acc.x, (_Float16)acc.y, (_Float16)acc.z, (_Float16)acc.w};
  *(half4v*)&rh[(size_t)n * D + f4] = o;
}

// ---------------------------------------------------------------- combo table
__global__ __launch_bounds__(128) void k_combo(
    const int* __restrict__ boff, const float* __restrict__ btab,
    float* __restrict__ combo) {
  int c = blockIdx.x, t = threadIdx.x;
  int a0 = c / 12, a1 = (c % 12) / 2, a2 = c % 2;
  combo[c * D + t] = btab[(boff[0] + a0) * D + t] +
                     btab[(boff[1] + a1) * D + t] +
                     btab[(boff[2] + a2) * D + t];
}

// ---------------------------------------------------------------- weight pre-pack: fp32 -> fp16 MFMA-fragment order
// w1p[l]: frag f = ((kc*16 + ntAll)*64 + lane), kc in [0,4) (K=128), ntAll in [0,16) (256 cols)
// w2p[l]: frag f = ((kcAll*8 + nt)*64 + lane), kcAll in [0,8) (K=256), nt in [0,8) (128 cols)
// lane = q*16 + (col&15), element j in [0,8): k = kc*32 + q*8 + j
__global__ __launch_bounds__(256) void k_packW(
    const float* __restrict__ w1, const float* __restrict__ w2,
    _Float16* __restrict__ w1p, _Float16* __restrict__ w2p) {
  int t = blockIdx.x * 256 + threadIdx.x;
  if (t < 7 * 4096) {
    int lane = t & 63, ntAll = (t >> 6) & 15, kc = (t >> 10) & 3, l = t >> 12;
    int q = lane >> 4, c = ntAll * 16 + (lane & 15);
    int kbase = kc * 32 + q * 8;
    const float* W = w1 + (size_t)l * D * D2;
    half8 v;
#pragma unroll
    for (int j = 0; j < 8; ++j) v[j] = (_Float16)W[(size_t)(kbase + j) * D2 + c];
    *(half8*)&w1p[(size_t)t * 8] = v;
  } else {
    int u = t - 7 * 4096;
    if (u < 7 * 4096) {
      int lane = u & 63, nt = (u >> 6) & 7, kcAll = (u >> 9) & 7, l = u >> 12;
      int q = lane >> 4, c = nt * 16 + (lane & 15);
      int kbase = kcAll * 32 + q * 8;
      const float* W = w2 + (size_t)l * D2 * D;
      half8 v;
#pragma unroll
      for (int j = 0; j < 8; ++j) v[j] = (_Float16)W[(size_t)(kbase + j) * D + c];
      *(half8*)&w2p[(size_t)u * 8] = v;
    }
  }
}

// ---------------------------------------------------------------- CSR build
__global__ __launch_bounds__(256) void k_degree(
    const int* __restrict__ ei, int* __restrict__ deg) {
  int e = blockIdx.x * 256 + threadIdx.x;
  if (e >= N_EDGES) return;
  atomicAdd(&deg[ei[N_EDGES + e]], 1);
}

// 3-phase parallel scan
__global__ __launch_bounds__(1024) void k_scan1(
    const int* __restrict__ deg, int* __restrict__ excl, int* __restrict__ bsum) {
  __shared__ int tmp[1024];
  int t = threadIdx.x, i = blockIdx.x * 1024 + t;
  int v = (i < N_NODES) ? deg[i] : 0;
  tmp[t] = v;
  __syncthreads();
  for (int off = 1; off < 1024; off <<= 1) {
    int add = (t >= off) ? tmp[t - off] : 0;
    __syncthreads();
    tmp[t] += add;
    __syncthreads();
  }
  if (i < N_NODES) excl[i] = tmp[t] - v;
  if (t == 1023) bsum[blockIdx.x] = tmp[1023];
}

__global__ __launch_bounds__(64) void k_scan2(int* __restrict__ bsum) {
  __shared__ int s[64];
  int t = threadIdx.x;
  int v = (t < NSB) ? bsum[t] : 0;
  s[t] = v;
  __syncthreads();
  for (int off = 1; off < 64; off <<= 1) {
    int add = (t >= off) ? s[t - off] : 0;
    __syncthreads();
    s[t] += add;
    __syncthreads();
  }
  if (t < NSB) bsum[t] = s[t] - v;  // exclusive block offsets
}

__global__ __launch_bounds__(256) void k_scan3(
    const int* __restrict__ excl, const int* __restrict__ bsum,
    int* __restrict__ rowptr, int* __restrict__ cursor) {
  int i = blockIdx.x * 256 + threadIdx.x;
  if (i < N_NODES) {
    int v = excl[i] + bsum[i >> 10];
    rowptr[i] = v;
    cursor[i] = v;
  }
  if (i == N_NODES) rowptr[N_NODES] = N_EDGES;
}

__global__ __launch_bounds__(256) void k_scatter(
    const int* __restrict__ ei, const int* __restrict__ eattr,
    int* __restrict__ cursor, int* __restrict__ payload) {
  int e = blockIdx.x * 256 + threadIdx.x;
  if (e >= N_EDGES) return;
  int src = ei[e], dst = ei[N_EDGES + e];
  int cid = eattr[e * 3 + 0] * 12 + eattr[e * 3 + 1] * 2 + eattr[e * 3 + 2];
  int pos = atomicAdd(&cursor[dst], 1);
  payload[pos] = (src << 6) | cid;
}

// ---------------------------------------------------------------- graph bounds from sorted batch
__global__ __launch_bounds__(256) void k_gbounds(
    const int* __restrict__ batch, int* __restrict__ gstart) {
  int n = blockIdx.x * 256 + threadIdx.x;
  if (n >= N_NODES) return;
  int b0 = batch[n];
  int b1 = (n + 1 < N_NODES) ? batch[n + 1] : NGRAPH;
  for (int bb = b0 + 1; bb <= b1; ++bb) gstart[bb] = n + 1;
  if (n == 0)
    for (int bb = 0; bb <= b0; ++bb) gstart[bb] = 0;
}

// ---------------------------------------------------------------- pre-norm: rh = fp16(relu(BN(h)))
__global__ __launch_bounds__(256) void k_prenorm(
    const float* __restrict__ h, const float* __restrict__ statH,
    const float* __restrict__ gamma, const float* __restrict__ beta,
    _Float16* __restrict__ rh) {
  int tid = blockIdx.x * 256 + threadIdx.x;
  int n = tid >> 5, f4 = (tid & 31) << 2;
  if (n >= N_NODES) return;
  const float invN = 1.0f / (float)N_NODES;
  float4 s  = *(const float4*)&statH[f4];
  float4 sq = *(const float4*)&statH[D + f4];
  float4 g  = *(const float4*)&gamma[f4];
  float4 b  = *(const float4*)&beta[f4];
  float4 hv = *(const float4*)&h[(size_t)n * D + f4];
  float mu = s.x * invN, var = sq.x * invN - mu * mu;
  float ox = fmaxf((hv.x - mu) * rsqrtf(var + BN_EPS_F) * g.x + b.x, 0.f);
  mu = s.y * invN; var = sq.y * invN - mu * mu;
  float oy = fmaxf((hv.y - mu) * rsqrtf(var + BN_EPS_F) * g.y + b.y, 0.f);
  mu = s.z * invN; var = sq.z * invN - mu * mu;
  float oz = fmaxf((hv.z - mu) * rsqrtf(var + BN_EPS_F) * g.z + b.z, 0.f);
  mu = s.w * invN; var = sq.w * invN - mu * mu;
  float ow = fmaxf((hv.w - mu) * rsqrtf(var + BN_EPS_F) * g.w + b.w, 0.f);
  half4v o = {(_Float16)ox, (_Float16)oy, (_Float16)oz, (_Float16)ow};
  *(half4v*)&rh[(size_t)n * D + f4] = o;
}

// ---------------------------------------------------------------- CSR softmax aggregation (fp16 gather) + stat zeroing
__global__ __launch_bounds__(256) void k_aggr(
    const _Float16* __restrict__ rh, const int* __restrict__ rowptr,
    const int* __restrict__ payload, const float* __restrict__ combo,
    const float* __restrict__ tptr, int l, _Float16* __restrict__ aggrh,
    float* __restrict__ statbuf) {
  if (blockIdx.x == 0) {
    for (int j = threadIdx.x; j < 768; j += 256) statbuf[j] = 0.f;
  }
  int tid = blockIdx.x * 256 + threadIdx.x;
  int dst = tid >> 5, f4 = (tid & 31) << 2;
  if (dst >= N_NODES) return;
  float tv = tptr[l];
  int s = rowptr[dst], e = rowptr[dst + 1];
  float4 den = make_float4(0.f, 0.f, 0.f, 0.f);
  float4 S = make_float4(0.f, 0.f, 0.f, 0.f);
  int i = s;
  for (; i + 1 < e; i += 2) {
    int p0 = payload[i], p1 = payload[i + 1];
    half4v r0 = *(const half4v*)&rh[(size_t)(p0 >> 6) * D + f4];
    half4v r1 = *(const half4v*)&rh[(size_t)(p1 >> 6) * D + f4];
    float4 cv0 = *(const float4*)&combo[(p0 & 63) * D + f4];
    float4 cv1 = *(const float4*)&combo[(p1 & 63) * D + f4];
    float m0x = fmaxf((float)r0[0] + cv0.x, 0.f) + MSG_EPS_F;
    float m0y = fmaxf((float)r0[1] + cv0.y, 0.f) + MSG_EPS_F;
    float m0z = fmaxf((float)r0[2] + cv0.z, 0.f) + MSG_EPS_F;
    float m0w = fmaxf((float)r0[3] + cv0.w, 0.f) + MSG_EPS_F;
    float m1x = fmaxf((float)r1[0] + cv1.x, 0.f) + MSG_EPS_F;
    float m1y = fmaxf((float)r1[1] + cv1.y, 0.f) + MSG_EPS_F;
    float m1z = fmaxf((float)r1[2] + cv1.z, 0.f) + MSG_EPS_F;
    float m1w = fmaxf((float)r1[3] + cv1.w, 0.f) + MSG_EPS_F;
    float e0x = __expf(m0x * tv), e0y = __expf(m0y * tv);
    float e0z = __expf(m0z * tv), e0w = __expf(m0w * tv);
    float e1x = __expf(m1x * tv), e1y = __expf(m1y * tv);
    float e1z = __expf(m1z * tv), e1w = __expf(m1w * tv);
    den.x += e0x + e1x; den.y += e0y + e1y;
    den.z += e0z + e1z; den.w += e0w + e1w;
    S.x += m0x * e0x + m1x * e1x; S.y += m0y * e0y + m1y * e1y;
    S.z += m0z * e0z + m1z * e1z; S.w += m0w * e0w + m1w * e1w;
  }
  if (i < e) {
    int p0 = payload[i];
    half4v r0 = *(const half4v*)&rh[(size_t)(p0 >> 6) * D + f4];
    float4 cv0 = *(const float4*)&combo[(p0 & 63) * D + f4];
    float m0x = fmaxf((float)r0[0] + cv0.x, 0.f) + MSG_EPS_F;
    float m0y = fmaxf((float)r0[1] + cv0.y, 0.f) + MSG_EPS_F;
    float m0z = fmaxf((float)r0[2] + cv0.z, 0.f) + MSG_EPS_F;
    float m0w = fmaxf((float)r0[3] + cv0.w, 0.f) + MSG_EPS_F;
    float e0x = __expf(m0x * tv), e0y = __expf(m0y * tv);
    float e0z = __expf(m0z * tv), e0w = __expf(m0w * tv);
    den.x += e0x; den.y += e0y; den.z += e0z; den.w += e0w;
    S.x += m0x * e0x; S.y += m0y * e0y; S.z += m0z * e0z; S.w += m0w * e0w;
  }
  half4v o;
  o[0] = (_Float16)(S.x / (den.x + 1e-16f));
  o[1] = (_Float16)(S.y / (den.y + 1e-16f));
  o[2] = (_Float16)(S.z / (den.z + 1e-16f));
  o[3] = (_Float16)(S.w / (den.w + 1e-16f));
  *(half4v*)&aggrh[(size_t)dst * D + f4] = o;
}

// ---------------------------------------------------------------- GEMM1 (MFMA fp16): z1h = fp16((rh+aggrh) @ W1 + b1); stats
// BM=64, BN=256 (full), K=128 staged once. 4 waves 2(M)x2(N); B direct from packed global.
__global__ __launch_bounds__(256) void k_gemm1(
    const _Float16* __restrict__ rh, const _Float16* __restrict__ aggrh,
    const _Float16* __restrict__ w1p, const float* __restrict__ b1,
    _Float16* __restrict__ z1h, float* __restrict__ stat1) {
  __shared__ __align__(16) _Float16 Af[1024 * 8];   // 16 KB
  int tid = threadIdx.x;
  int row0 = blockIdx.x * 64;

  // stage A fragments: slot s = (kc*4+mt)*64+lane
#pragma unroll
  for (int s0 = 0; s0 < 4; ++s0) {
    int s = s0 * 256 + tid;
    int kc = s >> 8, mt = (s >> 6) & 3, l2 = s & 63;
    int row = row0 + mt * 16 + (l2 & 15);
    int kb = kc * 32 + ((l2 >> 4) << 3);
    half8 v;
    if (row < N_NODES) {
      half8 rv = *(const half8*)&rh[(size_t)row * D + kb];
      half8 av = *(const half8*)&aggrh[(size_t)row * D + kb];
      v = rv + av;
    } else {
#pragma unroll
      for (int j = 0; j < 8; ++j) v[j] = (_Float16)0.f;
    }
    *(half8*)&Af[s * 8] = v;
  }
  __syncthreads();

  int wv = tid >> 6, ln = tid & 63;
  int wm = wv & 1, wn = wv >> 1;
  f32x4 acc[2][8];
#pragma unroll
  for (int i = 0; i < 2; ++i)
#pragma unroll
    for (int j = 0; j < 8; ++j) acc[i][j] = (f32x4){0.f, 0.f, 0.f, 0.f};

#pragma unroll
  for (int kc = 0; kc < 4; ++kc) {
    half8 a0 = *(half8*)&Af[((kc * 4 + wm * 2 + 0) * 64 + ln) * 8];
    half8 a1 = *(half8*)&Af[((kc * 4 + wm * 2 + 1) * 64 + ln) * 8];
#pragma unroll
    for (int nt = 0; nt < 8; ++nt) {
      half8 b = *(const half8*)&w1p[((size_t)(kc * 16 + wn * 8 + nt) * 64 + ln) * 8];
      acc[0][nt] = MFMA16(a0, b, acc[0][nt]);
      acc[1][nt] = MFMA16(a1, b, acc[1][nt]);
    }
  }
  int lq = ln >> 4, lc = ln & 15;
  float cs[8], cq[8];
#pragma unroll
  for (int nt = 0; nt < 8; ++nt) { cs[nt] = 0.f; cq[nt] = 0.f; }
#pragma unroll
  for (int nt = 0; nt < 8; ++nt) {
    int col = wn * 128 + nt * 16 + lc;
    float bias = b1[col];
#pragma unroll
    for (int mt = 0; mt < 2; ++mt) {
      int rbase = row0 + (wm * 2 + mt) * 16 + lq * 4;
#pragma unroll
      for (int rg = 0; rg < 4; ++rg) {
        int row = rbase + rg;
        if (row < N_NODES) {
          float z = acc[mt][nt][rg] + bias;
          z1h[(size_t)row * D2 + col] = (_Float16)z;
          cs[nt] += z; cq[nt] += z * z;
        }
      }
    }
  }
#pragma unroll
  for (int nt = 0; nt < 8; ++nt) {
    float v = cs[nt], q = cq[nt];
    v += __shfl_xor(v, 16); v += __shfl_xor(v, 32);
    q += __shfl_xor(q, 16); q += __shfl_xor(q, 32);
    if (lq == 0) {
      int col = wn * 128 + nt * 16 + lc;
      atomicAdd(&stat1[col], v);
      atomicAdd(&stat1[D2 + col], q);
    }
  }
}

// ---------------------------------------------------------------- GEMM2 (MFMA fp16): h = relu(BN(z1)) @ W2 + b2 (+h); stats
// BM=64, BN=128, BK=64 (4 k-tiles). B direct from packed global.
__global__ __launch_bounds__(256) void k_gemm2(
    const _Float16* __restrict__ z1h, const float* __restrict__ stat1,
    const float* __restrict__ g1, const float* __restrict__ bt1,
    const _Float16* __restrict__ w2p, const float* __restrict__ b2,
    float* __restrict__ h, int residual, float* __restrict__ statH) {
  __shared__ __align__(16) _Float16 Af[512 * 8];    // 8 KB
  const float invN = 1.0f / (float)N_NODES;
  int tid = threadIdx.x;
  int row0 = blockIdx.x * 64;
  int wv = tid >> 6, ln = tid & 63;
  int wm = wv & 1, wn = wv >> 1;
  f32x4 acc[2][4];
#pragma unroll
  for (int i = 0; i < 2; ++i)
#pragma unroll
    for (int j = 0; j < 4; ++j) acc[i][j] = (f32x4){0.f, 0.f, 0.f, 0.f};

  for (int kt = 0; kt < 4; ++kt) {
#pragma unroll
    for (int s0 = 0; s0 < 2; ++s0) {
      int s = s0 * 256 + tid;
      int kc = s >> 8, mt = (s >> 6) & 3, l2 = s & 63;
      int row = row0 + mt * 16 + (l2 & 15);
      int kb = kt * 64 + kc * 32 + ((l2 >> 4) << 3);
      float sm[8], sq[8], gg[8], bb[8];
      *(float4*)&sm[0] = *(const float4*)&stat1[kb];
      *(float4*)&sm[4] = *(const float4*)&stat1[kb + 4];
      *(float4*)&sq[0] = *(const float4*)&stat1[D2 + kb];
      *(float4*)&sq[4] = *(const float4*)&stat1[D2 + kb + 4];
      *(float4*)&gg[0] = *(const float4*)&g1[kb];
      *(float4*)&gg[4] = *(const float4*)&g1[kb + 4];
      *(float4*)&bb[0] = *(const float4*)&bt1[kb];
      *(float4*)&bb[4] = *(const float4*)&bt1[kb + 4];
      half8 v;
      if (row < N_NODES) {
        half8 z = *(const half8*)&z1h[(size_t)row * D2 + kb];
#pragma unroll
        for (int j = 0; j < 8; ++j) {
          float mu = sm[j] * invN;
          float isg = rsqrtf(sq[j] * invN - mu * mu + BN_EPS_F) * gg[j];
          v[j] = (_Float16)fmaxf(((float)z[j] - mu) * isg + bb[j], 0.f);
        }
      } else {
#pragma unroll
        for (int j = 0; j < 8; ++j) v[j] = (_Float16)0.f;
      }
      *(half8*)&Af[s * 8] = v;
    }
    __syncthreads();
#pragma unroll
    for (int kc = 0; kc < 2; ++kc) {
      int kcAll = kt * 2 + kc;
      half8 a0 = *(half8*)&Af[((kc * 4 + wm * 2 + 0) * 64 + ln) * 8];
      half8 a1 = *(half8*)&Af[((kc * 4 + wm * 2 + 1) * 64 + ln) * 8];
#pragma unroll
      for (int nt = 0; nt < 4; ++nt) {
        half8 b = *(const half8*)&w2p[((size_t)(kcAll * 8 + wn * 4 + nt) * 64 + ln) * 8];
        acc[0][nt] = MFMA16(a0, b, acc[0][nt]);
        acc[1][nt] = MFMA16(a1, b, acc[1][nt]);
      }
    }
    __syncthreads();
  }
  int lq = ln >> 4, lc = ln & 15;
  float cs[4], cq[4];
#pragma unroll
  for (int nt = 0; nt < 4; ++nt) { cs[nt] = 0.f; cq[nt] = 0.f; }
#pragma unroll
  for (int nt = 0; nt < 4; ++nt) {
    int col = (wn * 4 + nt) * 16 + lc;
    float bias = b2[col];
#pragma unroll
    for (int mt = 0; mt < 2; ++mt) {
      int rbase = row0 + (wm * 2 + mt) * 16 + lq * 4;
#pragma unroll
      for (int rg = 0; rg < 4; ++rg) {
        int row = rbase + rg;
        if (row < N_NODES) {
          float v = acc[mt][nt][rg] + bias;
          if (residual) v += h[(size_t)row * D + col];
          h[(size_t)row * D + col] = v;
          cs[nt] += v; cq[nt] += v * v;
        }
      }
    }
  }
#pragma unroll
  for (int nt = 0; nt < 4; ++nt) {
    float v = cs[nt], q = cq[nt];
    v += __shfl_xor(v, 16); v += __shfl_xor(v, 32);
    q += __shfl_xor(q, 16); q += __shfl_xor(q, 32);
    if (lq == 0) {
      int col = (wn * 4 + nt) * 16 + lc;
      atomicAdd(&statH[col], v);
      atomicAdd(&statH[D + col], q);
    }
  }
}

// ---------------------------------------------------------------- pool: segment-sum raw h per graph (no atomics)
__global__ __launch_bounds__(256) void k_pool(
    const float* __restrict__ h, const int* __restrict__ gstart,
    float* __restrict__ psum) {
  __shared__ float4 red[256];
  int b = blockIdx.x, tid = threadIdx.x;
  int fl = (tid & 31) << 2, ns = tid >> 5;
  int gs = gstart[b], ge = gstart[b + 1];
  float4 acc = make_float4(0.f, 0.f, 0.f, 0.f);
  for (int n = gs + ns; n < ge; n += 8) {
    float4 v = *(const float4*)&h[(size_t)n * D + fl];
    acc.x += v.x; acc.y += v.y; acc.z += v.z; acc.w += v.w;
  }
  red[tid] = acc;
  __syncthreads();
  if (ns < 4) {
    float4 o = red[tid + 128];
    acc.x += o.x; acc.y += o.y; acc.z += o.z; acc.w += o.w;
    red[tid] = acc;
  }
  __syncthreads();
  if (ns < 2) {
    float4 o = red[tid + 64];
    acc.x += o.x; acc.y += o.y; acc.z += o.z; acc.w += o.w;
    red[tid] = acc;
  }
  __syncthreads();
  if (ns == 0) {
    float4 o = red[tid + 32];
    acc.x += o.x; acc.y += o.y; acc.z += o.z; acc.w += o.w;
    *(float4*)&psum[(size_t)b * D + fl] = acc;
  }
}

// ---------------------------------------------------------------- predict: affine-BN + linear head
__global__ __launch_bounds__(64) void k_pred(
    const float* __restrict__ psum, const int* __restrict__ gstart,
    const float* __restrict__ statH, const float* __restrict__ gamma,
    const float* __restrict__ beta, const float* __restrict__ pw,
    const float* __restrict__ pb, float* __restrict__ out) {
  int b = blockIdx.x, t = threadIdx.x;
  if (t >= NTARGET) return;
  int gs = gstart[b], ge = gstart[b + 1];
  float acc = pb[t];
  if (ge > gs) {
    const float invN = 1.0f / (float)N_NODES;
    float inv = 1.0f / (float)(ge - gs);
    for (int k = 0; k < D; ++k) {
      float mu = statH[k] * invN;
      float var = statH[D + k] * invN - mu * mu;
      float emb = (psum[(size_t)b * D + k] * inv - mu) * rsqrtf(var + BN_EPS_F) * gamma[k] + beta[k];
      acc += emb * pw[k * NTARGET + t];
    }
  }
  out[b * NTARGET + t] = acc;
}

// ---------------------------------------------------------------- launch
extern "C" void kernel_launch(void* const* d_in, const int* in_sizes, int n_in,
                              void* d_out, int out_size, void* d_ws, size_t ws_size,
                              hipStream_t stream) {
  const int* x      = (const int*)d_in[0];
  const int* ei     = (const int*)d_in[1];
  const int* eattr  = (const int*)d_in[2];
  const int* batch  = (const int*)d_in[3];
  const int* aoff   = (const int*)d_in[4];
  const int* boff   = (const int*)d_in[5];
  const float* atab = (const float*)d_in[6];
  const float* btab = (const float*)d_in[7];
  const float* ngam = (const float*)d_in[8];
  const float* nbet = (const float*)d_in[9];
  const float* tptr = (const float*)d_in[10];
  const float* w1   = (const float*)d_in[11];
  const float* b1   = (const float*)d_in[12];
  const float* bng  = (const float*)d_in[13];
  const float* bnb  = (const float*)d_in[14];
  const float* w2   = (const float*)d_in[15];
  const float* b2   = (const float*)d_in[16];
  const float* pw   = (const float*)d_in[17];
  const float* pb   = (const float*)d_in[18];
  float* out = (float*)d_out;

  float* ws = (float*)d_ws;
  const size_t ND = (size_t)N_NODES * D;
  float* h      = ws;                          // ND fp32
  _Float16* rh  = (_Float16*)(ws + 1 * ND);    // ND halfs
  _Float16* aggrh = (_Float16*)(ws + 1 * ND + ND / 2);
  _Float16* z1h = (_Float16*)(ws + 2 * ND);    // N*D2 halfs
  float* stat1  = ws + 3 * ND;                 // 512 (also statbuf base)
  float* statH  = stat1 + 512;                 // 256
  float* psum   = statH + 256;                 // 512*128
  float* combo  = psum + (size_t)NGRAPH * D;   // 60*128
  _Float16* w1p = (_Float16*)(combo + 60 * D); // 7*32768 halfs
  _Float16* w2p = w1p + 7 * 32768;             // 7*32768 halfs
  int* ibuf     = (int*)(w2p + 7 * 32768);
  int* rowptr   = ibuf;                        // N+1
  int* cursor   = rowptr + N_NODES + 1;        // N
  int* deg      = cursor + N_NODES;            // N
  int* payload  = deg + N_NODES;               // E
  int* gstart   = payload + N_EDGES;           // NGRAPH+1
  int* excl     = gstart + NGRAPH + 1;         // N
  int* bsum     = excl + N_NODES;              // 64

  const int nodeBlocks = (N_NODES * 32 + 255) / 256;
  const int edgeThreadBlocks = (N_EDGES + 255) / 256;
  const int nBlocks256 = (N_NODES + 255) / 256;
  const int gRows = (N_NODES + 63) / 64;       // 782

  k_encode<<<nodeBlocks, 256, 0, stream>>>(x, aoff, atab, h, rh, deg);
  k_combo<<<60, 128, 0, stream>>>(boff, btab, combo);
  k_packW<<<(2 * 7 * 4096 + 255) / 256, 256, 0, stream>>>(w1, w2, w1p, w2p);
  k_gbounds<<<nBlocks256, 256, 0, stream>>>(batch, gstart);
  k_degree<<<edgeThreadBlocks, 256, 0, stream>>>(ei, deg);
  k_scan1<<<NSB, 1024, 0, stream>>>(deg, excl, bsum);
  k_scan2<<<1, 64, 0, stream>>>(bsum);
  k_scan3<<<(N_NODES + 256) / 256, 256, 0, stream>>>(excl, bsum, rowptr, cursor);
  k_scatter<<<edgeThreadBlocks, 256, 0, stream>>>(ei, eattr, cursor, payload);

  for (int l = 0; l < 7; ++l) {
    if (l > 0)
      k_prenorm<<<nodeBlocks, 256, 0, stream>>>(h, statH, ngam + l * D, nbet + l * D, rh);
    k_aggr<<<nodeBlocks, 256, 0, stream>>>(rh, rowptr, payload, combo, tptr, l, aggrh, stat1);
    k_gemm1<<<gRows, 256, 0, stream>>>(rh, aggrh, w1p + (size_t)l * 32768,
                                       b1 + l * D2, z1h, stat1);
    k_gemm2<<<gRows, 256, 0, stream>>>(z1h, stat1, bng + l * D2, bnb + l * D2,
                                       w2p + (size_t)l * 32768, b2 + l * D,
                                       h, l > 0 ? 1 : 0, statH);
  }

  k_pool<<<NGRAPH, 256, 0, stream>>>(h, gstart, psum);
  k_pred<<<NGRAPH, 64, 0, stream>>>(psum, gstart, statH, ngam, nbet, pw, pb, out);
}

// Round 7
// 1442.023 us; speedup vs baseline: 22.8679x; 1.0038x over previous
//
#include <hip/hip_runtime.h>
#include <hip/hip_bf16.h>

#define N_NODES 50000
#define N_EDGES 600000
#define D 128
#define D2 256
#define NGRAPH 512
#define NTARGET 10
#define NSB 49  // scan blocks: ceil(50000/1024)

static constexpr float MSG_EPS_F = 1e-7f;
static constexpr float BN_EPS_F  = 1e-5f;

typedef _Float16 half8 __attribute__((ext_vector_type(8)));
typedef _Float16 half4v __attribute__((ext_vector_type(4)));
typedef float f32x4 __attribute__((ext_vector_type(4)));
#define MFMA16(a, b, c) __builtin_amdgcn_mfma_f32_16x16x32_f16(a, b, c, 0, 0, 0)

// ---------------------------------------------------------------- encoder: h fp32 + rh fp16 (+ zero deg)
__global__ __launch_bounds__(256) void k_encode(
    const int* __restrict__ x, const int* __restrict__ aoff,
    const float* __restrict__ atab, float* __restrict__ h,
    _Float16* __restrict__ rh, int* __restrict__ deg) {
  int tid = blockIdx.x * 256 + threadIdx.x;
  if (tid < N_NODES) deg[tid] = 0;
  int n = tid >> 5, f4 = (tid & 31) << 2;
  if (n >= N_NODES) return;
  float4 acc = make_float4(0.f, 0.f, 0.f, 0.f);
#pragma unroll
  for (int i = 0; i < 9; ++i) {
    int row = x[n * 9 + i] + aoff[i];
    float4 v = *(const float4*)&atab[row * D + f4];
    acc.x += v.x; acc.y += v.y; acc.z += v.z; acc.w += v.w;
  }
  *(float4*)&h[(size_t)n * D + f4] = acc;
  half4v o = {(_Float16)acc.x, (_Float16)acc.y, (_Float16)acc.z, (_Float16)acc.w};
  *(half4v*)&rh[(size_t)n * D + f4] = o;
}

// ---------------------------------------------------------------- combo table
__global__ __launch_bounds__(128) void k_combo(
    const int* __restrict__ boff, const float* __restrict__ btab,
    float* __restrict__ combo) {
  int c = blockIdx.x, t = threadIdx.x;
  int a0 = c / 12, a1 = (c % 12) / 2, a2 = c % 2;
  combo[c * D + t] = btab[(boff[0] + a0) * D + t] +
                     btab[(boff[1] + a1) * D + t] +
                     btab[(boff[2] + a2) * D + t];
}

// ---------------------------------------------------------------- weight pre-pack: fp32 -> fp16 MFMA-fragment order
__global__ __launch_bounds__(256) void k_packW(
    const float* __restrict__ w1, const float* __restrict__ w2,
    _Float16* __restrict__ w1p, _Float16* __restrict__ w2p) {
  int t = blockIdx.x * 256 + threadIdx.x;
  if (t < 7 * 4096) {
    int lane = t & 63, ntAll = (t >> 6) & 15, kc = (t >> 10) & 3, l = t >> 12;
    int q = lane >> 4, c = ntAll * 16 + (lane & 15);
    int kbase = kc * 32 + q * 8;
    const float* W = w1 + (size_t)l * D * D2;
    half8 v;
#pragma unroll
    for (int j = 0; j < 8; ++j) v[j] = (_Float16)W[(size_t)(kbase + j) * D2 + c];
    *(half8*)&w1p[(size_t)t * 8] = v;
  } else {
    int u = t - 7 * 4096;
    if (u < 7 * 4096) {
      int lane = u & 63, nt = (u >> 6) & 7, kcAll = (u >> 9) & 7, l = u >> 12;
      int q = lane >> 4, c = nt * 16 + (lane & 15);
      int kbase = kcAll * 32 + q * 8;
      const float* W = w2 + (size_t)l * D2 * D;
      half8 v;
#pragma unroll
      for (int j = 0; j < 8; ++j) v[j] = (_Float16)W[(size_t)(kbase + j) * D + c];
      *(half8*)&w2p[(size_t)u * 8] = v;
    }
  }
}

// ---------------------------------------------------------------- CSR build
__global__ __launch_bounds__(256) void k_degree(
    const int* __restrict__ ei, int* __restrict__ deg) {
  int e = blockIdx.x * 256 + threadIdx.x;
  if (e >= N_EDGES) return;
  atomicAdd(&deg[ei[N_EDGES + e]], 1);
}

// 3-phase parallel scan
__global__ __launch_bounds__(1024) void k_scan1(
    const int* __restrict__ deg, int* __restrict__ excl, int* __restrict__ bsum) {
  __shared__ int tmp[1024];
  int t = threadIdx.x, i = blockIdx.x * 1024 + t;
  int v = (i < N_NODES) ? deg[i] : 0;
  tmp[t] = v;
  __syncthreads();
  for (int off = 1; off < 1024; off <<= 1) {
    int add = (t >= off) ? tmp[t - off] : 0;
    __syncthreads();
    tmp[t] += add;
    __syncthreads();
  }
  if (i < N_NODES) excl[i] = tmp[t] - v;
  if (t == 1023) bsum[blockIdx.x] = tmp[1023];
}

__global__ __launch_bounds__(64) void k_scan2(int* __restrict__ bsum) {
  __shared__ int s[64];
  int t = threadIdx.x;
  int v = (t < NSB) ? bsum[t] : 0;
  s[t] = v;
  __syncthreads();
  for (int off = 1; off < 64; off <<= 1) {
    int add = (t >= off) ? s[t - off] : 0;
    __syncthreads();
    s[t] += add;
    __syncthreads();
  }
  if (t < NSB) bsum[t] = s[t] - v;
}

__global__ __launch_bounds__(256) void k_scan3(
    const int* __restrict__ excl, const int* __restrict__ bsum,
    int* __restrict__ rowptr, int* __restrict__ cursor) {
  int i = blockIdx.x * 256 + threadIdx.x;
  if (i < N_NODES) {
    int v = excl[i] + bsum[i >> 10];
    rowptr[i] = v;
    cursor[i] = v;
  }
  if (i == N_NODES) rowptr[N_NODES] = N_EDGES;
}

__global__ __launch_bounds__(256) void k_scatter(
    const int* __restrict__ ei, const int* __restrict__ eattr,
    int* __restrict__ cursor, int* __restrict__ payload) {
  int e = blockIdx.x * 256 + threadIdx.x;
  if (e >= N_EDGES) return;
  int src = ei[e], dst = ei[N_EDGES + e];
  int cid = eattr[e * 3 + 0] * 12 + eattr[e * 3 + 1] * 2 + eattr[e * 3 + 2];
  int pos = atomicAdd(&cursor[dst], 1);
  payload[pos] = (src << 6) | cid;
}

// ---------------------------------------------------------------- graph bounds from sorted batch
__global__ __launch_bounds__(256) void k_gbounds(
    const int* __restrict__ batch, int* __restrict__ gstart) {
  int n = blockIdx.x * 256 + threadIdx.x;
  if (n >= N_NODES) return;
  int b0 = batch[n];
  int b1 = (n + 1 < N_NODES) ? batch[n + 1] : NGRAPH;
  for (int bb = b0 + 1; bb <= b1; ++bb) gstart[bb] = n + 1;
  if (n == 0)
    for (int bb = 0; bb <= b0; ++bb) gstart[bb] = 0;
}

// ---------------------------------------------------------------- pre-norm: rh = fp16(relu(BN(h)))
__global__ __launch_bounds__(256) void k_prenorm(
    const float* __restrict__ h, const float* __restrict__ statH,
    const float* __restrict__ gamma, const float* __restrict__ beta,
    _Float16* __restrict__ rh) {
  int tid = blockIdx.x * 256 + threadIdx.x;
  int n = tid >> 5, f4 = (tid & 31) << 2;
  if (n >= N_NODES) return;
  const float invN = 1.0f / (float)N_NODES;
  float4 s  = *(const float4*)&statH[f4];
  float4 sq = *(const float4*)&statH[D + f4];
  float4 g  = *(const float4*)&gamma[f4];
  float4 b  = *(const float4*)&beta[f4];
  float4 hv = *(const float4*)&h[(size_t)n * D + f4];
  float mu = s.x * invN, var = sq.x * invN - mu * mu;
  float ox = fmaxf((hv.x - mu) * rsqrtf(var + BN_EPS_F) * g.x + b.x, 0.f);
  mu = s.y * invN; var = sq.y * invN - mu * mu;
  float oy = fmaxf((hv.y - mu) * rsqrtf(var + BN_EPS_F) * g.y + b.y, 0.f);
  mu = s.z * invN; var = sq.z * invN - mu * mu;
  float oz = fmaxf((hv.z - mu) * rsqrtf(var + BN_EPS_F) * g.z + b.z, 0.f);
  mu = s.w * invN; var = sq.w * invN - mu * mu;
  float ow = fmaxf((hv.w - mu) * rsqrtf(var + BN_EPS_F) * g.w + b.w, 0.f);
  half4v o = {(_Float16)ox, (_Float16)oy, (_Float16)oz, (_Float16)ow};
  *(half4v*)&rh[(size_t)n * D + f4] = o;
}

// ---------------------------------------------------------------- CSR softmax aggregation (fp16 gather) + stat zeroing
__global__ __launch_bounds__(256) void k_aggr(
    const _Float16* __restrict__ rh, const int* __restrict__ rowptr,
    const int* __restrict__ payload, const float* __restrict__ combo,
    const float* __restrict__ tptr, int l, _Float16* __restrict__ aggrh,
    float* __restrict__ statbuf) {
  if (blockIdx.x == 0) {
    for (int j = threadIdx.x; j < 768; j += 256) statbuf[j] = 0.f;
  }
  int tid = blockIdx.x * 256 + threadIdx.x;
  int dst = tid >> 5, f4 = (tid & 31) << 2;
  if (dst >= N_NODES) return;
  float tv = tptr[l];
  int s = rowptr[dst], e = rowptr[dst + 1];
  float4 den = make_float4(0.f, 0.f, 0.f, 0.f);
  float4 S = make_float4(0.f, 0.f, 0.f, 0.f);
  int i = s;
  for (; i + 1 < e; i += 2) {
    int p0 = payload[i], p1 = payload[i + 1];
    half4v r0 = *(const half4v*)&rh[(size_t)(p0 >> 6) * D + f4];
    half4v r1 = *(const half4v*)&rh[(size_t)(p1 >> 6) * D + f4];
    float4 cv0 = *(const float4*)&combo[(p0 & 63) * D + f4];
    float4 cv1 = *(const float4*)&combo[(p1 & 63) * D + f4];
    float m0x = fmaxf((float)r0[0] + cv0.x, 0.f) + MSG_EPS_F;
    float m0y = fmaxf((float)r0[1] + cv0.y, 0.f) + MSG_EPS_F;
    float m0z = fmaxf((float)r0[2] + cv0.z, 0.f) + MSG_EPS_F;
    float m0w = fmaxf((float)r0[3] + cv0.w, 0.f) + MSG_EPS_F;
    float m1x = fmaxf((float)r1[0] + cv1.x, 0.f) + MSG_EPS_F;
    float m1y = fmaxf((float)r1[1] + cv1.y, 0.f) + MSG_EPS_F;
    float m1z = fmaxf((float)r1[2] + cv1.z, 0.f) + MSG_EPS_F;
    float m1w = fmaxf((float)r1[3] + cv1.w, 0.f) + MSG_EPS_F;
    float e0x = __expf(m0x * tv), e0y = __expf(m0y * tv);
    float e0z = __expf(m0z * tv), e0w = __expf(m0w * tv);
    float e1x = __expf(m1x * tv), e1y = __expf(m1y * tv);
    float e1z = __expf(m1z * tv), e1w = __expf(m1w * tv);
    den.x += e0x + e1x; den.y += e0y + e1y;
    den.z += e0z + e1z; den.w += e0w + e1w;
    S.x += m0x * e0x + m1x * e1x; S.y += m0y * e0y + m1y * e1y;
    S.z += m0z * e0z + m1z * e1z; S.w += m0w * e0w + m1w * e1w;
  }
  if (i < e) {
    int p0 = payload[i];
    half4v r0 = *(const half4v*)&rh[(size_t)(p0 >> 6) * D + f4];
    float4 cv0 = *(const float4*)&combo[(p0 & 63) * D + f4];
    float m0x = fmaxf((float)r0[0] + cv0.x, 0.f) + MSG_EPS_F;
    float m0y = fmaxf((float)r0[1] + cv0.y, 0.f) + MSG_EPS_F;
    float m0z = fmaxf((float)r0[2] + cv0.z, 0.f) + MSG_EPS_F;
    float m0w = fmaxf((float)r0[3] + cv0.w, 0.f) + MSG_EPS_F;
    float e0x = __expf(m0x * tv), e0y = __expf(m0y * tv);
    float e0z = __expf(m0z * tv), e0w = __expf(m0w * tv);
    den.x += e0x; den.y += e0y; den.z += e0z; den.w += e0w;
    S.x += m0x * e0x; S.y += m0y * e0y; S.z += m0z * e0z; S.w += m0w * e0w;
  }
  half4v o;
  o[0] = (_Float16)(S.x / (den.x + 1e-16f));
  o[1] = (_Float16)(S.y / (den.y + 1e-16f));
  o[2] = (_Float16)(S.z / (den.z + 1e-16f));
  o[3] = (_Float16)(S.w / (den.w + 1e-16f));
  *(half4v*)&aggrh[(size_t)dst * D + f4] = o;
}

// ---------------------------------------------------------------- GEMM1 (MFMA fp16): z1h = fp16((rh+aggrh) @ W1 + b1); stats
// BM=32, BN=128, K=128. grid (1563, 2). 4 waves; wave w: 32 cols (2 n-frags).
__global__ __launch_bounds__(256) void k_gemm1(
    const _Float16* __restrict__ rh, const _Float16* __restrict__ aggrh,
    const _Float16* __restrict__ w1p, const float* __restrict__ b1,
    _Float16* __restrict__ z1h, float* __restrict__ stat1) {
  __shared__ __align__(16) _Float16 Af[512 * 8];   // 8 KB
  int tid = threadIdx.x;
  int row0 = blockIdx.x * 32;
  int y = blockIdx.y;                              // col0 = y*128

  // stage A fragments: slot s = (kc*2+mt)*64+lane, kc in [0,4), mt in [0,2)
#pragma unroll
  for (int s0 = 0; s0 < 2; ++s0) {
    int s = s0 * 256 + tid;
    int kc = s >> 7, mt = (s >> 6) & 1, l2 = s & 63;
    int row = row0 + mt * 16 + (l2 & 15);
    int kb = kc * 32 + ((l2 >> 4) << 3);
    half8 v;
    if (row < N_NODES) {
      half8 rv = *(const half8*)&rh[(size_t)row * D + kb];
      half8 av = *(const half8*)&aggrh[(size_t)row * D + kb];
      v = rv + av;
    } else {
#pragma unroll
      for (int j = 0; j < 8; ++j) v[j] = (_Float16)0.f;
    }
    *(half8*)&Af[s * 8] = v;
  }
  __syncthreads();

  int wv = tid >> 6, ln = tid & 63;
  f32x4 acc[2][2];
#pragma unroll
  for (int i = 0; i < 2; ++i)
#pragma unroll
    for (int j = 0; j < 2; ++j) acc[i][j] = (f32x4){0.f, 0.f, 0.f, 0.f};

#pragma unroll
  for (int kc = 0; kc < 4; ++kc) {
    half8 a0 = *(half8*)&Af[((kc * 2 + 0) * 64 + ln) * 8];
    half8 a1 = *(half8*)&Af[((kc * 2 + 1) * 64 + ln) * 8];
#pragma unroll
    for (int nt = 0; nt < 2; ++nt) {
      int ntAll = y * 8 + wv * 2 + nt;
      half8 b = *(const half8*)&w1p[((size_t)(kc * 16 + ntAll) * 64 + ln) * 8];
      acc[0][nt] = MFMA16(a0, b, acc[0][nt]);
      acc[1][nt] = MFMA16(a1, b, acc[1][nt]);
    }
  }
  int lq = ln >> 4, lc = ln & 15;
  float cs[2], cq[2];
#pragma unroll
  for (int nt = 0; nt < 2; ++nt) { cs[nt] = 0.f; cq[nt] = 0.f; }
#pragma unroll
  for (int nt = 0; nt < 2; ++nt) {
    int col = y * 128 + (wv * 2 + nt) * 16 + lc;
    float bias = b1[col];
#pragma unroll
    for (int mt = 0; mt < 2; ++mt) {
      int rbase = row0 + mt * 16 + lq * 4;
#pragma unroll
      for (int rg = 0; rg < 4; ++rg) {
        int row = rbase + rg;
        if (row < N_NODES) {
          float z = acc[mt][nt][rg] + bias;
          z1h[(size_t)row * D2 + col] = (_Float16)z;
          cs[nt] += z; cq[nt] += z * z;
        }
      }
    }
  }
#pragma unroll
  for (int nt = 0; nt < 2; ++nt) {
    float v = cs[nt], q = cq[nt];
    v += __shfl_xor(v, 16); v += __shfl_xor(v, 32);
    q += __shfl_xor(q, 16); q += __shfl_xor(q, 32);
    if (lq == 0) {
      int col = y * 128 + (wv * 2 + nt) * 16 + lc;
      atomicAdd(&stat1[col], v);
      atomicAdd(&stat1[D2 + col], q);
    }
  }
}

// ---------------------------------------------------------------- GEMM2 (MFMA fp16): h = relu(BN(z1)) @ W2 + b2 (+h); stats
// BM=32, BN=128 (full), K=256 staged once. grid 1563. wave w: 32 cols.
__global__ __launch_bounds__(256) void k_gemm2(
    const _Float16* __restrict__ z1h, const float* __restrict__ stat1,
    const float* __restrict__ g1, const float* __restrict__ bt1,
    const _Float16* __restrict__ w2p, const float* __restrict__ b2,
    float* __restrict__ h, int residual, float* __restrict__ statH) {
  __shared__ __align__(16) _Float16 Af[1024 * 8];   // 16 KB
  const float invN = 1.0f / (float)N_NODES;
  int tid = threadIdx.x;
  int row0 = blockIdx.x * 32;

  // stage A: slot s = (kcAll*2+mt)*64+lane, kcAll in [0,8), mt in [0,2)
#pragma unroll
  for (int s0 = 0; s0 < 4; ++s0) {
    int s = s0 * 256 + tid;
    int kcAll = s >> 7, mt = (s >> 6) & 1, l2 = s & 63;
    int row = row0 + mt * 16 + (l2 & 15);
    int kb = kcAll * 32 + ((l2 >> 4) << 3);
    float sm[8], sq[8], gg[8], bb[8];
    *(float4*)&sm[0] = *(const float4*)&stat1[kb];
    *(float4*)&sm[4] = *(const float4*)&stat1[kb + 4];
    *(float4*)&sq[0] = *(const float4*)&stat1[D2 + kb];
    *(float4*)&sq[4] = *(const float4*)&stat1[D2 + kb + 4];
    *(float4*)&gg[0] = *(const float4*)&g1[kb];
    *(float4*)&gg[4] = *(const float4*)&g1[kb + 4];
    *(float4*)&bb[0] = *(const float4*)&bt1[kb];
    *(float4*)&bb[4] = *(const float4*)&bt1[kb + 4];
    half8 v;
    if (row < N_NODES) {
      half8 z = *(const half8*)&z1h[(size_t)row * D2 + kb];
#pragma unroll
      for (int j = 0; j < 8; ++j) {
        float mu = sm[j] * invN;
        float isg = rsqrtf(sq[j] * invN - mu * mu + BN_EPS_F) * gg[j];
        v[j] = (_Float16)fmaxf(((float)z[j] - mu) * isg + bb[j], 0.f);
      }
    } else {
#pragma unroll
      for (int j = 0; j < 8; ++j) v[j] = (_Float16)0.f;
    }
    *(half8*)&Af[s * 8] = v;
  }
  __syncthreads();

  int wv = tid >> 6, ln = tid & 63;
  f32x4 acc[2][2];
#pragma unroll
  for (int i = 0; i < 2; ++i)
#pragma unroll
    for (int j = 0; j < 2; ++j) acc[i][j] = (f32x4){0.f, 0.f, 0.f, 0.f};

#pragma unroll
  for (int kcAll = 0; kcAll < 8; ++kcAll) {
    half8 a0 = *(half8*)&Af[((kcAll * 2 + 0) * 64 + ln) * 8];
    half8 a1 = *(half8*)&Af[((kcAll * 2 + 1) * 64 + ln) * 8];
#pragma unroll
    for (int nt = 0; nt < 2; ++nt) {
      half8 b = *(const half8*)&w2p[((size_t)(kcAll * 8 + wv * 2 + nt) * 64 + ln) * 8];
      acc[0][nt] = MFMA16(a0, b, acc[0][nt]);
      acc[1][nt] = MFMA16(a1, b, acc[1][nt]);
    }
  }
  int lq = ln >> 4, lc = ln & 15;
  float cs[2], cq[2];
#pragma unroll
  for (int nt = 0; nt < 2; ++nt) { cs[nt] = 0.f; cq[nt] = 0.f; }
#pragma unroll
  for (int nt = 0; nt < 2; ++nt) {
    int col = (wv * 2 + nt) * 16 + lc;
    float bias = b2[col];
#pragma unroll
    for (int mt = 0; mt < 2; ++mt) {
      int rbase = row0 + mt * 16 + lq * 4;
#pragma unroll
      for (int rg = 0; rg < 4; ++rg) {
        int row = rbase + rg;
        if (row < N_NODES) {
          float v = acc[mt][nt][rg] + bias;
          if (residual) v += h[(size_t)row * D + col];
          h[(size_t)row * D + col] = v;
          cs[nt] += v; cq[nt] += v * v;
        }
      }
    }
  }
#pragma unroll
  for (int nt = 0; nt < 2; ++nt) {
    float v = cs[nt], q = cq[nt];
    v += __shfl_xor(v, 16); v += __shfl_xor(v, 32);
    q += __shfl_xor(q, 16); q += __shfl_xor(q, 32);
    if (lq == 0) {
      int col = (wv * 2 + nt) * 16 + lc;
      atomicAdd(&statH[col], v);
      atomicAdd(&statH[D + col], q);
    }
  }
}

// ---------------------------------------------------------------- pool: segment-sum raw h per graph (no atomics)
__global__ __launch_bounds__(256) void k_pool(
    const float* __restrict__ h, const int* __restrict__ gstart,
    float* __restrict__ psum) {
  __shared__ float4 red[256];
  int b = blockIdx.x, tid = threadIdx.x;
  int fl = (tid & 31) << 2, ns = tid >> 5;
  int gs = gstart[b], ge = gstart[b + 1];
  float4 acc = make_float4(0.f, 0.f, 0.f, 0.f);
  for (int n = gs + ns; n < ge; n += 8) {
    float4 v = *(const float4*)&h[(size_t)n * D + fl];
    acc.x += v.x; acc.y += v.y; acc.z += v.z; acc.w += v.w;
  }
  red[tid] = acc;
  __syncthreads();
  if (ns < 4) {
    float4 o = red[tid + 128];
    acc.x += o.x; acc.y += o.y; acc.z += o.z; acc.w += o.w;
    red[tid] = acc;
  }
  __syncthreads();
  if (ns < 2) {
    float4 o = red[tid + 64];
    acc.x += o.x; acc.y += o.y; acc.z += o.z; acc.w += o.w;
    red[tid] = acc;
  }
  __syncthreads();
  if (ns == 0) {
    float4 o = red[tid + 32];
    acc.x += o.x; acc.y += o.y; acc.z += o.z; acc.w += o.w;
    *(float4*)&psum[(size_t)b * D + fl] = acc;
  }
}

// ---------------------------------------------------------------- predict: affine-BN + linear head
__global__ __launch_bounds__(64) void k_pred(
    const float* __restrict__ psum, const int* __restrict__ gstart,
    const float* __restrict__ statH, const float* __restrict__ gamma,
    const float* __restrict__ beta, const float* __restrict__ pw,
    const float* __restrict__ pb, float* __restrict__ out) {
  int b = blockIdx.x, t = threadIdx.x;
  if (t >= NTARGET) return;
  int gs = gstart[b], ge = gstart[b + 1];
  float acc = pb[t];
  if (ge > gs) {
    const float invN = 1.0f / (float)N_NODES;
    float inv = 1.0f / (float)(ge - gs);
    for (int k = 0; k < D; ++k) {
      float mu = statH[k] * invN;
      float var = statH[D + k] * invN - mu * mu;
      float emb = (psum[(size_t)b * D + k] * inv - mu) * rsqrtf(var + BN_EPS_F) * gamma[k] + beta[k];
      acc += emb * pw[k * NTARGET + t];
    }
  }
  out[b * NTARGET + t] = acc;
}

// ---------------------------------------------------------------- launch
extern "C" void kernel_launch(void* const* d_in, const int* in_sizes, int n_in,
                              void* d_out, int out_size, void* d_ws, size_t ws_size,
                              hipStream_t stream) {
  const int* x      = (const int*)d_in[0];
  const int* ei     = (const int*)d_in[1];
  const int* eattr  = (const int*)d_in[2];
  const int* batch  = (const int*)d_in[3];
  const int* aoff   = (const int*)d_in[4];
  const int* boff   = (const int*)d_in[5];
  const float* atab = (const float*)d_in[6];
  const float* btab = (const float*)d_in[7];
  const float* ngam = (const float*)d_in[8];
  const float* nbet = (const float*)d_in[9];
  const float* tptr = (const float*)d_in[10];
  const float* w1   = (const float*)d_in[11];
  const float* b1   = (const float*)d_in[12];
  const float* bng  = (const float*)d_in[13];
  const float* bnb  = (const float*)d_in[14];
  const float* w2   = (const float*)d_in[15];
  const float* b2   = (const float*)d_in[16];
  const float* pw   = (const float*)d_in[17];
  const float* pb   = (const float*)d_in[18];
  float* out = (float*)d_out;

  float* ws = (float*)d_ws;
  const size_t ND = (size_t)N_NODES * D;
  float* h      = ws;                          // ND fp32
  _Float16* rh  = (_Float16*)(ws + 1 * ND);    // ND halfs
  _Float16* aggrh = (_Float16*)(ws + 1 * ND + ND / 2);
  _Float16* z1h = (_Float16*)(ws + 2 * ND);    // N*D2 halfs
  float* stat1  = ws + 3 * ND;                 // 512
  float* statH  = stat1 + 512;                 // 256
  float* psum   = statH + 256;                 // 512*128
  float* combo  = psum + (size_t)NGRAPH * D;   // 60*128
  _Float16* w1p = (_Float16*)(combo + 60 * D); // 7*32768 halfs
  _Float16* w2p = w1p + 7 * 32768;             // 7*32768 halfs
  int* ibuf     = (int*)(w2p + 7 * 32768);
  int* rowptr   = ibuf;                        // N+1
  int* cursor   = rowptr + N_NODES + 1;        // N
  int* deg      = cursor + N_NODES;            // N
  int* payload  = deg + N_NODES;               // E
  int* gstart   = payload + N_EDGES;           // NGRAPH+1
  int* excl     = gstart + NGRAPH + 1;         // N
  int* bsum     = excl + N_NODES;              // 64

  const int nodeBlocks = (N_NODES * 32 + 255) / 256;
  const int edgeThreadBlocks = (N_EDGES + 255) / 256;
  const int nBlocks256 = (N_NODES + 255) / 256;
  const int gRows32 = (N_NODES + 31) / 32;     // 1563

  k_encode<<<nodeBlocks, 256, 0, stream>>>(x, aoff, atab, h, rh, deg);
  k_combo<<<60, 128, 0, stream>>>(boff, btab, combo);
  k_packW<<<(2 * 7 * 4096 + 255) / 256, 256, 0, stream>>>(w1, w2, w1p, w2p);
  k_gbounds<<<nBlocks256, 256, 0, stream>>>(batch, gstart);
  k_degree<<<edgeThreadBlocks, 256, 0, stream>>>(ei, deg);
  k_scan1<<<NSB, 1024, 0, stream>>>(deg, excl, bsum);
  k_scan2<<<1, 64, 0, stream>>>(bsum);
  k_scan3<<<(N_NODES + 256) / 256, 256, 0, stream>>>(excl, bsum, rowptr, cursor);
  k_scatter<<<edgeThreadBlocks, 256, 0, stream>>>(ei, eattr, cursor, payload);

  for (int l = 0; l < 7; ++l) {
    if (l > 0)
      k_prenorm<<<nodeBlocks, 256, 0, stream>>>(h, statH, ngam + l * D, nbet + l * D, rh);
    k_aggr<<<nodeBlocks, 256, 0, stream>>>(rh, rowptr, payload, combo, tptr, l, aggrh, stat1);
    k_gemm1<<<dim3(gRows32, 2), 256, 0, stream>>>(rh, aggrh, w1p + (size_t)l * 32768,
                                                  b1 + l * D2, z1h, stat1);
    k_gemm2<<<gRows32, 256, 0, stream>>>(z1h, stat1, bng + l * D2, bnb + l * D2,
                                         w2p + (size_t)l * 32768, b2 + l * D,
                                         h, l > 0 ? 1 : 0, statH);
  }

  k_pool<<<NGRAPH, 256, 0, stream>>>(h, gstart, psum);
  k_pred<<<NGRAPH, 64, 0, stream>>>(psum, gstart, statH, ngam, nbet, pw, pb, out);
}

// Round 8
// 909.254 us; speedup vs baseline: 36.2672x; 1.5859x over previous
//
#include <hip/hip_runtime.h>
#include <hip/hip_bf16.h>

#define N_NODES 50000
#define N_EDGES 600000
#define D 128
#define D2 256
#define NGRAPH 512
#define NTARGET 10
#define NSB 49   // scan blocks
#define NSLOT 32 // stat accumulation slots

static constexpr float MSG_EPS_F = 1e-7f;
static constexpr float BN_EPS_F  = 1e-5f;

typedef _Float16 half8 __attribute__((ext_vector_type(8)));
typedef _Float16 half4v __attribute__((ext_vector_type(4)));
typedef float f32x4 __attribute__((ext_vector_type(4)));
#define MFMA16(a, b, c) __builtin_amdgcn_mfma_f32_16x16x32_f16(a, b, c, 0, 0, 0)

// ---------------------------------------------------------------- encoder: h fp32 + rh fp16 (+ zero deg)
__global__ __launch_bounds__(256) void k_encode(
    const int* __restrict__ x, const int* __restrict__ aoff,
    const float* __restrict__ atab, float* __restrict__ h,
    _Float16* __restrict__ rh, int* __restrict__ deg) {
  int tid = blockIdx.x * 256 + threadIdx.x;
  if (tid < N_NODES) deg[tid] = 0;
  int n = tid >> 5, f4 = (tid & 31) << 2;
  if (n >= N_NODES) return;
  float4 acc = make_float4(0.f, 0.f, 0.f, 0.f);
#pragma unroll
  for (int i = 0; i < 9; ++i) {
    int row = x[n * 9 + i] + aoff[i];
    float4 v = *(const float4*)&atab[row * D + f4];
    acc.x += v.x; acc.y += v.y; acc.z += v.z; acc.w += v.w;
  }
  *(float4*)&h[(size_t)n * D + f4] = acc;
  half4v o = {(_Float16)acc.x, (_Float16)acc.y, (_Float16)acc.z, (_Float16)acc.w};
  *(half4v*)&rh[(size_t)n * D + f4] = o;
}

// ---------------------------------------------------------------- combo table
__global__ __launch_bounds__(128) void k_combo(
    const int* __restrict__ boff, const float* __restrict__ btab,
    float* __restrict__ combo) {
  int c = blockIdx.x, t = threadIdx.x;
  int a0 = c / 12, a1 = (c % 12) / 2, a2 = c % 2;
  combo[c * D + t] = btab[(boff[0] + a0) * D + t] +
                     btab[(boff[1] + a1) * D + t] +
                     btab[(boff[2] + a2) * D + t];
}

// ---------------------------------------------------------------- weight pre-pack
__global__ __launch_bounds__(256) void k_packW(
    const float* __restrict__ w1, const float* __restrict__ w2,
    _Float16* __restrict__ w1p, _Float16* __restrict__ w2p) {
  int t = blockIdx.x * 256 + threadIdx.x;
  if (t < 7 * 4096) {
    int lane = t & 63, ntAll = (t >> 6) & 15, kc = (t >> 10) & 3, l = t >> 12;
    int q = lane >> 4, c = ntAll * 16 + (lane & 15);
    int kbase = kc * 32 + q * 8;
    const float* W = w1 + (size_t)l * D * D2;
    half8 v;
#pragma unroll
    for (int j = 0; j < 8; ++j) v[j] = (_Float16)W[(size_t)(kbase + j) * D2 + c];
    *(half8*)&w1p[(size_t)t * 8] = v;
  } else {
    int u = t - 7 * 4096;
    if (u < 7 * 4096) {
      int lane = u & 63, nt = (u >> 6) & 7, kcAll = (u >> 9) & 7, l = u >> 12;
      int q = lane >> 4, c = nt * 16 + (lane & 15);
      int kbase = kcAll * 32 + q * 8;
      const float* W = w2 + (size_t)l * D2 * D;
      half8 v;
#pragma unroll
      for (int j = 0; j < 8; ++j) v[j] = (_Float16)W[(size_t)(kbase + j) * D + c];
      *(half8*)&w2p[(size_t)u * 8] = v;
    }
  }
}

// ---------------------------------------------------------------- CSR build
__global__ __launch_bounds__(256) void k_degree(
    const int* __restrict__ ei, int* __restrict__ deg) {
  int e = blockIdx.x * 256 + threadIdx.x;
  if (e >= N_EDGES) return;
  atomicAdd(&deg[ei[N_EDGES + e]], 1);
}

__global__ __launch_bounds__(1024) void k_scan1(
    const int* __restrict__ deg, int* __restrict__ excl, int* __restrict__ bsum) {
  __shared__ int tmp[1024];
  int t = threadIdx.x, i = blockIdx.x * 1024 + t;
  int v = (i < N_NODES) ? deg[i] : 0;
  tmp[t] = v;
  __syncthreads();
  for (int off = 1; off < 1024; off <<= 1) {
    int add = (t >= off) ? tmp[t - off] : 0;
    __syncthreads();
    tmp[t] += add;
    __syncthreads();
  }
  if (i < N_NODES) excl[i] = tmp[t] - v;
  if (t == 1023) bsum[blockIdx.x] = tmp[1023];
}

__global__ __launch_bounds__(64) void k_scan2(int* __restrict__ bsum) {
  __shared__ int s[64];
  int t = threadIdx.x;
  int v = (t < NSB) ? bsum[t] : 0;
  s[t] = v;
  __syncthreads();
  for (int off = 1; off < 64; off <<= 1) {
    int add = (t >= off) ? s[t - off] : 0;
    __syncthreads();
    s[t] += add;
    __syncthreads();
  }
  if (t < NSB) bsum[t] = s[t] - v;
}

__global__ __launch_bounds__(256) void k_scan3(
    const int* __restrict__ excl, const int* __restrict__ bsum,
    int* __restrict__ rowptr, int* __restrict__ cursor) {
  int i = blockIdx.x * 256 + threadIdx.x;
  if (i < N_NODES) {
    int v = excl[i] + bsum[i >> 10];
    rowptr[i] = v;
    cursor[i] = v;
  }
  if (i == N_NODES) rowptr[N_NODES] = N_EDGES;
}

__global__ __launch_bounds__(256) void k_scatter(
    const int* __restrict__ ei, const int* __restrict__ eattr,
    int* __restrict__ cursor, int* __restrict__ payload) {
  int e = blockIdx.x * 256 + threadIdx.x;
  if (e >= N_EDGES) return;
  int src = ei[e], dst = ei[N_EDGES + e];
  int cid = eattr[e * 3 + 0] * 12 + eattr[e * 3 + 1] * 2 + eattr[e * 3 + 2];
  int pos = atomicAdd(&cursor[dst], 1);
  payload[pos] = (src << 6) | cid;
}

// ---------------------------------------------------------------- graph bounds
__global__ __launch_bounds__(256) void k_gbounds(
    const int* __restrict__ batch, int* __restrict__ gstart) {
  int n = blockIdx.x * 256 + threadIdx.x;
  if (n >= N_NODES) return;
  int b0 = batch[n];
  int b1 = (n + 1 < N_NODES) ? batch[n + 1] : NGRAPH;
  for (int bb = b0 + 1; bb <= b1; ++bb) gstart[bb] = n + 1;
  if (n == 0)
    for (int bb = 0; bb <= b0; ++bb) gstart[bb] = 0;
}

// ---------------------------------------------------------------- pre-norm: rh = fp16(relu(BN(h))); statH from slots
__global__ __launch_bounds__(256) void k_prenorm(
    const float* __restrict__ h, const float* __restrict__ statHs,
    const float* __restrict__ gamma, const float* __restrict__ beta,
    _Float16* __restrict__ rh) {
  __shared__ float sH[256];
  int t = threadIdx.x;
  {
    float a = 0.f;
#pragma unroll
    for (int s = 0; s < NSLOT; ++s) a += statHs[s * 256 + t];
    sH[t] = a;
  }
  __syncthreads();
  int tid = blockIdx.x * 256 + t;
  int n = tid >> 5, f4 = (t & 31) << 2;
  if (n >= N_NODES) return;
  const float invN = 1.0f / (float)N_NODES;
  float4 s  = *(const float4*)&sH[f4];
  float4 sq = *(const float4*)&sH[D + f4];
  float4 g  = *(const float4*)&gamma[f4];
  float4 b  = *(const float4*)&beta[f4];
  float4 hv = *(const float4*)&h[(size_t)n * D + f4];
  float mu = s.x * invN, var = sq.x * invN - mu * mu;
  float ox = fmaxf((hv.x - mu) * rsqrtf(var + BN_EPS_F) * g.x + b.x, 0.f);
  mu = s.y * invN; var = sq.y * invN - mu * mu;
  float oy = fmaxf((hv.y - mu) * rsqrtf(var + BN_EPS_F) * g.y + b.y, 0.f);
  mu = s.z * invN; var = sq.z * invN - mu * mu;
  float oz = fmaxf((hv.z - mu) * rsqrtf(var + BN_EPS_F) * g.z + b.z, 0.f);
  mu = s.w * invN; var = sq.w * invN - mu * mu;
  float ow = fmaxf((hv.w - mu) * rsqrtf(var + BN_EPS_F) * g.w + b.w, 0.f);
  half4v o = {(_Float16)ox, (_Float16)oy, (_Float16)oz, (_Float16)ow};
  *(half4v*)&rh[(size_t)n * D + f4] = o;
}

// ---------------------------------------------------------------- CSR softmax aggregation + stat-slot zeroing
__global__ __launch_bounds__(256) void k_aggr(
    const _Float16* __restrict__ rh, const int* __restrict__ rowptr,
    const int* __restrict__ payload, const float* __restrict__ combo,
    const float* __restrict__ tptr, int l, _Float16* __restrict__ aggrh,
    float* __restrict__ stat1s, float* __restrict__ statHs) {
  if (blockIdx.x < NSLOT) {
    float* z1 = stat1s + blockIdx.x * 512;
    float* zH = statHs + blockIdx.x * 256;
    for (int j = threadIdx.x; j < 768; j += 256) {
      if (j < 512) z1[j] = 0.f;
      else zH[j - 512] = 0.f;
    }
  }
  int tid = blockIdx.x * 256 + threadIdx.x;
  int dst = tid >> 5, f4 = (tid & 31) << 2;
  if (dst >= N_NODES) return;
  float tv = tptr[l];
  int s = rowptr[dst], e = rowptr[dst + 1];
  float4 den = make_float4(0.f, 0.f, 0.f, 0.f);
  float4 S = make_float4(0.f, 0.f, 0.f, 0.f);
  int i = s;
  for (; i + 1 < e; i += 2) {
    int p0 = payload[i], p1 = payload[i + 1];
    half4v r0 = *(const half4v*)&rh[(size_t)(p0 >> 6) * D + f4];
    half4v r1 = *(const half4v*)&rh[(size_t)(p1 >> 6) * D + f4];
    float4 cv0 = *(const float4*)&combo[(p0 & 63) * D + f4];
    float4 cv1 = *(const float4*)&combo[(p1 & 63) * D + f4];
    float m0x = fmaxf((float)r0[0] + cv0.x, 0.f) + MSG_EPS_F;
    float m0y = fmaxf((float)r0[1] + cv0.y, 0.f) + MSG_EPS_F;
    float m0z = fmaxf((float)r0[2] + cv0.z, 0.f) + MSG_EPS_F;
    float m0w = fmaxf((float)r0[3] + cv0.w, 0.f) + MSG_EPS_F;
    float m1x = fmaxf((float)r1[0] + cv1.x, 0.f) + MSG_EPS_F;
    float m1y = fmaxf((float)r1[1] + cv1.y, 0.f) + MSG_EPS_F;
    float m1z = fmaxf((float)r1[2] + cv1.z, 0.f) + MSG_EPS_F;
    float m1w = fmaxf((float)r1[3] + cv1.w, 0.f) + MSG_EPS_F;
    float e0x = __expf(m0x * tv), e0y = __expf(m0y * tv);
    float e0z = __expf(m0z * tv), e0w = __expf(m0w * tv);
    float e1x = __expf(m1x * tv), e1y = __expf(m1y * tv);
    float e1z = __expf(m1z * tv), e1w = __expf(m1w * tv);
    den.x += e0x + e1x; den.y += e0y + e1y;
    den.z += e0z + e1z; den.w += e0w + e1w;
    S.x += m0x * e0x + m1x * e1x; S.y += m0y * e0y + m1y * e1y;
    S.z += m0z * e0z + m1z * e1z; S.w += m0w * e0w + m1w * e1w;
  }
  if (i < e) {
    int p0 = payload[i];
    half4v r0 = *(const half4v*)&rh[(size_t)(p0 >> 6) * D + f4];
    float4 cv0 = *(const float4*)&combo[(p0 & 63) * D + f4];
    float m0x = fmaxf((float)r0[0] + cv0.x, 0.f) + MSG_EPS_F;
    float m0y = fmaxf((float)r0[1] + cv0.y, 0.f) + MSG_EPS_F;
    float m0z = fmaxf((float)r0[2] + cv0.z, 0.f) + MSG_EPS_F;
    float m0w = fmaxf((float)r0[3] + cv0.w, 0.f) + MSG_EPS_F;
    float e0x = __expf(m0x * tv), e0y = __expf(m0y * tv);
    float e0z = __expf(m0z * tv), e0w = __expf(m0w * tv);
    den.x += e0x; den.y += e0y; den.z += e0z; den.w += e0w;
    S.x += m0x * e0x; S.y += m0y * e0y; S.z += m0z * e0z; S.w += m0w * e0w;
  }
  half4v o;
  o[0] = (_Float16)(S.x / (den.x + 1e-16f));
  o[1] = (_Float16)(S.y / (den.y + 1e-16f));
  o[2] = (_Float16)(S.z / (den.z + 1e-16f));
  o[3] = (_Float16)(S.w / (den.w + 1e-16f));
  *(half4v*)&aggrh[(size_t)dst * D + f4] = o;
}

// ---------------------------------------------------------------- GEMM1 (MFMA fp16): z1h = fp16((rh+aggrh) @ W1 + b1); slotted stats
// BM=32, BN=256 (full), K=128. grid 1563. 4 waves; wave w: 64 cols (4 n-frags).
__global__ __launch_bounds__(256) void k_gemm1(
    const _Float16* __restrict__ rh, const _Float16* __restrict__ aggrh,
    const _Float16* __restrict__ w1p, const float* __restrict__ b1,
    _Float16* __restrict__ z1h, float* __restrict__ stat1s) {
  __shared__ __align__(16) _Float16 Af[512 * 8];   // 8 KB
  int tid = threadIdx.x;
  int row0 = blockIdx.x * 32;
  int slot = blockIdx.x & (NSLOT - 1);

  // stage A fragments: slot s = (kc*2+mt)*64+lane
#pragma unroll
  for (int s0 = 0; s0 < 2; ++s0) {
    int s = s0 * 256 + tid;
    int kc = s >> 7, mt = (s >> 6) & 1, l2 = s & 63;
    int row = row0 + mt * 16 + (l2 & 15);
    int kb = kc * 32 + ((l2 >> 4) << 3);
    half8 v;
    if (row < N_NODES) {
      half8 rv = *(const half8*)&rh[(size_t)row * D + kb];
      half8 av = *(const half8*)&aggrh[(size_t)row * D + kb];
      v = rv + av;
    } else {
#pragma unroll
      for (int j = 0; j < 8; ++j) v[j] = (_Float16)0.f;
    }
    *(half8*)&Af[s * 8] = v;
  }
  __syncthreads();

  int wv = tid >> 6, ln = tid & 63;
  f32x4 acc[2][4];
#pragma unroll
  for (int i = 0; i < 2; ++i)
#pragma unroll
    for (int j = 0; j < 4; ++j) acc[i][j] = (f32x4){0.f, 0.f, 0.f, 0.f};

#pragma unroll
  for (int kc = 0; kc < 4; ++kc) {
    half8 a0 = *(half8*)&Af[((kc * 2 + 0) * 64 + ln) * 8];
    half8 a1 = *(half8*)&Af[((kc * 2 + 1) * 64 + ln) * 8];
#pragma unroll
    for (int nt = 0; nt < 4; ++nt) {
      int ntAll = wv * 4 + nt;
      half8 b = *(const half8*)&w1p[((size_t)(kc * 16 + ntAll) * 64 + ln) * 8];
      acc[0][nt] = MFMA16(a0, b, acc[0][nt]);
      acc[1][nt] = MFMA16(a1, b, acc[1][nt]);
    }
  }
  int lq = ln >> 4, lc = ln & 15;
  float cs[4], cq[4];
#pragma unroll
  for (int nt = 0; nt < 4; ++nt) { cs[nt] = 0.f; cq[nt] = 0.f; }
#pragma unroll
  for (int nt = 0; nt < 4; ++nt) {
    int col = (wv * 4 + nt) * 16 + lc;
    float bias = b1[col];
#pragma unroll
    for (int mt = 0; mt < 2; ++mt) {
      int rbase = row0 + mt * 16 + lq * 4;
#pragma unroll
      for (int rg = 0; rg < 4; ++rg) {
        int row = rbase + rg;
        if (row < N_NODES) {
          float z = acc[mt][nt][rg] + bias;
          z1h[(size_t)row * D2 + col] = (_Float16)z;
          cs[nt] += z; cq[nt] += z * z;
        }
      }
    }
  }
#pragma unroll
  for (int nt = 0; nt < 4; ++nt) {
    float v = cs[nt], q = cq[nt];
    v += __shfl_xor(v, 16); v += __shfl_xor(v, 32);
    q += __shfl_xor(q, 16); q += __shfl_xor(q, 32);
    if (lq == 0) {
      int col = (wv * 4 + nt) * 16 + lc;
      atomicAdd(&stat1s[slot * 512 + col], v);
      atomicAdd(&stat1s[slot * 512 + 256 + col], q);
    }
  }
}

// ---------------------------------------------------------------- GEMM2 (MFMA fp16): h = relu(BN(z1)) @ W2 + b2 (+h); slotted stats
// BM=32, BN=128, K=256 staged once. grid 1563.
__global__ __launch_bounds__(256) void k_gemm2(
    const _Float16* __restrict__ z1h, const float* __restrict__ stat1s,
    const float* __restrict__ g1, const float* __restrict__ bt1,
    const _Float16* __restrict__ w2p, const float* __restrict__ b2,
    float* __restrict__ h, int residual, float* __restrict__ statHs) {
  __shared__ __align__(16) _Float16 Af[1024 * 8];   // 16 KB
  __shared__ float s1[512];
  const float invN = 1.0f / (float)N_NODES;
  int tid = threadIdx.x;
  int row0 = blockIdx.x * 32;
  int slot = blockIdx.x & (NSLOT - 1);

  // reduce stat1 slots into LDS
#pragma unroll
  for (int jj = 0; jj < 2; ++jj) {
    int j = jj * 256 + tid;
    float a = 0.f;
#pragma unroll
    for (int s = 0; s < NSLOT; ++s) a += stat1s[s * 512 + j];
    s1[j] = a;
  }
  __syncthreads();

  // stage A: slot s = (kcAll*2+mt)*64+lane
#pragma unroll
  for (int s0 = 0; s0 < 4; ++s0) {
    int s = s0 * 256 + tid;
    int kcAll = s >> 7, mt = (s >> 6) & 1, l2 = s & 63;
    int row = row0 + mt * 16 + (l2 & 15);
    int kb = kcAll * 32 + ((l2 >> 4) << 3);
    half8 v;
    if (row < N_NODES) {
      half8 z = *(const half8*)&z1h[(size_t)row * D2 + kb];
#pragma unroll
      for (int j = 0; j < 8; ++j) {
        float mu = s1[kb + j] * invN;
        float isg = rsqrtf(s1[256 + kb + j] * invN - mu * mu + BN_EPS_F) * g1[kb + j];
        v[j] = (_Float16)fmaxf(((float)z[j] - mu) * isg + bt1[kb + j], 0.f);
      }
    } else {
#pragma unroll
      for (int j = 0; j < 8; ++j) v[j] = (_Float16)0.f;
    }
    *(half8*)&Af[s * 8] = v;
  }
  __syncthreads();

  int wv = tid >> 6, ln = tid & 63;
  f32x4 acc[2][2];
#pragma unroll
  for (int i = 0; i < 2; ++i)
#pragma unroll
    for (int j = 0; j < 2; ++j) acc[i][j] = (f32x4){0.f, 0.f, 0.f, 0.f};

#pragma unroll
  for (int kcAll = 0; kcAll < 8; ++kcAll) {
    half8 a0 = *(half8*)&Af[((kcAll * 2 + 0) * 64 + ln) * 8];
    half8 a1 = *(half8*)&Af[((kcAll * 2 + 1) * 64 + ln) * 8];
#pragma unroll
    for (int nt = 0; nt < 2; ++nt) {
      half8 b = *(const half8*)&w2p[((size_t)(kcAll * 8 + wv * 2 + nt) * 64 + ln) * 8];
      acc[0][nt] = MFMA16(a0, b, acc[0][nt]);
      acc[1][nt] = MFMA16(a1, b, acc[1][nt]);
    }
  }
  int lq = ln >> 4, lc = ln & 15;
  float cs[2], cq[2];
#pragma unroll
  for (int nt = 0; nt < 2; ++nt) { cs[nt] = 0.f; cq[nt] = 0.f; }
#pragma unroll
  for (int nt = 0; nt < 2; ++nt) {
    int col = (wv * 2 + nt) * 16 + lc;
    float bias = b2[col];
#pragma unroll
    for (int mt = 0; mt < 2; ++mt) {
      int rbase = row0 + mt * 16 + lq * 4;
#pragma unroll
      for (int rg = 0; rg < 4; ++rg) {
        int row = rbase + rg;
        if (row < N_NODES) {
          float v = acc[mt][nt][rg] + bias;
          if (residual) v += h[(size_t)row * D + col];
          h[(size_t)row * D + col] = v;
          cs[nt] += v; cq[nt] += v * v;
        }
      }
    }
  }
#pragma unroll
  for (int nt = 0; nt < 2; ++nt) {
    float v = cs[nt], q = cq[nt];
    v += __shfl_xor(v, 16); v += __shfl_xor(v, 32);
    q += __shfl_xor(q, 16); q += __shfl_xor(q, 32);
    if (lq == 0) {
      int col = (wv * 2 + nt) * 16 + lc;
      atomicAdd(&statHs[slot * 256 + col], v);
      atomicAdd(&statHs[slot * 256 + 128 + col], q);
    }
  }
}

// ---------------------------------------------------------------- pool: segment-sum raw h per graph
__global__ __launch_bounds__(256) void k_pool(
    const float* __restrict__ h, const int* __restrict__ gstart,
    float* __restrict__ psum) {
  __shared__ float4 red[256];
  int b = blockIdx.x, tid = threadIdx.x;
  int fl = (tid & 31) << 2, ns = tid >> 5;
  int gs = gstart[b], ge = gstart[b + 1];
  float4 acc = make_float4(0.f, 0.f, 0.f, 0.f);
  for (int n = gs + ns; n < ge; n += 8) {
    float4 v = *(const float4*)&h[(size_t)n * D + fl];
    acc.x += v.x; acc.y += v.y; acc.z += v.z; acc.w += v.w;
  }
  red[tid] = acc;
  __syncthreads();
  if (ns < 4) {
    float4 o = red[tid + 128];
    acc.x += o.x; acc.y += o.y; acc.z += o.z; acc.w += o.w;
    red[tid] = acc;
  }
  __syncthreads();
  if (ns < 2) {
    float4 o = red[tid + 64];
    acc.x += o.x; acc.y += o.y; acc.z += o.z; acc.w += o.w;
    red[tid] = acc;
  }
  __syncthreads();
  if (ns == 0) {
    float4 o = red[tid + 32];
    acc.x += o.x; acc.y += o.y; acc.z += o.z; acc.w += o.w;
    *(float4*)&psum[(size_t)b * D + fl] = acc;
  }
}

// ---------------------------------------------------------------- predict: slot-reduce statH + affine-BN + head
__global__ __launch_bounds__(64) void k_pred(
    const float* __restrict__ psum, const int* __restrict__ gstart,
    const float* __restrict__ statHs, const float* __restrict__ gamma,
    const float* __restrict__ beta, const float* __restrict__ pw,
    const float* __restrict__ pb, float* __restrict__ out) {
  __shared__ float sH[256];
  int b = blockIdx.x, t = threadIdx.x;
  for (int j = t; j < 256; j += 64) {
    float a = 0.f;
#pragma unroll
    for (int s = 0; s < NSLOT; ++s) a += statHs[s * 256 + j];
    sH[j] = a;
  }
  __syncthreads();
  if (t >= NTARGET) return;
  int gs = gstart[b], ge = gstart[b + 1];
  float acc = pb[t];
  if (ge > gs) {
    const float invN = 1.0f / (float)N_NODES;
    float inv = 1.0f / (float)(ge - gs);
    for (int k = 0; k < D; ++k) {
      float mu = sH[k] * invN;
      float var = sH[D + k] * invN - mu * mu;
      float emb = (psum[(size_t)b * D + k] * inv - mu) * rsqrtf(var + BN_EPS_F) * gamma[k] + beta[k];
      acc += emb * pw[k * NTARGET + t];
    }
  }
  out[b * NTARGET + t] = acc;
}

// ---------------------------------------------------------------- launch
extern "C" void kernel_launch(void* const* d_in, const int* in_sizes, int n_in,
                              void* d_out, int out_size, void* d_ws, size_t ws_size,
                              hipStream_t stream) {
  const int* x      = (const int*)d_in[0];
  const int* ei     = (const int*)d_in[1];
  const int* eattr  = (const int*)d_in[2];
  const int* batch  = (const int*)d_in[3];
  const int* aoff   = (const int*)d_in[4];
  const int* boff   = (const int*)d_in[5];
  const float* atab = (const float*)d_in[6];
  const float* btab = (const float*)d_in[7];
  const float* ngam = (const float*)d_in[8];
  const float* nbet = (const float*)d_in[9];
  const float* tptr = (const float*)d_in[10];
  const float* w1   = (const float*)d_in[11];
  const float* b1   = (const float*)d_in[12];
  const float* bng  = (const float*)d_in[13];
  const float* bnb  = (const float*)d_in[14];
  const float* w2   = (const float*)d_in[15];
  const float* b2   = (const float*)d_in[16];
  const float* pw   = (const float*)d_in[17];
  const float* pb   = (const float*)d_in[18];
  float* out = (float*)d_out;

  float* ws = (float*)d_ws;
  const size_t ND = (size_t)N_NODES * D;
  float* h      = ws;                          // ND fp32
  _Float16* rh  = (_Float16*)(ws + 1 * ND);    // ND halfs
  _Float16* aggrh = (_Float16*)(ws + 1 * ND + ND / 2);
  _Float16* z1h = (_Float16*)(ws + 2 * ND);    // N*D2 halfs
  float* stat1s = ws + 3 * ND;                 // NSLOT*512
  float* statHs = stat1s + NSLOT * 512;        // NSLOT*256
  float* psum   = statHs + NSLOT * 256;        // 512*128
  float* combo  = psum + (size_t)NGRAPH * D;   // 60*128
  _Float16* w1p = (_Float16*)(combo + 60 * D); // 7*32768 halfs
  _Float16* w2p = w1p + 7 * 32768;             // 7*32768 halfs
  int* ibuf     = (int*)(w2p + 7 * 32768);
  int* rowptr   = ibuf;                        // N+1
  int* cursor   = rowptr + N_NODES + 1;        // N
  int* deg      = cursor + N_NODES;            // N
  int* payload  = deg + N_NODES;               // E
  int* gstart   = payload + N_EDGES;           // NGRAPH+1
  int* excl     = gstart + NGRAPH + 1;         // N
  int* bsum     = excl + N_NODES;              // 64

  const int nodeBlocks = (N_NODES * 32 + 255) / 256;
  const int edgeThreadBlocks = (N_EDGES + 255) / 256;
  const int nBlocks256 = (N_NODES + 255) / 256;
  const int gRows32 = (N_NODES + 31) / 32;     // 1563

  k_encode<<<nodeBlocks, 256, 0, stream>>>(x, aoff, atab, h, rh, deg);
  k_combo<<<60, 128, 0, stream>>>(boff, btab, combo);
  k_packW<<<(2 * 7 * 4096 + 255) / 256, 256, 0, stream>>>(w1, w2, w1p, w2p);
  k_gbounds<<<nBlocks256, 256, 0, stream>>>(batch, gstart);
  k_degree<<<edgeThreadBlocks, 256, 0, stream>>>(ei, deg);
  k_scan1<<<NSB, 1024, 0, stream>>>(deg, excl, bsum);
  k_scan2<<<1, 64, 0, stream>>>(bsum);
  k_scan3<<<(N_NODES + 256) / 256, 256, 0, stream>>>(excl, bsum, rowptr, cursor);
  k_scatter<<<edgeThreadBlocks, 256, 0, stream>>>(ei, eattr, cursor, payload);

  for (int l = 0; l < 7; ++l) {
    if (l > 0)
      k_prenorm<<<nodeBlocks, 256, 0, stream>>>(h, statHs, ngam + l * D, nbet + l * D, rh);
    k_aggr<<<nodeBlocks, 256, 0, stream>>>(rh, rowptr, payload, combo, tptr, l, aggrh,
                                           stat1s, statHs);
    k_gemm1<<<gRows32, 256, 0, stream>>>(rh, aggrh, w1p + (size_t)l * 32768,
                                         b1 + l * D2, z1h, stat1s);
    k_gemm2<<<gRows32, 256, 0, stream>>>(z1h, stat1s, bng + l * D2, bnb + l * D2,
                                         w2p + (size_t)l * 32768, b2 + l * D,
                                         h, l > 0 ? 1 : 0, statHs);
  }

  k_pool<<<NGRAPH, 256, 0, stream>>>(h, gstart, psum);
  k_pred<<<NGRAPH, 64, 0, stream>>>(psum, gstart, statHs, ngam, nbet, pw, pb, out);
}